// Round 8
// baseline (341.473 us; speedup 1.0000x reference)
//
#include <hip/hip_runtime.h>
#include <hip/hip_bf16.h>
#include <hip/hip_fp16.h>

// Problem constants
#define B_   2048
#define NN   128    // NMAX
#define MM   64     // HN
#define HD_  128
#define IND  18
#define FD_  16

typedef unsigned int u32;
typedef _Float16 h2_t __attribute__((ext_vector_type(2)));
typedef __attribute__((ext_vector_type(8))) short bf16x8;
typedef __attribute__((ext_vector_type(4))) float f32x4;

__device__ __forceinline__ float rcpf_(float x) {
#if defined(__has_builtin)
#if __has_builtin(__builtin_amdgcn_rcpf)
  return __builtin_amdgcn_rcpf(x);
#else
  return 1.0f / x;
#endif
#else
  return 1.0f / x;
#endif
}

__device__ __forceinline__ float h_lo(u32 d) {
  return __half2float(__ushort_as_half((unsigned short)(d & 0xffffu)));
}
__device__ __forceinline__ float h_hi(u32 d) {
  return __half2float(__ushort_as_half((unsigned short)(d >> 16)));
}

__device__ __forceinline__ float bf2f(unsigned short u) {
  union { float f; u32 i; } z; z.i = ((u32)u) << 16; return z.f;
}
__device__ __forceinline__ unsigned short f2bf(float f) {
  union { float fv; u32 u; } z; z.fv = f;
  u32 lsb = (z.u >> 16) & 1u;
  return (unsigned short)((z.u + 0x7fffu + lsb) >> 16);
}
__device__ __forceinline__ u32 bfpk(float a, float b) {
  return (u32)f2bf(a) | ((u32)f2bf(b) << 16);
}

// DPP full-wave sum: 4x row_shr + row_bcast15/31, then readlane(63) -> uniform.
#if defined(__has_builtin)
#if __has_builtin(__builtin_amdgcn_update_dpp) && __has_builtin(__builtin_amdgcn_readlane)
#define HAVE_DPP 1
#endif
#endif

#ifdef HAVE_DPP
template <int CTRL>
__device__ __forceinline__ float dpp_add(float v) {
  int t = __builtin_amdgcn_update_dpp(0, (int)__builtin_bit_cast(u32, v),
                                      CTRL, 0xf, 0xf, true);
  return v + __builtin_bit_cast(float, (u32)t);
}
__device__ __forceinline__ float wave_sum(float v) {
  v = dpp_add<0x111>(v);   // row_shr:1
  v = dpp_add<0x112>(v);   // row_shr:2
  v = dpp_add<0x114>(v);   // row_shr:4
  v = dpp_add<0x118>(v);   // row_shr:8
  v = dpp_add<0x142>(v);   // row_bcast:15
  v = dpp_add<0x143>(v);   // row_bcast:31
  int r = __builtin_amdgcn_readlane((int)__builtin_bit_cast(u32, v), 63);
  return __builtin_bit_cast(float, (u32)r);
}
#else
__device__ __forceinline__ float wave_sum(float v) {
  v += __shfl_xor(v, 1);  v += __shfl_xor(v, 2);
  v += __shfl_xor(v, 4);  v += __shfl_xor(v, 8);
  v += __shfl_xor(v, 16); v += __shfl_xor(v, 32);
  return v;
}
#endif

// ---------------------------------------------------------------------------
// Kernel A: ONE WAVE per (batch, stream) OT problem. grid (2048,2), block 64.
// Phase 1 on bf16 MFMA (verified). Sinkhorn R8: u/v kept in **f32** LDS
// (f16 RTZ exchange noise made every TOL fire only at quantized
// stationarity ~iter 40); dots via half->f32 fma (v_fma_mix); DPP wave
// reductions replace shuffle butterflies. Expect ~5-6 iterations.
// ---------------------------------------------------------------------------
__launch_bounds__(64, 2)
__global__ void ot_kernel(const float* __restrict__ x,
                          const float* __restrict__ w1,
                          const float* __restrict__ w2,
                          const float* __restrict__ fc2w, const float* __restrict__ fc2b,
                          const float* __restrict__ fc3w, const float* __restrict__ fc3b,
                          const float* __restrict__ bin_score,
                          unsigned short* __restrict__ Pbuf)
{
  __shared__ __align__(16) u32 Ksh[64 * 68];              // K f16, pitch 68 dw (136 h)
  __shared__ __align__(16) unsigned short actL[16 * 136]; // act slice bf16
  __shared__ __align__(16) float vfs[130];                // v f32 (128 + pad)
  __shared__ __align__(16) float ufs[64];                 // u f32

  const int l = threadIdx.x;
  const int b = blockIdx.x, s = blockIdx.y;
  const int l15 = l & 15, q = l >> 4;
  const float* wm = s ? w2 : w1;
  const float* fw = s ? fc3w : fc2w;
  const float* fb = s ? fc3b : fc2b;
  unsigned short* Kshh = reinterpret_cast<unsigned short*>(Ksh);

  // ---- preload w A-frags (rows m = 16at+l15, ch-octet q within kt) ----
  uint4 wA[4][4];
  #pragma unroll
  for (int at = 0; at < 4; ++at) {
    const float* wrow = wm + (size_t)(16 * at + l15) * 128;
    #pragma unroll
    for (int kt = 0; kt < 4; ++kt) {
      float4 va = *reinterpret_cast<const float4*>(wrow + 32 * kt + 8 * q);
      float4 vb = *reinterpret_cast<const float4*>(wrow + 32 * kt + 8 * q + 4);
      wA[at][kt] = make_uint4(bfpk(va.x, va.y), bfpk(va.z, va.w),
                              bfpk(vb.x, vb.y), bfpk(vb.z, vb.w));
    }
  }
  // ---- preload fcw B-frags (col ch = 16nt+l15, ind-octet q, K=32 zero-pad) ----
  uint4 fcwB[8];
  #pragma unroll
  for (int nt = 0; nt < 8; ++nt) {
    const int ch = 16 * nt + l15;
    uint4 o = make_uint4(0u, 0u, 0u, 0u);
    if (s) {
      if (q < 2) {
        const float* fr = fw + (size_t)ch * 16 + 8 * q;
        float4 va = *reinterpret_cast<const float4*>(fr);
        float4 vb = *reinterpret_cast<const float4*>(fr + 4);
        o = make_uint4(bfpk(va.x, va.y), bfpk(va.z, va.w),
                       bfpk(vb.x, vb.y), bfpk(vb.z, vb.w));
      }
    } else {
      if (q == 0) o.x = bfpk(fw[ch * 2], fw[ch * 2 + 1]);
    }
    fcwB[nt] = o;
  }
  float bb[8];
  #pragma unroll
  for (int nt = 0; nt < 8; ++nt) bb[nt] = fb[16 * nt + l15];

  // ---- preload x A-frags (row node = 16mt+l15, ind-octet q) ----
  uint4 xa[8];
  #pragma unroll
  for (int mt = 0; mt < 8; ++mt) {
    const int node = 16 * mt + l15;
    const float* xp = x + ((size_t)b * NN + node) * IND + (s ? 2 : 0);
    uint4 o = make_uint4(0u, 0u, 0u, 0u);
    if (s) {
      if (q < 2) {
        float2 p0 = *reinterpret_cast<const float2*>(xp + 8 * q);
        float2 p1 = *reinterpret_cast<const float2*>(xp + 8 * q + 2);
        float2 p2 = *reinterpret_cast<const float2*>(xp + 8 * q + 4);
        float2 p3 = *reinterpret_cast<const float2*>(xp + 8 * q + 6);
        o = make_uint4(bfpk(p0.x, p0.y), bfpk(p1.x, p1.y),
                       bfpk(p2.x, p2.y), bfpk(p3.x, p3.y));
      }
    } else {
      if (q == 0) {
        float2 p0 = *reinterpret_cast<const float2*>(xp);
        o.x = bfpk(p0.x, p0.y);
      }
    }
    xa[mt] = o;
  }
  const float ebs = __expf(bin_score[0]);

  // ---- Phase 1: 8 slices of 16 nodes ----
  #pragma unroll
  for (int mt = 0; mt < 8; ++mt) {
    f32x4 acc[8];
    #pragma unroll
    for (int nt = 0; nt < 8; ++nt)
      acc[nt] = __builtin_amdgcn_mfma_f32_16x16x32_bf16(
          __builtin_bit_cast(bf16x8, xa[mt]), __builtin_bit_cast(bf16x8, fcwB[nt]),
          f32x4{0.f, 0.f, 0.f, 0.f}, 0, 0, 0);
    #pragma unroll
    for (int nt = 0; nt < 8; ++nt) {
      #pragma unroll
      for (int r = 0; r < 4; ++r) {
        float v = fmaxf(acc[nt][r] + bb[nt], 0.0f);
        actL[(4 * q + r) * 136 + 16 * nt + l15] = f2bf(v);
      }
    }
    uint4 sB[4];
    #pragma unroll
    for (int kt = 0; kt < 4; ++kt)
      sB[kt] = *reinterpret_cast<const uint4*>(&actL[l15 * 136 + 32 * kt + 8 * q]);
    #pragma unroll
    for (int at = 0; at < 4; ++at) {
      f32x4 sa = f32x4{0.f, 0.f, 0.f, 0.f};
      #pragma unroll
      for (int kt = 0; kt < 4; ++kt)
        sa = __builtin_amdgcn_mfma_f32_16x16x32_bf16(
            __builtin_bit_cast(bf16x8, wA[at][kt]), __builtin_bit_cast(bf16x8, sB[kt]),
            sa, 0, 0, 0);
      #pragma unroll
      for (int r = 0; r < 4; ++r) {
        float kv = fminf(__expf(fmaxf(sa[r], 0.0f)), 60000.0f);
        Kshh[(16 * at + 4 * q + r) * 136 + 16 * mt + l15] =
            __half_as_ushort(__float2half_rn(kv));
      }
    }
  }

  // ---- register K tiles ----
  u32 kr[64];
  #pragma unroll
  for (int t = 0; t < 16; ++t) {
    uint4 kv = *reinterpret_cast<const uint4*>(Ksh + l * 68 + 4 * t);
    kr[4 * t + 0] = kv.x; kr[4 * t + 1] = kv.y;
    kr[4 * t + 2] = kv.z; kr[4 * t + 3] = kv.w;
  }
  u32 kta[32], ktb[32];
  #pragma unroll
  for (int j = 0; j < 32; ++j) {
    u32 d0 = Ksh[(2 * j) * 68 + l];
    u32 d1 = Ksh[(2 * j + 1) * 68 + l];
    kta[j] = (d0 & 0xffffu) | (d1 << 16);
    ktb[j] = (d0 >> 16) | (d1 & 0xffff0000u);
  }

  // ---- Phase 2: barrier-free exp-space Sinkhorn, f32 u/v ----
  vfs[l] = 1.0f;
  vfs[64 + l] = 1.0f;
  float v128 = 1.0f, sum_v = 129.0f;
  float u_old = 0.0f, vo0 = 1.0f, vo1 = 1.0f;
  float ur = 0.0f;
  const float TOL = 1.5e-3f;

  for (int it = 0; it < 100; ++it) {
    const float u64v = 128.0f * rcpf_(ebs * sum_v);
    // u-pass: row l
    float a0 = ebs * v128, a1 = 0.f, a2 = 0.f, a3 = 0.f;
    const float4* vf4 = reinterpret_cast<const float4*>(vfs);
    #pragma unroll
    for (int t = 0; t < 16; ++t) {
      float4 vv = vf4[2 * t];
      float4 vw = vf4[2 * t + 1];
      u32 k0 = kr[4 * t + 0], k1 = kr[4 * t + 1];
      u32 k2 = kr[4 * t + 2], k3 = kr[4 * t + 3];
      a0 = fmaf(h_lo(k0), vv.x, a0); a0 = fmaf(h_hi(k0), vv.y, a0);
      a1 = fmaf(h_lo(k1), vv.z, a1); a1 = fmaf(h_hi(k1), vv.w, a1);
      a2 = fmaf(h_lo(k2), vw.x, a2); a2 = fmaf(h_hi(k2), vw.y, a2);
      a3 = fmaf(h_lo(k3), vw.z, a3); a3 = fmaf(h_hi(k3), vw.w, a3);
    }
    float urn = rcpf_((a0 + a1) + (a2 + a3));
    float m1 = fabsf(urn - u_old) - TOL * urn;
    u_old = urn; ur = urn;
    ufs[l] = urn;
    float su = wave_sum(urn);
    const float sum_u = su + u64v;
    const float v128n = 64.0f * rcpf_(ebs * sum_u);
    // v-pass: cols 2l, 2l+1
    float c0a = ebs * u64v, c0b = 0.f, c1a = ebs * u64v, c1b = 0.f;
    const float4* uf4 = reinterpret_cast<const float4*>(ufs);
    #pragma unroll
    for (int t = 0; t < 16; ++t) {
      float4 uu = uf4[t];
      u32 ka0 = kta[2 * t], ka1 = kta[2 * t + 1];
      u32 kb0 = ktb[2 * t], kb1 = ktb[2 * t + 1];
      c0a = fmaf(h_lo(ka0), uu.x, c0a); c0a = fmaf(h_hi(ka0), uu.y, c0a);
      c0b = fmaf(h_lo(ka1), uu.z, c0b); c0b = fmaf(h_hi(ka1), uu.w, c0b);
      c1a = fmaf(h_lo(kb0), uu.x, c1a); c1a = fmaf(h_hi(kb0), uu.y, c1a);
      c1b = fmaf(h_lo(kb1), uu.z, c1b); c1b = fmaf(h_hi(kb1), uu.w, c1b);
    }
    float v0n = rcpf_(c0a + c0b);
    float v1n = rcpf_(c1a + c1b);
    float m2 = fabsf(v0n - vo0) - TOL * v0n;
    float m3 = fabsf(v1n - vo1) - TOL * v1n;
    vo0 = v0n; vo1 = v1n;
    *reinterpret_cast<float2*>(&vfs[2 * l]) = make_float2(v0n, v1n);
    sum_v = wave_sum(v0n + v1n) + v128n;
    v128 = v128n;
    float mcond = fmaxf(m1, fmaxf(m2, m3));
    if (__all(mcond <= 0.0f)) break;
  }

  // ---- Phase 3: P[l][n] = K*u*v -> bf16 ----
  {
    unsigned short* Pout = Pbuf + ((size_t)(s * B_ + b)) * (MM * NN);
    uint4* P4 = reinterpret_cast<uint4*>(Pout);
    const float4* vf4 = reinterpret_cast<const float4*>(vfs);
    #pragma unroll
    for (int t = 0; t < 16; ++t) {
      float4 v0 = vf4[2 * t];
      float4 v1 = vf4[2 * t + 1];
      u32 o0 = bfpk(h_lo(kr[4 * t + 0]) * ur * v0.x, h_hi(kr[4 * t + 0]) * ur * v0.y);
      u32 o1 = bfpk(h_lo(kr[4 * t + 1]) * ur * v0.z, h_hi(kr[4 * t + 1]) * ur * v0.w);
      u32 o2 = bfpk(h_lo(kr[4 * t + 2]) * ur * v1.x, h_hi(kr[4 * t + 2]) * ur * v1.y);
      u32 o3 = bfpk(h_lo(kr[4 * t + 3]) * ur * v1.z, h_hi(kr[4 * t + 3]) * ur * v1.w);
      P4[l * 16 + t] = make_uint4(o0, o1, o2, o3);
    }
  }
}

// ---------------------------------------------------------------------------
// Kernel B (MFMA): unchanged (passed).
// ---------------------------------------------------------------------------
#define AP 136   // bf16 row pitch (272 B, 16B aligned)

__device__ __forceinline__ bf16x8 ldfrag(const unsigned short* p) {
  return __builtin_bit_cast(bf16x8, *reinterpret_cast<const uint4*>(p));
}
__device__ __forceinline__ u32 comb2(u32 ps, u32 pf, float a, float na) {
  float r0 = a * bf2f((unsigned short)(ps & 0xffffu)) + na * bf2f((unsigned short)(pf & 0xffffu));
  float r1 = a * bf2f((unsigned short)(ps >> 16)) + na * bf2f((unsigned short)(pf >> 16));
  return (u32)f2bf(r0) | ((u32)f2bf(r1) << 16);
}

__launch_bounds__(256, 2)
__global__ void align_kernel(const unsigned short* __restrict__ Pbuf,
                             const float* __restrict__ adj,
                             const float* __restrict__ x,
                             const float* __restrict__ alpha_p,
                             const float* __restrict__ ln1g, const float* __restrict__ ln1b,
                             const float* __restrict__ ln2g, const float* __restrict__ ln2b,
                             unsigned short* __restrict__ lnadj,
                             unsigned short* __restrict__ lnfeats)
{
  __shared__ __align__(16) unsigned short adjb[128 * AP];
  __shared__ __align__(16) unsigned short Pms[64 * AP];
  __shared__ __align__(16) unsigned short Z1T[64 * AP];
  __shared__ __align__(16) unsigned short xfT[16 * AP];
  __shared__ float red[16];

  const int tid = threadIdx.x;
  const int b = blockIdx.x;
  const int w = tid >> 6;
  const int lane = tid & 63;
  const int l15 = lane & 15;
  const int q = lane >> 4;
  const float a = 1.0f / (1.0f + __expf(-alpha_p[0]));
  const float na = 1.0f - a;

  {
    const float4* src = reinterpret_cast<const float4*>(adj + (size_t)b * (NN * NN));
    for (int i = tid; i < 128 * 32; i += 256) {
      int row = i >> 5, c4 = i & 31;
      float4 v = src[i];
      u32 w0 = (u32)f2bf(v.x) | ((u32)f2bf(v.y) << 16);
      u32 w1 = (u32)f2bf(v.z) | ((u32)f2bf(v.w) << 16);
      *reinterpret_cast<uint2*>(&adjb[row * AP + c4 * 4]) = make_uint2(w0, w1);
    }
  }
  {
    const uint4* Ps4 = reinterpret_cast<const uint4*>(Pbuf + (size_t)b * (MM * NN));
    const uint4* Pf4 = reinterpret_cast<const uint4*>(Pbuf + ((size_t)B_ + b) * (MM * NN));
    for (int i = tid; i < 64 * 16; i += 256) {
      int row = i >> 4, g = i & 15;
      uint4 sa = Ps4[i];
      uint4 fa = Pf4[i];
      uint4 o;
      o.x = comb2(sa.x, fa.x, a, na); o.y = comb2(sa.y, fa.y, a, na);
      o.z = comb2(sa.z, fa.z, a, na); o.w = comb2(sa.w, fa.w, a, na);
      *reinterpret_cast<uint4*>(&Pms[row * AP + g * 8]) = o;
    }
  }
  for (int i = tid; i < 2048; i += 256) {
    int n = i & 127, f = i >> 7;
    xfT[f * AP + n] = f2bf(x[((size_t)b * NN + n) * IND + 2 + f]);
  }
  __syncthreads();

  {
    f32x4 acc[2][4];
    #pragma unroll
    for (int i = 0; i < 2; ++i)
      #pragma unroll
      for (int j = 0; j < 4; ++j) acc[i][j] = f32x4{0.f, 0.f, 0.f, 0.f};
    #pragma unroll
    for (int kt = 0; kt < 4; ++kt) {
      const int d0 = 32 * kt + 8 * q;
      bf16x8 bf[4];
      #pragma unroll
      for (int j = 0; j < 4; ++j)
        bf[j] = ldfrag(&Pms[(16 * j + l15) * AP + d0]);
      #pragma unroll
      for (int ai = 0; ai < 2; ++ai) {
        bf16x8 af = ldfrag(&adjb[(32 * w + 16 * ai + l15) * AP + d0]);
        #pragma unroll
        for (int j = 0; j < 4; ++j)
          acc[ai][j] = __builtin_amdgcn_mfma_f32_16x16x32_bf16(af, bf[j], acc[ai][j], 0, 0, 0);
      }
    }
    #pragma unroll
    for (int ai = 0; ai < 2; ++ai) {
      #pragma unroll
      for (int j = 0; j < 4; ++j) {
        const int k = 16 * j + l15;
        const int nbase = 32 * w + 16 * ai + 4 * q;
        u32 w0 = (u32)f2bf(acc[ai][j][0]) | ((u32)f2bf(acc[ai][j][1]) << 16);
        u32 w1 = (u32)f2bf(acc[ai][j][2]) | ((u32)f2bf(acc[ai][j][3]) << 16);
        *reinterpret_cast<uint2*>(&Z1T[k * AP + nbase]) = make_uint2(w0, w1);
      }
    }
  }
  __syncthreads();

  f32x4 acc2[4];
  f32x4 acc3 = f32x4{0.f, 0.f, 0.f, 0.f};
  #pragma unroll
  for (int j = 0; j < 4; ++j) acc2[j] = f32x4{0.f, 0.f, 0.f, 0.f};
  #pragma unroll
  for (int nt = 0; nt < 4; ++nt) {
    const int n0 = 32 * nt + 8 * q;
    bf16x8 af = ldfrag(&Pms[(16 * w + l15) * AP + n0]);
    #pragma unroll
    for (int j = 0; j < 4; ++j) {
      bf16x8 bv = ldfrag(&Z1T[(16 * j + l15) * AP + n0]);
      acc2[j] = __builtin_amdgcn_mfma_f32_16x16x32_bf16(af, bv, acc2[j], 0, 0, 0);
    }
    bf16x8 bx = ldfrag(&xfT[l15 * AP + n0]);
    acc3 = __builtin_amdgcn_mfma_f32_16x16x32_bf16(af, bx, acc3, 0, 0, 0);
  }

  {
    float s1 = 0.f, q1 = 0.f, s2 = 0.f, q2 = 0.f;
    #pragma unroll
    for (int j = 0; j < 4; ++j)
      #pragma unroll
      for (int r = 0; r < 4; ++r) { float v = acc2[j][r]; s1 += v; q1 += v * v; }
    #pragma unroll
    for (int r = 0; r < 4; ++r) { float v = acc3[r]; s2 += v; q2 += v * v; }
    #pragma unroll
    for (int off = 1; off < 64; off <<= 1) {
      s1 += __shfl_xor(s1, off); q1 += __shfl_xor(q1, off);
      s2 += __shfl_xor(s2, off); q2 += __shfl_xor(q2, off);
    }
    if (lane == 0) { red[w] = s1; red[4 + w] = q1; red[8 + w] = s2; red[12 + w] = q2; }
  }
  __syncthreads();
  const float S1 = red[0] + red[1] + red[2] + red[3];
  const float Q1 = red[4] + red[5] + red[6] + red[7];
  const float S2 = red[8] + red[9] + red[10] + red[11];
  const float Q2 = red[12] + red[13] + red[14] + red[15];
  const float mean1 = S1 * (1.0f / 4096.0f);
  const float rstd1 = rsqrtf(Q1 * (1.0f / 4096.0f) - mean1 * mean1 + 1e-5f);
  const float mean2 = S2 * (1.0f / 1024.0f);
  const float rstd2 = rsqrtf(Q2 * (1.0f / 1024.0f) - mean2 * mean2 + 1e-5f);

  unsigned short* ob1 = adjb;
  unsigned short* ob2 = Z1T;
  #pragma unroll
  for (int j = 0; j < 4; ++j) {
    const int k = 16 * j + l15;
    #pragma unroll
    for (int r = 0; r < 4; ++r) {
      const int m = 16 * w + 4 * q + r;
      const int pos = m * 64 + k;
      float vv = (acc2[j][r] - mean1) * rstd1 * ln1g[pos] + ln1b[pos];
      ob1[pos] = f2bf(vv);
    }
  }
  {
    const int f = l15;
    #pragma unroll
    for (int r = 0; r < 4; ++r) {
      const int m = 16 * w + 4 * q + r;
      const int pos = m * 16 + f;
      float vv = (acc3[r] - mean2) * rstd2 * ln2g[pos] + ln2b[pos];
      ob2[pos] = f2bf(vv);
    }
  }
  __syncthreads();
  {
    const uint4* sp = reinterpret_cast<const uint4*>(ob1);
    uint4* dp = reinterpret_cast<uint4*>(lnadj + (size_t)b * 4096);
    for (int i = tid; i < 512; i += 256) dp[i] = sp[i];
    if (tid < 128)
      reinterpret_cast<uint4*>(lnfeats + (size_t)b * 1024)[tid] =
          reinterpret_cast<const uint4*>(ob2)[tid];
  }
}

// ---------------------------------------------------------------------------
// Kernel C (MFMA): unchanged.
// ---------------------------------------------------------------------------
#define GP 72
__launch_bounds__(256, 2)
__global__ void gemm_mfma_kernel(const unsigned short* __restrict__ A,
                                 const float* __restrict__ W,
                                 const float* __restrict__ bias,
                                 float* __restrict__ C,
                                 int K, int ldc, int coff)
{
  __shared__ __align__(16) unsigned short At[64 * GP];
  __shared__ __align__(16) unsigned short Wt[64 * GP];
  const int tid = threadIdx.x;
  const int m0 = blockIdx.x * 64;
  const int n0 = blockIdx.y * 64;
  const int w = tid >> 6, lane = tid & 63;
  const int l15 = lane & 15, q = lane >> 4;
  const int srow = tid >> 2, sko = (tid & 3) * 16;

  f32x4 acc[4];
  #pragma unroll
  for (int j = 0; j < 4; ++j) acc[j] = f32x4{0.f, 0.f, 0.f, 0.f};

  for (int kc = 0; kc < K; kc += 64) {
    __syncthreads();
    {
      const unsigned short* ap = &A[(size_t)(m0 + srow) * K + kc + sko];
      *reinterpret_cast<uint4*>(&At[srow * GP + sko]) =
          *reinterpret_cast<const uint4*>(ap);
      *reinterpret_cast<uint4*>(&At[srow * GP + sko + 8]) =
          *reinterpret_cast<const uint4*>(ap + 8);
      const float* wp = &W[(size_t)(n0 + srow) * K + kc + sko];
      const float4 v0 = reinterpret_cast<const float4*>(wp)[0];
      const float4 v1 = reinterpret_cast<const float4*>(wp)[1];
      const float4 v2 = reinterpret_cast<const float4*>(wp)[2];
      const float4 v3 = reinterpret_cast<const float4*>(wp)[3];
      uint4 o0, o1;
      o0.x = (u32)f2bf(v0.x) | ((u32)f2bf(v0.y) << 16);
      o0.y = (u32)f2bf(v0.z) | ((u32)f2bf(v0.w) << 16);
      o0.z = (u32)f2bf(v1.x) | ((u32)f2bf(v1.y) << 16);
      o0.w = (u32)f2bf(v1.z) | ((u32)f2bf(v1.w) << 16);
      o1.x = (u32)f2bf(v2.x) | ((u32)f2bf(v2.y) << 16);
      o1.y = (u32)f2bf(v2.z) | ((u32)f2bf(v2.w) << 16);
      o1.z = (u32)f2bf(v3.x) | ((u32)f2bf(v3.y) << 16);
      o1.w = (u32)f2bf(v3.z) | ((u32)f2bf(v3.w) << 16);
      *reinterpret_cast<uint4*>(&Wt[srow * GP + sko]) = o0;
      *reinterpret_cast<uint4*>(&Wt[srow * GP + sko + 8]) = o1;
    }
    __syncthreads();
    #pragma unroll
    for (int s = 0; s < 2; ++s) {
      bf16x8 af = ldfrag(&At[(16 * w + l15) * GP + 32 * s + 8 * q]);
      #pragma unroll
      for (int j = 0; j < 4; ++j) {
        bf16x8 bf = ldfrag(&Wt[(16 * j + l15) * GP + 32 * s + 8 * q]);
        acc[j] = __builtin_amdgcn_mfma_f32_16x16x32_bf16(af, bf, acc[j], 0, 0, 0);
      }
    }
  }
  #pragma unroll
  for (int j = 0; j < 4; ++j) {
    const int col = n0 + 16 * j + l15;
    const float bb = bias[col];
    #pragma unroll
    for (int r = 0; r < 4; ++r) {
      const int m = m0 + 16 * w + 4 * q + r;
      C[(size_t)m * ldc + coff + col] = fmaxf(acc[j][r] + bb, 0.0f);
    }
  }
}

// ---------------------------------------------------------------------------
// Kernel D: unchanged (8 rows/block).
// ---------------------------------------------------------------------------
__launch_bounds__(256)
__global__ void head_kernel(const float* __restrict__ h45,
                            const float* __restrict__ wT6,   // [512][64]
                            const float* __restrict__ b6,
                            const float* __restrict__ w7,    // [10][64]
                            const float* __restrict__ b7,
                            float* __restrict__ out)
{
  __shared__ float row[8][512];
  __shared__ float h6[8][64];
  __shared__ float zb[8][12];
  const int tid = threadIdx.x;
  const int r0 = blockIdx.x * 8;
  for (int i = tid; i < 8 * 128; i += 256) {
    int r = i >> 7, c4 = i & 127;
    *reinterpret_cast<float4*>(&row[r][c4 * 4]) =
        reinterpret_cast<const float4*>(h45 + (size_t)(r0 + r) * 512)[c4];
  }
  __syncthreads();
  const int o = tid & 63, rg = tid >> 6;
  float a0 = b6[o], a1 = a0;
  #pragma unroll 8
  for (int k = 0; k < 512; ++k) {
    float wv = wT6[k * 64 + o];
    a0 += row[rg][k] * wv;
    a1 += row[rg + 4][k] * wv;
  }
  h6[rg][o] = fmaxf(a0, 0.0f);
  h6[rg + 4][o] = fmaxf(a1, 0.0f);
  __syncthreads();
  if (tid < 80) {
    int r = tid / 10, c = tid - r * 10;
    float z = b7[c];
    #pragma unroll
    for (int k = 0; k < 64; ++k) z += h6[r][k] * w7[c * 64 + k];
    zb[r][c] = z;
  }
  __syncthreads();
  if (tid < 80) {
    int r = tid / 10, c = tid - r * 10;
    float mx = zb[r][0];
    #pragma unroll
    for (int j = 1; j < 10; ++j) mx = fmaxf(mx, zb[r][j]);
    float se = 0.f;
    #pragma unroll
    for (int j = 0; j < 10; ++j) se += __expf(zb[r][j] - mx);
    out[(size_t)(r0 + r) * 10 + c] = zb[r][c] - mx - __logf(se);
  }
}

__global__ void transpose_kernel(const float* __restrict__ in, float* __restrict__ outp,
                                 int R, int Cc)
{
  int idx = blockIdx.x * blockDim.x + threadIdx.x;
  int total = R * Cc;
  for (; idx < total; idx += gridDim.x * blockDim.x) {
    int rr = idx / Cc, cc = idx - rr * Cc;
    outp[cc * R + rr] = in[idx];
  }
}

// ---------------------------------------------------------------------------
extern "C" void kernel_launch(void* const* d_in, const int* in_sizes, int n_in,
                              void* d_out, int out_size, void* d_ws, size_t ws_size,
                              hipStream_t stream)
{
  (void)in_sizes; (void)n_in; (void)out_size; (void)ws_size;
  const float* x    = (const float*)d_in[0];
  const float* adj  = (const float*)d_in[1];
  const float* w1   = (const float*)d_in[2];
  const float* w2   = (const float*)d_in[3];
  const float* alpha = (const float*)d_in[4];
  const float* bin_score = (const float*)d_in[5];
  const float* fc2w = (const float*)d_in[6];
  const float* fc2b = (const float*)d_in[7];
  const float* fc3w = (const float*)d_in[8];
  const float* fc3b = (const float*)d_in[9];
  const float* ln1g = (const float*)d_in[10];
  const float* ln1b = (const float*)d_in[11];
  const float* fc4w = (const float*)d_in[12];
  const float* fc4b = (const float*)d_in[13];
  const float* ln2g = (const float*)d_in[14];
  const float* ln2b = (const float*)d_in[15];
  const float* fc5w = (const float*)d_in[16];
  const float* fc5b = (const float*)d_in[17];
  const float* fc6w = (const float*)d_in[18];
  const float* fc6b = (const float*)d_in[19];
  const float* fc7w = (const float*)d_in[20];
  const float* fc7b = (const float*)d_in[21];
  float* out = (float*)d_out;

  char* ws = (char*)d_ws;
  unsigned short* Pbuf = (unsigned short*)ws;                       // 4096*8192 bf16 = 64 MB
  size_t off = (size_t)4096 * 8192 * 2;
  unsigned short* lnadj = (unsigned short*)(ws + off);  off += (size_t)2048 * 4096 * 2;
  unsigned short* lnfeats = (unsigned short*)(ws + off); off += (size_t)2048 * 1024 * 2;
  float* h45 = (float*)(ws + off);                      off += (size_t)2048 * 512 * 4;
  float* wT6 = (float*)(ws + off);                      off += (size_t)512 * 64 * 4;

  hipLaunchKernelGGL(ot_kernel, dim3(2048, 2), dim3(64), 0, stream,
                     x, w1, w2, fc2w, fc2b, fc3w, fc3b, bin_score, Pbuf);
  hipLaunchKernelGGL(transpose_kernel, dim3(32), dim3(256), 0, stream, fc6w, wT6, 64, 512);
  hipLaunchKernelGGL(align_kernel, dim3(2048), dim3(256), 0, stream,
                     Pbuf, adj, x, alpha, ln1g, ln1b, ln2g, ln2b, lnadj, lnfeats);
  hipLaunchKernelGGL(gemm_mfma_kernel, dim3(32, 4), dim3(256), 0, stream,
                     lnadj, fc4w, fc4b, h45, 4096, 512, 0);
  hipLaunchKernelGGL(gemm_mfma_kernel, dim3(32, 4), dim3(256), 0, stream,
                     lnfeats, fc5w, fc5b, h45, 1024, 512, 256);
  hipLaunchKernelGGL(head_kernel, dim3(256), dim3(256), 0, stream,
                     h45, wT6, fc6b, fc7w, fc7b, out);
}

// Round 9
// 254.509 us; speedup vs baseline: 1.3417x; 1.3417x over previous
//
#include <hip/hip_runtime.h>
#include <hip/hip_bf16.h>
#include <hip/hip_fp16.h>

// Problem constants
#define B_   2048
#define NN   128    // NMAX
#define MM   64     // HN
#define HD_  128
#define IND  18
#define FD_  16

typedef unsigned int u32;
typedef _Float16 h2_t __attribute__((ext_vector_type(2)));
typedef __attribute__((ext_vector_type(8))) short bf16x8;
typedef __attribute__((ext_vector_type(4))) float f32x4;

__device__ __forceinline__ float fdot2f(u32 a, u32 b, float c) {
#if defined(__has_builtin)
#if __has_builtin(__builtin_amdgcn_fdot2)
  return __builtin_amdgcn_fdot2(__builtin_bit_cast(h2_t, a),
                                __builtin_bit_cast(h2_t, b), c, false);
#else
  h2_t x = __builtin_bit_cast(h2_t, a), y = __builtin_bit_cast(h2_t, b);
  return c + (float)x[0] * (float)y[0] + (float)x[1] * (float)y[1];
#endif
#else
  h2_t x = __builtin_bit_cast(h2_t, a), y = __builtin_bit_cast(h2_t, b);
  return c + (float)x[0] * (float)y[0] + (float)x[1] * (float)y[1];
#endif
}

__device__ __forceinline__ u32 pk2(float a, float b) {
#if defined(__has_builtin)
#if __has_builtin(__builtin_amdgcn_cvt_pkrtz)
  return __builtin_bit_cast(u32, __builtin_amdgcn_cvt_pkrtz(a, b));
#else
  __half ha = __float2half_rn(a), hb = __float2half_rn(b);
  return (u32)__half_as_ushort(ha) | ((u32)__half_as_ushort(hb) << 16);
#endif
#else
  __half ha = __float2half_rn(a), hb = __float2half_rn(b);
  return (u32)__half_as_ushort(ha) | ((u32)__half_as_ushort(hb) << 16);
#endif
}

__device__ __forceinline__ float rcpf_(float x) {
#if defined(__has_builtin)
#if __has_builtin(__builtin_amdgcn_rcpf)
  return __builtin_amdgcn_rcpf(x);
#else
  return 1.0f / x;
#endif
#else
  return 1.0f / x;
#endif
}

__device__ __forceinline__ float h_lo(u32 d) {
  return __half2float(__ushort_as_half((unsigned short)(d & 0xffffu)));
}
__device__ __forceinline__ float h_hi(u32 d) {
  return __half2float(__ushort_as_half((unsigned short)(d >> 16)));
}

__device__ __forceinline__ float bf2f(unsigned short u) {
  union { float f; u32 i; } z; z.i = ((u32)u) << 16; return z.f;
}
__device__ __forceinline__ unsigned short f2bf(float f) {
  union { float fv; u32 u; } z; z.fv = f;
  u32 lsb = (z.u >> 16) & 1u;
  return (unsigned short)((z.u + 0x7fffu + lsb) >> 16);
}
__device__ __forceinline__ u32 bfpk(float a, float b) {
  return (u32)f2bf(a) | ((u32)f2bf(b) << 16);
}

// DPP full-wave sum (verified in R8: results passed). Fallback: shfl butterfly.
#if defined(__has_builtin)
#if __has_builtin(__builtin_amdgcn_update_dpp) && __has_builtin(__builtin_amdgcn_readlane)
#define HAVE_DPP 1
#endif
#endif

#ifdef HAVE_DPP
template <int CTRL>
__device__ __forceinline__ float dpp_add(float v) {
  int t = __builtin_amdgcn_update_dpp(0, (int)__builtin_bit_cast(u32, v),
                                      CTRL, 0xf, 0xf, true);
  return v + __builtin_bit_cast(float, (u32)t);
}
__device__ __forceinline__ float wave_sum(float v) {
  v = dpp_add<0x111>(v);   // row_shr:1
  v = dpp_add<0x112>(v);   // row_shr:2
  v = dpp_add<0x114>(v);   // row_shr:4
  v = dpp_add<0x118>(v);   // row_shr:8
  v = dpp_add<0x142>(v);   // row_bcast:15
  v = dpp_add<0x143>(v);   // row_bcast:31
  int r = __builtin_amdgcn_readlane((int)__builtin_bit_cast(u32, v), 63);
  return __builtin_bit_cast(float, (u32)r);
}
#else
__device__ __forceinline__ float wave_sum(float v) {
  v += __shfl_xor(v, 1);  v += __shfl_xor(v, 2);
  v += __shfl_xor(v, 4);  v += __shfl_xor(v, 8);
  v += __shfl_xor(v, 16); v += __shfl_xor(v, 32);
  return v;
}
#endif

// ---------------------------------------------------------------------------
// Kernel A (R9): TWO waves per (batch, stream) OT problem. grid (2048,2),
// block 128. Phase 1 (bf16 MFMA, verified): wave wv does mt slices 4wv..4wv+3.
// Sinkhorn (f16 exchange, fdot2 — R7's proven numerics, registers halved):
//   u-pass: lane pair (row mrow = 32wv + l>>1, col-half h = l&1), kr[32].
//   v-pass: lane owns col c = 64wv + l, kt[32].
//   2 barriers/iter; cross-wave sums + convergence flag via tiny LDS.
// ---------------------------------------------------------------------------
__launch_bounds__(128, 2)
__global__ void ot_kernel(const float* __restrict__ x,
                          const float* __restrict__ w1,
                          const float* __restrict__ w2,
                          const float* __restrict__ fc2w, const float* __restrict__ fc2b,
                          const float* __restrict__ fc3w, const float* __restrict__ fc3b,
                          const float* __restrict__ bin_score,
                          unsigned short* __restrict__ Pbuf)
{
  __shared__ __align__(16) u32 Ksh[64 * 68];               // K f16, pitch 68 dw
  __shared__ __align__(16) unsigned short actL[2][16 * 136]; // per-wave act slice
  __shared__ __align__(16) u32 vhs[64];                    // v packed f16 pairs
  __shared__ __align__(16) u32 uhs[32];                    // u packed f16 pairs
  __shared__ float red[4];
  __shared__ int flg[2];

  const int tid = threadIdx.x;
  const int wv = tid >> 6;       // wave 0/1
  const int l = tid & 63;
  const int b = blockIdx.x, s = blockIdx.y;
  const int l15 = l & 15, q = l >> 4;
  const float* wm = s ? w2 : w1;
  const float* fw = s ? fc3w : fc2w;
  const float* fb = s ? fc3b : fc2b;
  unsigned short* Kshh = reinterpret_cast<unsigned short*>(Ksh);

  // ---- preload w A-frags (all 64 rows; both waves need all at) ----
  uint4 wA[4][4];
  #pragma unroll
  for (int at = 0; at < 4; ++at) {
    const float* wrow = wm + (size_t)(16 * at + l15) * 128;
    #pragma unroll
    for (int kt2 = 0; kt2 < 4; ++kt2) {
      float4 va = *reinterpret_cast<const float4*>(wrow + 32 * kt2 + 8 * q);
      float4 vb = *reinterpret_cast<const float4*>(wrow + 32 * kt2 + 8 * q + 4);
      wA[at][kt2] = make_uint4(bfpk(va.x, va.y), bfpk(va.z, va.w),
                               bfpk(vb.x, vb.y), bfpk(vb.z, vb.w));
    }
  }
  // ---- preload fcw B-frags ----
  uint4 fcwB[8];
  #pragma unroll
  for (int nt = 0; nt < 8; ++nt) {
    const int ch = 16 * nt + l15;
    uint4 o = make_uint4(0u, 0u, 0u, 0u);
    if (s) {
      if (q < 2) {
        const float* fr = fw + (size_t)ch * 16 + 8 * q;
        float4 va = *reinterpret_cast<const float4*>(fr);
        float4 vb = *reinterpret_cast<const float4*>(fr + 4);
        o = make_uint4(bfpk(va.x, va.y), bfpk(va.z, va.w),
                       bfpk(vb.x, vb.y), bfpk(vb.z, vb.w));
      }
    } else {
      if (q == 0) o.x = bfpk(fw[ch * 2], fw[ch * 2 + 1]);
    }
    fcwB[nt] = o;
  }
  float bb[8];
  #pragma unroll
  for (int nt = 0; nt < 8; ++nt) bb[nt] = fb[16 * nt + l15];

  // ---- preload x A-frags for this wave's 4 slices ----
  uint4 xa[4];
  #pragma unroll
  for (int mi = 0; mi < 4; ++mi) {
    const int node = 16 * (4 * wv + mi) + l15;
    const float* xp = x + ((size_t)b * NN + node) * IND + (s ? 2 : 0);
    uint4 o = make_uint4(0u, 0u, 0u, 0u);
    if (s) {
      if (q < 2) {
        float2 p0 = *reinterpret_cast<const float2*>(xp + 8 * q);
        float2 p1 = *reinterpret_cast<const float2*>(xp + 8 * q + 2);
        float2 p2 = *reinterpret_cast<const float2*>(xp + 8 * q + 4);
        float2 p3 = *reinterpret_cast<const float2*>(xp + 8 * q + 6);
        o = make_uint4(bfpk(p0.x, p0.y), bfpk(p1.x, p1.y),
                       bfpk(p2.x, p2.y), bfpk(p3.x, p3.y));
      }
    } else {
      if (q == 0) {
        float2 p0 = *reinterpret_cast<const float2*>(xp);
        o.x = bfpk(p0.x, p0.y);
      }
    }
    xa[mi] = o;
  }
  const float ebs = __expf(bin_score[0]);

  // ---- Phase 1: this wave's 4 slices of 16 nodes ----
  unsigned short* actw = actL[wv];
  #pragma unroll
  for (int mi = 0; mi < 4; ++mi) {
    const int mt = 4 * wv + mi;
    f32x4 acc[8];
    #pragma unroll
    for (int nt = 0; nt < 8; ++nt)
      acc[nt] = __builtin_amdgcn_mfma_f32_16x16x32_bf16(
          __builtin_bit_cast(bf16x8, xa[mi]), __builtin_bit_cast(bf16x8, fcwB[nt]),
          f32x4{0.f, 0.f, 0.f, 0.f}, 0, 0, 0);
    #pragma unroll
    for (int nt = 0; nt < 8; ++nt) {
      #pragma unroll
      for (int r = 0; r < 4; ++r) {
        float v = fmaxf(acc[nt][r] + bb[nt], 0.0f);
        actw[(4 * q + r) * 136 + 16 * nt + l15] = f2bf(v);
      }
    }
    uint4 sB[4];
    #pragma unroll
    for (int kt2 = 0; kt2 < 4; ++kt2)
      sB[kt2] = *reinterpret_cast<const uint4*>(&actw[l15 * 136 + 32 * kt2 + 8 * q]);
    #pragma unroll
    for (int at = 0; at < 4; ++at) {
      f32x4 sa = f32x4{0.f, 0.f, 0.f, 0.f};
      #pragma unroll
      for (int kt2 = 0; kt2 < 4; ++kt2)
        sa = __builtin_amdgcn_mfma_f32_16x16x32_bf16(
            __builtin_bit_cast(bf16x8, wA[at][kt2]), __builtin_bit_cast(bf16x8, sB[kt2]),
            sa, 0, 0, 0);
      #pragma unroll
      for (int r = 0; r < 4; ++r) {
        float kv = fminf(__expf(fmaxf(sa[r], 0.0f)), 60000.0f);
        Kshh[(16 * at + 4 * q + r) * 136 + 16 * mt + l15] =
            __half_as_ushort(__float2half_rn(kv));
      }
    }
  }
  __syncthreads();   // Ksh complete (both waves)

  // ---- extraction: kr = row mrow, col-half h; kt = col c, row pairs ----
  const int h = l & 1;
  const int mrow = 32 * wv + (l >> 1);
  u32 kr[32];
  #pragma unroll
  for (int t = 0; t < 8; ++t) {
    uint4 kv = *reinterpret_cast<const uint4*>(Ksh + mrow * 68 + 32 * h + 4 * t);
    kr[4 * t + 0] = kv.x; kr[4 * t + 1] = kv.y;
    kr[4 * t + 2] = kv.z; kr[4 * t + 3] = kv.w;
  }
  u32 kt[32];
  {
    const int ch = (64 * wv + l) >> 1;
    #pragma unroll
    for (int j = 0; j < 32; ++j) {
      u32 d0 = Ksh[(2 * j) * 68 + ch];
      u32 d1 = Ksh[(2 * j + 1) * 68 + ch];
      kt[j] = h ? ((d0 >> 16) | (d1 & 0xffff0000u))
                : ((d0 & 0xffffu) | (d1 << 16));
    }
  }
  if (tid < 64) vhs[tid] = 0x3C003C00u;   // v = 1
  __syncthreads();

  // ---- Phase 2: 2-wave exp-space Sinkhorn (f16 exchange, R7 numerics) ----
  float v128 = 1.0f, sum_v = 129.0f;
  float u_old = 0.0f, v_old = 1.0f;
  const float TOL = 1.5e-3f;

  for (int it = 0; it < 100; ++it) {
    const float u64v = 128.0f * rcpf_(ebs * sum_v);
    // u-pass
    float a0 = h ? 0.0f : ebs * v128;
    float a1 = 0.f, a2 = 0.f, a3 = 0.f;
    const uint4* vh4 = reinterpret_cast<const uint4*>(vhs) + 8 * h;
    #pragma unroll
    for (int t = 0; t < 8; ++t) {
      uint4 vv = vh4[t];
      a0 = fdot2f(kr[4 * t + 0], vv.x, a0);
      a1 = fdot2f(kr[4 * t + 1], vv.y, a1);
      a2 = fdot2f(kr[4 * t + 2], vv.z, a2);
      a3 = fdot2f(kr[4 * t + 3], vv.w, a3);
    }
    float part = (a0 + a1) + (a2 + a3);
    part += __shfl_xor(part, 1);           // combine col halves
    float urn = rcpf_(part);
    float m1 = fabsf(urn - u_old) - TOL * urn;
    u_old = urn;
    float u_pair = __shfl_xor(urn, 2);     // next row of the pair
    if ((l & 3) == 0) uhs[16 * wv + (l >> 2)] = pk2(urn, u_pair);
    float su = wave_sum(h ? 0.0f : urn);   // each row counted once
    if (l == 0) red[wv] = su;
    __syncthreads();                       // barrier A: uhs, red[0..1]
    const float sum_u = red[0] + red[1] + u64v;
    const float v128n = 64.0f * rcpf_(ebs * sum_u);
    // v-pass: col c = 64wv + l
    float c0 = ebs * u64v, c1 = 0.f, c2 = 0.f, c3 = 0.f;
    const uint4* uh4 = reinterpret_cast<const uint4*>(uhs);
    #pragma unroll
    for (int t = 0; t < 8; ++t) {
      uint4 uu = uh4[t];
      c0 = fdot2f(kt[4 * t + 0], uu.x, c0);
      c1 = fdot2f(kt[4 * t + 1], uu.y, c1);
      c2 = fdot2f(kt[4 * t + 2], uu.z, c2);
      c3 = fdot2f(kt[4 * t + 3], uu.w, c3);
    }
    float vn = rcpf_((c0 + c1) + (c2 + c3));
    float m2 = fabsf(vn - v_old) - TOL * vn;
    v_old = vn;
    float v_nb = __shfl_xor(vn, 1);
    if (!h) vhs[(64 * wv + l) >> 1] = pk2(vn, v_nb);
    float sv = wave_sum(vn);
    int wall = __all(fmaxf(m1, m2) <= 0.0f);
    if (l == 0) { red[2 + wv] = sv; flg[wv] = wall; }
    __syncthreads();                       // barrier B: vhs, red[2..3], flg
    sum_v = red[2] + red[3] + v128n;
    v128 = v128n;
    if (flg[0] & flg[1]) break;
  }

  // ---- Phase 3: P[mrow][64h..64h+63] = K*u*v -> bf16 ----
  {
    const float ur = u_old;
    unsigned short* Pout = Pbuf + ((size_t)(s * B_ + b)) * (MM * NN);
    uint4* P4 = reinterpret_cast<uint4*>(Pout);
    const uint4* vh4 = reinterpret_cast<const uint4*>(vhs) + 8 * h;
    #pragma unroll
    for (int t = 0; t < 8; ++t) {
      uint4 vv = vh4[t];
      u32 o0 = bfpk(h_lo(kr[4 * t + 0]) * ur * h_lo(vv.x),
                    h_hi(kr[4 * t + 0]) * ur * h_hi(vv.x));
      u32 o1 = bfpk(h_lo(kr[4 * t + 1]) * ur * h_lo(vv.y),
                    h_hi(kr[4 * t + 1]) * ur * h_hi(vv.y));
      u32 o2 = bfpk(h_lo(kr[4 * t + 2]) * ur * h_lo(vv.z),
                    h_hi(kr[4 * t + 2]) * ur * h_hi(vv.z));
      u32 o3 = bfpk(h_lo(kr[4 * t + 3]) * ur * h_lo(vv.w),
                    h_hi(kr[4 * t + 3]) * ur * h_hi(vv.w));
      P4[mrow * 16 + 8 * h + t] = make_uint4(o0, o1, o2, o3);
    }
  }
}

// ---------------------------------------------------------------------------
// Kernel B (MFMA): unchanged (passed R4-R8).
// ---------------------------------------------------------------------------
#define AP 136   // bf16 row pitch (272 B, 16B aligned)

__device__ __forceinline__ bf16x8 ldfrag(const unsigned short* p) {
  return __builtin_bit_cast(bf16x8, *reinterpret_cast<const uint4*>(p));
}
__device__ __forceinline__ u32 comb2(u32 ps, u32 pf, float a, float na) {
  float r0 = a * bf2f((unsigned short)(ps & 0xffffu)) + na * bf2f((unsigned short)(pf & 0xffffu));
  float r1 = a * bf2f((unsigned short)(ps >> 16)) + na * bf2f((unsigned short)(pf >> 16));
  return (u32)f2bf(r0) | ((u32)f2bf(r1) << 16);
}

__launch_bounds__(256, 2)
__global__ void align_kernel(const unsigned short* __restrict__ Pbuf,
                             const float* __restrict__ adj,
                             const float* __restrict__ x,
                             const float* __restrict__ alpha_p,
                             const float* __restrict__ ln1g, const float* __restrict__ ln1b,
                             const float* __restrict__ ln2g, const float* __restrict__ ln2b,
                             unsigned short* __restrict__ lnadj,
                             unsigned short* __restrict__ lnfeats)
{
  __shared__ __align__(16) unsigned short adjb[128 * AP];
  __shared__ __align__(16) unsigned short Pms[64 * AP];
  __shared__ __align__(16) unsigned short Z1T[64 * AP];
  __shared__ __align__(16) unsigned short xfT[16 * AP];
  __shared__ float red[16];

  const int tid = threadIdx.x;
  const int b = blockIdx.x;
  const int w = tid >> 6;
  const int lane = tid & 63;
  const int l15 = lane & 15;
  const int q = lane >> 4;
  const float a = 1.0f / (1.0f + __expf(-alpha_p[0]));
  const float na = 1.0f - a;

  {
    const float4* src = reinterpret_cast<const float4*>(adj + (size_t)b * (NN * NN));
    for (int i = tid; i < 128 * 32; i += 256) {
      int row = i >> 5, c4 = i & 31;
      float4 v = src[i];
      u32 w0 = (u32)f2bf(v.x) | ((u32)f2bf(v.y) << 16);
      u32 w1 = (u32)f2bf(v.z) | ((u32)f2bf(v.w) << 16);
      *reinterpret_cast<uint2*>(&adjb[row * AP + c4 * 4]) = make_uint2(w0, w1);
    }
  }
  {
    const uint4* Ps4 = reinterpret_cast<const uint4*>(Pbuf + (size_t)b * (MM * NN));
    const uint4* Pf4 = reinterpret_cast<const uint4*>(Pbuf + ((size_t)B_ + b) * (MM * NN));
    for (int i = tid; i < 64 * 16; i += 256) {
      int row = i >> 4, g = i & 15;
      uint4 sa = Ps4[i];
      uint4 fa = Pf4[i];
      uint4 o;
      o.x = comb2(sa.x, fa.x, a, na); o.y = comb2(sa.y, fa.y, a, na);
      o.z = comb2(sa.z, fa.z, a, na); o.w = comb2(sa.w, fa.w, a, na);
      *reinterpret_cast<uint4*>(&Pms[row * AP + g * 8]) = o;
    }
  }
  for (int i = tid; i < 2048; i += 256) {
    int n = i & 127, f = i >> 7;
    xfT[f * AP + n] = f2bf(x[((size_t)b * NN + n) * IND + 2 + f]);
  }
  __syncthreads();

  {
    f32x4 acc[2][4];
    #pragma unroll
    for (int i = 0; i < 2; ++i)
      #pragma unroll
      for (int j = 0; j < 4; ++j) acc[i][j] = f32x4{0.f, 0.f, 0.f, 0.f};
    #pragma unroll
    for (int kt = 0; kt < 4; ++kt) {
      const int d0 = 32 * kt + 8 * q;
      bf16x8 bf[4];
      #pragma unroll
      for (int j = 0; j < 4; ++j)
        bf[j] = ldfrag(&Pms[(16 * j + l15) * AP + d0]);
      #pragma unroll
      for (int ai = 0; ai < 2; ++ai) {
        bf16x8 af = ldfrag(&adjb[(32 * w + 16 * ai + l15) * AP + d0]);
        #pragma unroll
        for (int j = 0; j < 4; ++j)
          acc[ai][j] = __builtin_amdgcn_mfma_f32_16x16x32_bf16(af, bf[j], acc[ai][j], 0, 0, 0);
      }
    }
    #pragma unroll
    for (int ai = 0; ai < 2; ++ai) {
      #pragma unroll
      for (int j = 0; j < 4; ++j) {
        const int k = 16 * j + l15;
        const int nbase = 32 * w + 16 * ai + 4 * q;
        u32 w0 = (u32)f2bf(acc[ai][j][0]) | ((u32)f2bf(acc[ai][j][1]) << 16);
        u32 w1 = (u32)f2bf(acc[ai][j][2]) | ((u32)f2bf(acc[ai][j][3]) << 16);
        *reinterpret_cast<uint2*>(&Z1T[k * AP + nbase]) = make_uint2(w0, w1);
      }
    }
  }
  __syncthreads();

  f32x4 acc2[4];
  f32x4 acc3 = f32x4{0.f, 0.f, 0.f, 0.f};
  #pragma unroll
  for (int j = 0; j < 4; ++j) acc2[j] = f32x4{0.f, 0.f, 0.f, 0.f};
  #pragma unroll
  for (int nt = 0; nt < 4; ++nt) {
    const int n0 = 32 * nt + 8 * q;
    bf16x8 af = ldfrag(&Pms[(16 * w + l15) * AP + n0]);
    #pragma unroll
    for (int j = 0; j < 4; ++j) {
      bf16x8 bv = ldfrag(&Z1T[(16 * j + l15) * AP + n0]);
      acc2[j] = __builtin_amdgcn_mfma_f32_16x16x32_bf16(af, bv, acc2[j], 0, 0, 0);
    }
    bf16x8 bx = ldfrag(&xfT[l15 * AP + n0]);
    acc3 = __builtin_amdgcn_mfma_f32_16x16x32_bf16(af, bx, acc3, 0, 0, 0);
  }

  {
    float s1 = 0.f, q1 = 0.f, s2 = 0.f, q2 = 0.f;
    #pragma unroll
    for (int j = 0; j < 4; ++j)
      #pragma unroll
      for (int r = 0; r < 4; ++r) { float v = acc2[j][r]; s1 += v; q1 += v * v; }
    #pragma unroll
    for (int r = 0; r < 4; ++r) { float v = acc3[r]; s2 += v; q2 += v * v; }
    #pragma unroll
    for (int off = 1; off < 64; off <<= 1) {
      s1 += __shfl_xor(s1, off); q1 += __shfl_xor(q1, off);
      s2 += __shfl_xor(s2, off); q2 += __shfl_xor(q2, off);
    }
    if (lane == 0) { red[w] = s1; red[4 + w] = q1; red[8 + w] = s2; red[12 + w] = q2; }
  }
  __syncthreads();
  const float S1 = red[0] + red[1] + red[2] + red[3];
  const float Q1 = red[4] + red[5] + red[6] + red[7];
  const float S2 = red[8] + red[9] + red[10] + red[11];
  const float Q2 = red[12] + red[13] + red[14] + red[15];
  const float mean1 = S1 * (1.0f / 4096.0f);
  const float rstd1 = rsqrtf(Q1 * (1.0f / 4096.0f) - mean1 * mean1 + 1e-5f);
  const float mean2 = S2 * (1.0f / 1024.0f);
  const float rstd2 = rsqrtf(Q2 * (1.0f / 1024.0f) - mean2 * mean2 + 1e-5f);

  unsigned short* ob1 = adjb;
  unsigned short* ob2 = Z1T;
  #pragma unroll
  for (int j = 0; j < 4; ++j) {
    const int k = 16 * j + l15;
    #pragma unroll
    for (int r = 0; r < 4; ++r) {
      const int m = 16 * w + 4 * q + r;
      const int pos = m * 64 + k;
      float vv = (acc2[j][r] - mean1) * rstd1 * ln1g[pos] + ln1b[pos];
      ob1[pos] = f2bf(vv);
    }
  }
  {
    const int f = l15;
    #pragma unroll
    for (int r = 0; r < 4; ++r) {
      const int m = 16 * w + 4 * q + r;
      const int pos = m * 16 + f;
      float vv = (acc3[r] - mean2) * rstd2 * ln2g[pos] + ln2b[pos];
      ob2[pos] = f2bf(vv);
    }
  }
  __syncthreads();
  {
    const uint4* sp = reinterpret_cast<const uint4*>(ob1);
    uint4* dp = reinterpret_cast<uint4*>(lnadj + (size_t)b * 4096);
    for (int i = tid; i < 512; i += 256) dp[i] = sp[i];
    if (tid < 128)
      reinterpret_cast<uint4*>(lnfeats + (size_t)b * 1024)[tid] =
          reinterpret_cast<const uint4*>(ob2)[tid];
  }
}

// ---------------------------------------------------------------------------
// Kernel C (MFMA): unchanged.
// ---------------------------------------------------------------------------
#define GP 72
__launch_bounds__(256, 2)
__global__ void gemm_mfma_kernel(const unsigned short* __restrict__ A,
                                 const float* __restrict__ W,
                                 const float* __restrict__ bias,
                                 float* __restrict__ C,
                                 int K, int ldc, int coff)
{
  __shared__ __align__(16) unsigned short At[64 * GP];
  __shared__ __align__(16) unsigned short Wt[64 * GP];
  const int tid = threadIdx.x;
  const int m0 = blockIdx.x * 64;
  const int n0 = blockIdx.y * 64;
  const int w = tid >> 6, lane = tid & 63;
  const int l15 = lane & 15, q = lane >> 4;
  const int srow = tid >> 2, sko = (tid & 3) * 16;

  f32x4 acc[4];
  #pragma unroll
  for (int j = 0; j < 4; ++j) acc[j] = f32x4{0.f, 0.f, 0.f, 0.f};

  for (int kc = 0; kc < K; kc += 64) {
    __syncthreads();
    {
      const unsigned short* ap = &A[(size_t)(m0 + srow) * K + kc + sko];
      *reinterpret_cast<uint4*>(&At[srow * GP + sko]) =
          *reinterpret_cast<const uint4*>(ap);
      *reinterpret_cast<uint4*>(&At[srow * GP + sko + 8]) =
          *reinterpret_cast<const uint4*>(ap + 8);
      const float* wp = &W[(size_t)(n0 + srow) * K + kc + sko];
      const float4 v0 = reinterpret_cast<const float4*>(wp)[0];
      const float4 v1 = reinterpret_cast<const float4*>(wp)[1];
      const float4 v2 = reinterpret_cast<const float4*>(wp)[2];
      const float4 v3 = reinterpret_cast<const float4*>(wp)[3];
      uint4 o0, o1;
      o0.x = (u32)f2bf(v0.x) | ((u32)f2bf(v0.y) << 16);
      o0.y = (u32)f2bf(v0.z) | ((u32)f2bf(v0.w) << 16);
      o0.z = (u32)f2bf(v1.x) | ((u32)f2bf(v1.y) << 16);
      o0.w = (u32)f2bf(v1.z) | ((u32)f2bf(v1.w) << 16);
      o1.x = (u32)f2bf(v2.x) | ((u32)f2bf(v2.y) << 16);
      o1.y = (u32)f2bf(v2.z) | ((u32)f2bf(v2.w) << 16);
      o1.z = (u32)f2bf(v3.x) | ((u32)f2bf(v3.y) << 16);
      o1.w = (u32)f2bf(v3.z) | ((u32)f2bf(v3.w) << 16);
      *reinterpret_cast<uint4*>(&Wt[srow * GP + sko]) = o0;
      *reinterpret_cast<uint4*>(&Wt[srow * GP + sko + 8]) = o1;
    }
    __syncthreads();
    #pragma unroll
    for (int s = 0; s < 2; ++s) {
      bf16x8 af = ldfrag(&At[(16 * w + l15) * GP + 32 * s + 8 * q]);
      #pragma unroll
      for (int j = 0; j < 4; ++j) {
        bf16x8 bf = ldfrag(&Wt[(16 * j + l15) * GP + 32 * s + 8 * q]);
        acc[j] = __builtin_amdgcn_mfma_f32_16x16x32_bf16(af, bf, acc[j], 0, 0, 0);
      }
    }
  }
  #pragma unroll
  for (int j = 0; j < 4; ++j) {
    const int col = n0 + 16 * j + l15;
    const float bb = bias[col];
    #pragma unroll
    for (int r = 0; r < 4; ++r) {
      const int m = m0 + 16 * w + 4 * q + r;
      C[(size_t)m * ldc + coff + col] = fmaxf(acc[j][r] + bb, 0.0f);
    }
  }
}

// ---------------------------------------------------------------------------
// Kernel D: unchanged (8 rows/block).
// ---------------------------------------------------------------------------
__launch_bounds__(256)
__global__ void head_kernel(const float* __restrict__ h45,
                            const float* __restrict__ wT6,   // [512][64]
                            const float* __restrict__ b6,
                            const float* __restrict__ w7,    // [10][64]
                            const float* __restrict__ b7,
                            float* __restrict__ out)
{
  __shared__ float row[8][512];
  __shared__ float h6[8][64];
  __shared__ float zb[8][12];
  const int tid = threadIdx.x;
  const int r0 = blockIdx.x * 8;
  for (int i = tid; i < 8 * 128; i += 256) {
    int r = i >> 7, c4 = i & 127;
    *reinterpret_cast<float4*>(&row[r][c4 * 4]) =
        reinterpret_cast<const float4*>(h45 + (size_t)(r0 + r) * 512)[c4];
  }
  __syncthreads();
  const int o = tid & 63, rg = tid >> 6;
  float a0 = b6[o], a1 = a0;
  #pragma unroll 8
  for (int k = 0; k < 512; ++k) {
    float wv = wT6[k * 64 + o];
    a0 += row[rg][k] * wv;
    a1 += row[rg + 4][k] * wv;
  }
  h6[rg][o] = fmaxf(a0, 0.0f);
  h6[rg + 4][o] = fmaxf(a1, 0.0f);
  __syncthreads();
  if (tid < 80) {
    int r = tid / 10, c = tid - r * 10;
    float z = b7[c];
    #pragma unroll
    for (int k = 0; k < 64; ++k) z += h6[r][k] * w7[c * 64 + k];
    zb[r][c] = z;
  }
  __syncthreads();
  if (tid < 80) {
    int r = tid / 10, c = tid - r * 10;
    float mx = zb[r][0];
    #pragma unroll
    for (int j = 1; j < 10; ++j) mx = fmaxf(mx, zb[r][j]);
    float se = 0.f;
    #pragma unroll
    for (int j = 0; j < 10; ++j) se += __expf(zb[r][j] - mx);
    out[(size_t)(r0 + r) * 10 + c] = zb[r][c] - mx - __logf(se);
  }
}

__global__ void transpose_kernel(const float* __restrict__ in, float* __restrict__ outp,
                                 int R, int Cc)
{
  int idx = blockIdx.x * blockDim.x + threadIdx.x;
  int total = R * Cc;
  for (; idx < total; idx += gridDim.x * blockDim.x) {
    int rr = idx / Cc, cc = idx - rr * Cc;
    outp[cc * R + rr] = in[idx];
  }
}

// ---------------------------------------------------------------------------
extern "C" void kernel_launch(void* const* d_in, const int* in_sizes, int n_in,
                              void* d_out, int out_size, void* d_ws, size_t ws_size,
                              hipStream_t stream)
{
  (void)in_sizes; (void)n_in; (void)out_size; (void)ws_size;
  const float* x    = (const float*)d_in[0];
  const float* adj  = (const float*)d_in[1];
  const float* w1   = (const float*)d_in[2];
  const float* w2   = (const float*)d_in[3];
  const float* alpha = (const float*)d_in[4];
  const float* bin_score = (const float*)d_in[5];
  const float* fc2w = (const float*)d_in[6];
  const float* fc2b = (const float*)d_in[7];
  const float* fc3w = (const float*)d_in[8];
  const float* fc3b = (const float*)d_in[9];
  const float* ln1g = (const float*)d_in[10];
  const float* ln1b = (const float*)d_in[11];
  const float* fc4w = (const float*)d_in[12];
  const float* fc4b = (const float*)d_in[13];
  const float* ln2g = (const float*)d_in[14];
  const float* ln2b = (const float*)d_in[15];
  const float* fc5w = (const float*)d_in[16];
  const float* fc5b = (const float*)d_in[17];
  const float* fc6w = (const float*)d_in[18];
  const float* fc6b = (const float*)d_in[19];
  const float* fc7w = (const float*)d_in[20];
  const float* fc7b = (const float*)d_in[21];
  float* out = (float*)d_out;

  char* ws = (char*)d_ws;
  unsigned short* Pbuf = (unsigned short*)ws;                       // 4096*8192 bf16 = 64 MB
  size_t off = (size_t)4096 * 8192 * 2;
  unsigned short* lnadj = (unsigned short*)(ws + off);  off += (size_t)2048 * 4096 * 2;
  unsigned short* lnfeats = (unsigned short*)(ws + off); off += (size_t)2048 * 1024 * 2;
  float* h45 = (float*)(ws + off);                      off += (size_t)2048 * 512 * 4;
  float* wT6 = (float*)(ws + off);                      off += (size_t)512 * 64 * 4;

  hipLaunchKernelGGL(ot_kernel, dim3(2048, 2), dim3(128), 0, stream,
                     x, w1, w2, fc2w, fc2b, fc3w, fc3b, bin_score, Pbuf);
  hipLaunchKernelGGL(transpose_kernel, dim3(32), dim3(256), 0, stream, fc6w, wT6, 64, 512);
  hipLaunchKernelGGL(align_kernel, dim3(2048), dim3(256), 0, stream,
                     Pbuf, adj, x, alpha, ln1g, ln1b, ln2g, ln2b, lnadj, lnfeats);
  hipLaunchKernelGGL(gemm_mfma_kernel, dim3(32, 4), dim3(256), 0, stream,
                     lnadj, fc4w, fc4b, h45, 4096, 512, 0);
  hipLaunchKernelGGL(gemm_mfma_kernel, dim3(32, 4), dim3(256), 0, stream,
                     lnfeats, fc5w, fc5b, h45, 1024, 512, 256);
  hipLaunchKernelGGL(head_kernel, dim3(256), dim3(256), 0, stream,
                     h45, wT6, fc6b, fc7w, fc7b, out);
}

// Round 10
// 250.411 us; speedup vs baseline: 1.3636x; 1.0164x over previous
//
#include <hip/hip_runtime.h>
#include <hip/hip_bf16.h>
#include <hip/hip_fp16.h>

// Problem constants
#define B_   2048
#define NN   128    // NMAX
#define MM   64     // HN
#define HD_  128
#define IND  18
#define FD_  16

typedef unsigned int u32;
typedef _Float16 h2_t __attribute__((ext_vector_type(2)));
typedef __attribute__((ext_vector_type(8))) short bf16x8;
typedef __attribute__((ext_vector_type(4))) float f32x4;

__device__ __forceinline__ float fdot2f(u32 a, u32 b, float c) {
#if defined(__has_builtin)
#if __has_builtin(__builtin_amdgcn_fdot2)
  return __builtin_amdgcn_fdot2(__builtin_bit_cast(h2_t, a),
                                __builtin_bit_cast(h2_t, b), c, false);
#else
  h2_t x = __builtin_bit_cast(h2_t, a), y = __builtin_bit_cast(h2_t, b);
  return c + (float)x[0] * (float)y[0] + (float)x[1] * (float)y[1];
#endif
#else
  h2_t x = __builtin_bit_cast(h2_t, a), y = __builtin_bit_cast(h2_t, b);
  return c + (float)x[0] * (float)y[0] + (float)x[1] * (float)y[1];
#endif
}

__device__ __forceinline__ u32 pk2(float a, float b) {
#if defined(__has_builtin)
#if __has_builtin(__builtin_amdgcn_cvt_pkrtz)
  return __builtin_bit_cast(u32, __builtin_amdgcn_cvt_pkrtz(a, b));
#else
  __half ha = __float2half_rn(a), hb = __float2half_rn(b);
  return (u32)__half_as_ushort(ha) | ((u32)__half_as_ushort(hb) << 16);
#endif
#else
  __half ha = __float2half_rn(a), hb = __float2half_rn(b);
  return (u32)__half_as_ushort(ha) | ((u32)__half_as_ushort(hb) << 16);
#endif
}

__device__ __forceinline__ float rcpf_(float x) {
#if defined(__has_builtin)
#if __has_builtin(__builtin_amdgcn_rcpf)
  return __builtin_amdgcn_rcpf(x);
#else
  return 1.0f / x;
#endif
#else
  return 1.0f / x;
#endif
}

__device__ __forceinline__ float h_lo(u32 d) {
  return __half2float(__ushort_as_half((unsigned short)(d & 0xffffu)));
}
__device__ __forceinline__ float h_hi(u32 d) {
  return __half2float(__ushort_as_half((unsigned short)(d >> 16)));
}

__device__ __forceinline__ float bf2f(unsigned short u) {
  union { float f; u32 i; } z; z.i = ((u32)u) << 16; return z.f;
}
__device__ __forceinline__ unsigned short f2bf(float f) {
  union { float fv; u32 u; } z; z.fv = f;
  u32 lsb = (z.u >> 16) & 1u;
  return (unsigned short)((z.u + 0x7fffu + lsb) >> 16);
}
__device__ __forceinline__ u32 bfpk(float a, float b) {
  return (u32)f2bf(a) | ((u32)f2bf(b) << 16);
}

// DPP full-wave sum (verified R8/R9: passed).
#if defined(__has_builtin)
#if __has_builtin(__builtin_amdgcn_update_dpp) && __has_builtin(__builtin_amdgcn_readlane)
#define HAVE_DPP 1
#endif
#endif

#ifdef HAVE_DPP
template <int CTRL>
__device__ __forceinline__ float dpp_add(float v) {
  int t = __builtin_amdgcn_update_dpp(0, (int)__builtin_bit_cast(u32, v),
                                      CTRL, 0xf, 0xf, true);
  return v + __builtin_bit_cast(float, (u32)t);
}
__device__ __forceinline__ float wave_sum(float v) {
  v = dpp_add<0x111>(v);   // row_shr:1
  v = dpp_add<0x112>(v);   // row_shr:2
  v = dpp_add<0x114>(v);   // row_shr:4
  v = dpp_add<0x118>(v);   // row_shr:8
  v = dpp_add<0x142>(v);   // row_bcast:15
  v = dpp_add<0x143>(v);   // row_bcast:31
  int r = __builtin_amdgcn_readlane((int)__builtin_bit_cast(u32, v), 63);
  return __builtin_bit_cast(float, (u32)r);
}
#else
__device__ __forceinline__ float wave_sum(float v) {
  v += __shfl_xor(v, 1);  v += __shfl_xor(v, 2);
  v += __shfl_xor(v, 4);  v += __shfl_xor(v, 8);
  v += __shfl_xor(v, 16); v += __shfl_xor(v, 32);
  return v;
}
#endif

// ---------------------------------------------------------------------------
// Kernel A (R10): ONE wave per (batch, stream) OT problem. grid (2048,2),
// block 64 — R7's proven structure (102us), with the Sinkhorn loop replaced
// by a FIXED 12-iteration loop, no convergence bookkeeping.
// Rationale: K in [1,1.5]U{e} => Hilbert contraction per sweep ~0.06 =>
// residual ~1e-14 after 12 sweeps == the reference's converged 100-iter
// fixed point. Removes the (never-firing, f16-limit-cycle) __all exit and
// all m1/m2/m3 + flag reductions. This is also the loop-vs-phase1 ablation.
// ---------------------------------------------------------------------------
__launch_bounds__(64, 2)
__global__ void ot_kernel(const float* __restrict__ x,
                          const float* __restrict__ w1,
                          const float* __restrict__ w2,
                          const float* __restrict__ fc2w, const float* __restrict__ fc2b,
                          const float* __restrict__ fc3w, const float* __restrict__ fc3b,
                          const float* __restrict__ bin_score,
                          unsigned short* __restrict__ Pbuf)
{
  __shared__ __align__(16) u32 Ksh[64 * 68];              // K f16, pitch 68 dw (136 h)
  __shared__ __align__(16) unsigned short actL[16 * 136]; // act slice bf16
  __shared__ __align__(16) u32 vhs[64];                   // v packed f16 pairs
  __shared__ __align__(16) u32 uhs[32];                   // u packed f16 pairs

  const int l = threadIdx.x;
  const int b = blockIdx.x, s = blockIdx.y;
  const int l15 = l & 15, q = l >> 4;
  const float* wm = s ? w2 : w1;
  const float* fw = s ? fc3w : fc2w;
  const float* fb = s ? fc3b : fc2b;
  unsigned short* Kshh = reinterpret_cast<unsigned short*>(Ksh);

  // ---- preload w A-frags (rows m = 16at+l15, ch-octet q within kt) ----
  uint4 wA[4][4];
  #pragma unroll
  for (int at = 0; at < 4; ++at) {
    const float* wrow = wm + (size_t)(16 * at + l15) * 128;
    #pragma unroll
    for (int kt = 0; kt < 4; ++kt) {
      float4 va = *reinterpret_cast<const float4*>(wrow + 32 * kt + 8 * q);
      float4 vb = *reinterpret_cast<const float4*>(wrow + 32 * kt + 8 * q + 4);
      wA[at][kt] = make_uint4(bfpk(va.x, va.y), bfpk(va.z, va.w),
                              bfpk(vb.x, vb.y), bfpk(vb.z, vb.w));
    }
  }
  // ---- preload fcw B-frags (col ch = 16nt+l15, ind-octet q, K=32 zero-pad) ----
  uint4 fcwB[8];
  #pragma unroll
  for (int nt = 0; nt < 8; ++nt) {
    const int ch = 16 * nt + l15;
    uint4 o = make_uint4(0u, 0u, 0u, 0u);
    if (s) {
      if (q < 2) {
        const float* fr = fw + (size_t)ch * 16 + 8 * q;
        float4 va = *reinterpret_cast<const float4*>(fr);
        float4 vb = *reinterpret_cast<const float4*>(fr + 4);
        o = make_uint4(bfpk(va.x, va.y), bfpk(va.z, va.w),
                       bfpk(vb.x, vb.y), bfpk(vb.z, vb.w));
      }
    } else {
      if (q == 0) o.x = bfpk(fw[ch * 2], fw[ch * 2 + 1]);
    }
    fcwB[nt] = o;
  }
  float bb[8];
  #pragma unroll
  for (int nt = 0; nt < 8; ++nt) bb[nt] = fb[16 * nt + l15];

  // ---- preload x A-frags (row node = 16mt+l15, ind-octet q) ----
  uint4 xa[8];
  #pragma unroll
  for (int mt = 0; mt < 8; ++mt) {
    const int node = 16 * mt + l15;
    const float* xp = x + ((size_t)b * NN + node) * IND + (s ? 2 : 0);
    uint4 o = make_uint4(0u, 0u, 0u, 0u);
    if (s) {
      if (q < 2) {
        float2 p0 = *reinterpret_cast<const float2*>(xp + 8 * q);
        float2 p1 = *reinterpret_cast<const float2*>(xp + 8 * q + 2);
        float2 p2 = *reinterpret_cast<const float2*>(xp + 8 * q + 4);
        float2 p3 = *reinterpret_cast<const float2*>(xp + 8 * q + 6);
        o = make_uint4(bfpk(p0.x, p0.y), bfpk(p1.x, p1.y),
                       bfpk(p2.x, p2.y), bfpk(p3.x, p3.y));
      }
    } else {
      if (q == 0) {
        float2 p0 = *reinterpret_cast<const float2*>(xp);
        o.x = bfpk(p0.x, p0.y);
      }
    }
    xa[mt] = o;
  }
  const float ebs = __expf(bin_score[0]);

  // ---- Phase 1: 8 slices of 16 nodes (bf16 MFMA, verified R6-R9) ----
  #pragma unroll
  for (int mt = 0; mt < 8; ++mt) {
    f32x4 acc[8];
    #pragma unroll
    for (int nt = 0; nt < 8; ++nt)
      acc[nt] = __builtin_amdgcn_mfma_f32_16x16x32_bf16(
          __builtin_bit_cast(bf16x8, xa[mt]), __builtin_bit_cast(bf16x8, fcwB[nt]),
          f32x4{0.f, 0.f, 0.f, 0.f}, 0, 0, 0);
    #pragma unroll
    for (int nt = 0; nt < 8; ++nt) {
      #pragma unroll
      for (int r = 0; r < 4; ++r) {
        float v = fmaxf(acc[nt][r] + bb[nt], 0.0f);
        actL[(4 * q + r) * 136 + 16 * nt + l15] = f2bf(v);
      }
    }
    uint4 sB[4];
    #pragma unroll
    for (int kt = 0; kt < 4; ++kt)
      sB[kt] = *reinterpret_cast<const uint4*>(&actL[l15 * 136 + 32 * kt + 8 * q]);
    #pragma unroll
    for (int at = 0; at < 4; ++at) {
      f32x4 sa = f32x4{0.f, 0.f, 0.f, 0.f};
      #pragma unroll
      for (int kt = 0; kt < 4; ++kt)
        sa = __builtin_amdgcn_mfma_f32_16x16x32_bf16(
            __builtin_bit_cast(bf16x8, wA[at][kt]), __builtin_bit_cast(bf16x8, sB[kt]),
            sa, 0, 0, 0);
      #pragma unroll
      for (int r = 0; r < 4; ++r) {
        float kv = fminf(__expf(fmaxf(sa[r], 0.0f)), 60000.0f);
        Kshh[(16 * at + 4 * q + r) * 136 + 16 * mt + l15] =
            __half_as_ushort(__float2half_rn(kv));
      }
    }
  }

  // ---- register K tiles ----
  u32 kr[64];
  #pragma unroll
  for (int t = 0; t < 16; ++t) {
    uint4 kv = *reinterpret_cast<const uint4*>(Ksh + l * 68 + 4 * t);
    kr[4 * t + 0] = kv.x; kr[4 * t + 1] = kv.y;
    kr[4 * t + 2] = kv.z; kr[4 * t + 3] = kv.w;
  }
  u32 kta[32], ktb[32];
  #pragma unroll
  for (int j = 0; j < 32; ++j) {
    u32 d0 = Ksh[(2 * j) * 68 + l];
    u32 d1 = Ksh[(2 * j + 1) * 68 + l];
    kta[j] = (d0 & 0xffffu) | (d1 << 16);
    ktb[j] = (d0 >> 16) | (d1 & 0xffff0000u);
  }

  // ---- Phase 2: FIXED 12-iteration exp-space Sinkhorn (no convergence) ----
  vhs[l] = 0x3C003C00u;
  float v128 = 1.0f, sum_v = 129.0f;
  float ur = 0.0f;

  #pragma unroll 1
  for (int it = 0; it < 12; ++it) {
    const float u64v = 128.0f * rcpf_(ebs * sum_v);
    // u-pass: row l
    float a0 = ebs * v128, a1 = 0.f, a2 = 0.f, a3 = 0.f;
    const uint4* vh4 = reinterpret_cast<const uint4*>(vhs);
    #pragma unroll
    for (int t = 0; t < 16; ++t) {
      uint4 vv = vh4[t];
      a0 = fdot2f(kr[4 * t + 0], vv.x, a0);
      a1 = fdot2f(kr[4 * t + 1], vv.y, a1);
      a2 = fdot2f(kr[4 * t + 2], vv.z, a2);
      a3 = fdot2f(kr[4 * t + 3], vv.w, a3);
    }
    float urn = rcpf_((a0 + a1) + (a2 + a3));
    ur = urn;
    float su = wave_sum(urn);
    const float sum_u = su + u64v;
    const float v128n = 64.0f * rcpf_(ebs * sum_u);
    // publish u (packed pairs)
    float upr = __shfl_xor(urn, 1);
    if (!(l & 1)) uhs[l >> 1] = pk2(urn, upr);
    // v-pass: cols 2l, 2l+1
    float c0a = ebs * u64v, c0b = 0.f, c1a = ebs * u64v, c1b = 0.f;
    const uint4* uh4 = reinterpret_cast<const uint4*>(uhs);
    #pragma unroll
    for (int t = 0; t < 8; ++t) {
      uint4 uu = uh4[t];
      c0a = fdot2f(kta[4 * t + 0], uu.x, c0a);
      c0b = fdot2f(kta[4 * t + 1], uu.y, c0b);
      c0a = fdot2f(kta[4 * t + 2], uu.z, c0a);
      c0b = fdot2f(kta[4 * t + 3], uu.w, c0b);
      c1a = fdot2f(ktb[4 * t + 0], uu.x, c1a);
      c1b = fdot2f(ktb[4 * t + 1], uu.y, c1b);
      c1a = fdot2f(ktb[4 * t + 2], uu.z, c1a);
      c1b = fdot2f(ktb[4 * t + 3], uu.w, c1b);
    }
    float v0n = rcpf_(c0a + c0b);
    float v1n = rcpf_(c1a + c1b);
    vhs[l] = pk2(v0n, v1n);
    sum_v = wave_sum(v0n + v1n) + v128n;
    v128 = v128n;
  }

  // ---- Phase 3: P[l][n] = K*u*v -> bf16 ----
  {
    unsigned short* Pout = Pbuf + ((size_t)(s * B_ + b)) * (MM * NN);
    uint4* P4 = reinterpret_cast<uint4*>(Pout);
    const uint4* vh4 = reinterpret_cast<const uint4*>(vhs);
    #pragma unroll
    for (int t = 0; t < 16; ++t) {
      uint4 vv = vh4[t];
      u32 o0 = bfpk(h_lo(kr[4 * t + 0]) * ur * h_lo(vv.x),
                    h_hi(kr[4 * t + 0]) * ur * h_hi(vv.x));
      u32 o1 = bfpk(h_lo(kr[4 * t + 1]) * ur * h_lo(vv.y),
                    h_hi(kr[4 * t + 1]) * ur * h_hi(vv.y));
      u32 o2 = bfpk(h_lo(kr[4 * t + 2]) * ur * h_lo(vv.z),
                    h_hi(kr[4 * t + 2]) * ur * h_hi(vv.z));
      u32 o3 = bfpk(h_lo(kr[4 * t + 3]) * ur * h_lo(vv.w),
                    h_hi(kr[4 * t + 3]) * ur * h_hi(vv.w));
      P4[l * 16 + t] = make_uint4(o0, o1, o2, o3);
    }
  }
}

// ---------------------------------------------------------------------------
// Kernel B (MFMA): unchanged (passed R4-R9).
// ---------------------------------------------------------------------------
#define AP 136   // bf16 row pitch (272 B, 16B aligned)

__device__ __forceinline__ bf16x8 ldfrag(const unsigned short* p) {
  return __builtin_bit_cast(bf16x8, *reinterpret_cast<const uint4*>(p));
}
__device__ __forceinline__ u32 comb2(u32 ps, u32 pf, float a, float na) {
  float r0 = a * bf2f((unsigned short)(ps & 0xffffu)) + na * bf2f((unsigned short)(pf & 0xffffu));
  float r1 = a * bf2f((unsigned short)(ps >> 16)) + na * bf2f((unsigned short)(pf >> 16));
  return (u32)f2bf(r0) | ((u32)f2bf(r1) << 16);
}

__launch_bounds__(256, 2)
__global__ void align_kernel(const unsigned short* __restrict__ Pbuf,
                             const float* __restrict__ adj,
                             const float* __restrict__ x,
                             const float* __restrict__ alpha_p,
                             const float* __restrict__ ln1g, const float* __restrict__ ln1b,
                             const float* __restrict__ ln2g, const float* __restrict__ ln2b,
                             unsigned short* __restrict__ lnadj,
                             unsigned short* __restrict__ lnfeats)
{
  __shared__ __align__(16) unsigned short adjb[128 * AP];
  __shared__ __align__(16) unsigned short Pms[64 * AP];
  __shared__ __align__(16) unsigned short Z1T[64 * AP];
  __shared__ __align__(16) unsigned short xfT[16 * AP];
  __shared__ float red[16];

  const int tid = threadIdx.x;
  const int b = blockIdx.x;
  const int w = tid >> 6;
  const int lane = tid & 63;
  const int l15 = lane & 15;
  const int q = lane >> 4;
  const float a = 1.0f / (1.0f + __expf(-alpha_p[0]));
  const float na = 1.0f - a;

  {
    const float4* src = reinterpret_cast<const float4*>(adj + (size_t)b * (NN * NN));
    for (int i = tid; i < 128 * 32; i += 256) {
      int row = i >> 5, c4 = i & 31;
      float4 v = src[i];
      u32 w0 = (u32)f2bf(v.x) | ((u32)f2bf(v.y) << 16);
      u32 w1 = (u32)f2bf(v.z) | ((u32)f2bf(v.w) << 16);
      *reinterpret_cast<uint2*>(&adjb[row * AP + c4 * 4]) = make_uint2(w0, w1);
    }
  }
  {
    const uint4* Ps4 = reinterpret_cast<const uint4*>(Pbuf + (size_t)b * (MM * NN));
    const uint4* Pf4 = reinterpret_cast<const uint4*>(Pbuf + ((size_t)B_ + b) * (MM * NN));
    for (int i = tid; i < 64 * 16; i += 256) {
      int row = i >> 4, g = i & 15;
      uint4 sa = Ps4[i];
      uint4 fa = Pf4[i];
      uint4 o;
      o.x = comb2(sa.x, fa.x, a, na); o.y = comb2(sa.y, fa.y, a, na);
      o.z = comb2(sa.z, fa.z, a, na); o.w = comb2(sa.w, fa.w, a, na);
      *reinterpret_cast<uint4*>(&Pms[row * AP + g * 8]) = o;
    }
  }
  for (int i = tid; i < 2048; i += 256) {
    int n = i & 127, f = i >> 7;
    xfT[f * AP + n] = f2bf(x[((size_t)b * NN + n) * IND + 2 + f]);
  }
  __syncthreads();

  {
    f32x4 acc[2][4];
    #pragma unroll
    for (int i = 0; i < 2; ++i)
      #pragma unroll
      for (int j = 0; j < 4; ++j) acc[i][j] = f32x4{0.f, 0.f, 0.f, 0.f};
    #pragma unroll
    for (int kt = 0; kt < 4; ++kt) {
      const int d0 = 32 * kt + 8 * q;
      bf16x8 bf[4];
      #pragma unroll
      for (int j = 0; j < 4; ++j)
        bf[j] = ldfrag(&Pms[(16 * j + l15) * AP + d0]);
      #pragma unroll
      for (int ai = 0; ai < 2; ++ai) {
        bf16x8 af = ldfrag(&adjb[(32 * w + 16 * ai + l15) * AP + d0]);
        #pragma unroll
        for (int j = 0; j < 4; ++j)
          acc[ai][j] = __builtin_amdgcn_mfma_f32_16x16x32_bf16(af, bf[j], acc[ai][j], 0, 0, 0);
      }
    }
    #pragma unroll
    for (int ai = 0; ai < 2; ++ai) {
      #pragma unroll
      for (int j = 0; j < 4; ++j) {
        const int k = 16 * j + l15;
        const int nbase = 32 * w + 16 * ai + 4 * q;
        u32 w0 = (u32)f2bf(acc[ai][j][0]) | ((u32)f2bf(acc[ai][j][1]) << 16);
        u32 w1 = (u32)f2bf(acc[ai][j][2]) | ((u32)f2bf(acc[ai][j][3]) << 16);
        *reinterpret_cast<uint2*>(&Z1T[k * AP + nbase]) = make_uint2(w0, w1);
      }
    }
  }
  __syncthreads();

  f32x4 acc2[4];
  f32x4 acc3 = f32x4{0.f, 0.f, 0.f, 0.f};
  #pragma unroll
  for (int j = 0; j < 4; ++j) acc2[j] = f32x4{0.f, 0.f, 0.f, 0.f};
  #pragma unroll
  for (int nt = 0; nt < 4; ++nt) {
    const int n0 = 32 * nt + 8 * q;
    bf16x8 af = ldfrag(&Pms[(16 * w + l15) * AP + n0]);
    #pragma unroll
    for (int j = 0; j < 4; ++j) {
      bf16x8 bv = ldfrag(&Z1T[(16 * j + l15) * AP + n0]);
      acc2[j] = __builtin_amdgcn_mfma_f32_16x16x32_bf16(af, bv, acc2[j], 0, 0, 0);
    }
    bf16x8 bx = ldfrag(&xfT[l15 * AP + n0]);
    acc3 = __builtin_amdgcn_mfma_f32_16x16x32_bf16(af, bx, acc3, 0, 0, 0);
  }

  {
    float s1 = 0.f, q1 = 0.f, s2 = 0.f, q2 = 0.f;
    #pragma unroll
    for (int j = 0; j < 4; ++j)
      #pragma unroll
      for (int r = 0; r < 4; ++r) { float v = acc2[j][r]; s1 += v; q1 += v * v; }
    #pragma unroll
    for (int r = 0; r < 4; ++r) { float v = acc3[r]; s2 += v; q2 += v * v; }
    #pragma unroll
    for (int off = 1; off < 64; off <<= 1) {
      s1 += __shfl_xor(s1, off); q1 += __shfl_xor(q1, off);
      s2 += __shfl_xor(s2, off); q2 += __shfl_xor(q2, off);
    }
    if (lane == 0) { red[w] = s1; red[4 + w] = q1; red[8 + w] = s2; red[12 + w] = q2; }
  }
  __syncthreads();
  const float S1 = red[0] + red[1] + red[2] + red[3];
  const float Q1 = red[4] + red[5] + red[6] + red[7];
  const float S2 = red[8] + red[9] + red[10] + red[11];
  const float Q2 = red[12] + red[13] + red[14] + red[15];
  const float mean1 = S1 * (1.0f / 4096.0f);
  const float rstd1 = rsqrtf(Q1 * (1.0f / 4096.0f) - mean1 * mean1 + 1e-5f);
  const float mean2 = S2 * (1.0f / 1024.0f);
  const float rstd2 = rsqrtf(Q2 * (1.0f / 1024.0f) - mean2 * mean2 + 1e-5f);

  unsigned short* ob1 = adjb;
  unsigned short* ob2 = Z1T;
  #pragma unroll
  for (int j = 0; j < 4; ++j) {
    const int k = 16 * j + l15;
    #pragma unroll
    for (int r = 0; r < 4; ++r) {
      const int m = 16 * w + 4 * q + r;
      const int pos = m * 64 + k;
      float vv = (acc2[j][r] - mean1) * rstd1 * ln1g[pos] + ln1b[pos];
      ob1[pos] = f2bf(vv);
    }
  }
  {
    const int f = l15;
    #pragma unroll
    for (int r = 0; r < 4; ++r) {
      const int m = 16 * w + 4 * q + r;
      const int pos = m * 16 + f;
      float vv = (acc3[r] - mean2) * rstd2 * ln2g[pos] + ln2b[pos];
      ob2[pos] = f2bf(vv);
    }
  }
  __syncthreads();
  {
    const uint4* sp = reinterpret_cast<const uint4*>(ob1);
    uint4* dp = reinterpret_cast<uint4*>(lnadj + (size_t)b * 4096);
    for (int i = tid; i < 512; i += 256) dp[i] = sp[i];
    if (tid < 128)
      reinterpret_cast<uint4*>(lnfeats + (size_t)b * 1024)[tid] =
          reinterpret_cast<const uint4*>(ob2)[tid];
  }
}

// ---------------------------------------------------------------------------
// Kernel C (MFMA): unchanged.
// ---------------------------------------------------------------------------
#define GP 72
__launch_bounds__(256, 2)
__global__ void gemm_mfma_kernel(const unsigned short* __restrict__ A,
                                 const float* __restrict__ W,
                                 const float* __restrict__ bias,
                                 float* __restrict__ C,
                                 int K, int ldc, int coff)
{
  __shared__ __align__(16) unsigned short At[64 * GP];
  __shared__ __align__(16) unsigned short Wt[64 * GP];
  const int tid = threadIdx.x;
  const int m0 = blockIdx.x * 64;
  const int n0 = blockIdx.y * 64;
  const int w = tid >> 6, lane = tid & 63;
  const int l15 = lane & 15, q = lane >> 4;
  const int srow = tid >> 2, sko = (tid & 3) * 16;

  f32x4 acc[4];
  #pragma unroll
  for (int j = 0; j < 4; ++j) acc[j] = f32x4{0.f, 0.f, 0.f, 0.f};

  for (int kc = 0; kc < K; kc += 64) {
    __syncthreads();
    {
      const unsigned short* ap = &A[(size_t)(m0 + srow) * K + kc + sko];
      *reinterpret_cast<uint4*>(&At[srow * GP + sko]) =
          *reinterpret_cast<const uint4*>(ap);
      *reinterpret_cast<uint4*>(&At[srow * GP + sko + 8]) =
          *reinterpret_cast<const uint4*>(ap + 8);
      const float* wp = &W[(size_t)(n0 + srow) * K + kc + sko];
      const float4 v0 = reinterpret_cast<const float4*>(wp)[0];
      const float4 v1 = reinterpret_cast<const float4*>(wp)[1];
      const float4 v2 = reinterpret_cast<const float4*>(wp)[2];
      const float4 v3 = reinterpret_cast<const float4*>(wp)[3];
      uint4 o0, o1;
      o0.x = (u32)f2bf(v0.x) | ((u32)f2bf(v0.y) << 16);
      o0.y = (u32)f2bf(v0.z) | ((u32)f2bf(v0.w) << 16);
      o0.z = (u32)f2bf(v1.x) | ((u32)f2bf(v1.y) << 16);
      o0.w = (u32)f2bf(v1.z) | ((u32)f2bf(v1.w) << 16);
      o1.x = (u32)f2bf(v2.x) | ((u32)f2bf(v2.y) << 16);
      o1.y = (u32)f2bf(v2.z) | ((u32)f2bf(v2.w) << 16);
      o1.z = (u32)f2bf(v3.x) | ((u32)f2bf(v3.y) << 16);
      o1.w = (u32)f2bf(v3.z) | ((u32)f2bf(v3.w) << 16);
      *reinterpret_cast<uint4*>(&Wt[srow * GP + sko]) = o0;
      *reinterpret_cast<uint4*>(&Wt[srow * GP + sko + 8]) = o1;
    }
    __syncthreads();
    #pragma unroll
    for (int s = 0; s < 2; ++s) {
      bf16x8 af = ldfrag(&At[(16 * w + l15) * GP + 32 * s + 8 * q]);
      #pragma unroll
      for (int j = 0; j < 4; ++j) {
        bf16x8 bf = ldfrag(&Wt[(16 * j + l15) * GP + 32 * s + 8 * q]);
        acc[j] = __builtin_amdgcn_mfma_f32_16x16x32_bf16(af, bf, acc[j], 0, 0, 0);
      }
    }
  }
  #pragma unroll
  for (int j = 0; j < 4; ++j) {
    const int col = n0 + 16 * j + l15;
    const float bb = bias[col];
    #pragma unroll
    for (int r = 0; r < 4; ++r) {
      const int m = m0 + 16 * w + 4 * q + r;
      C[(size_t)m * ldc + coff + col] = fmaxf(acc[j][r] + bb, 0.0f);
    }
  }
}

// ---------------------------------------------------------------------------
// Kernel D: unchanged (8 rows/block).
// ---------------------------------------------------------------------------
__launch_bounds__(256)
__global__ void head_kernel(const float* __restrict__ h45,
                            const float* __restrict__ wT6,   // [512][64]
                            const float* __restrict__ b6,
                            const float* __restrict__ w7,    // [10][64]
                            const float* __restrict__ b7,
                            float* __restrict__ out)
{
  __shared__ float row[8][512];
  __shared__ float h6[8][64];
  __shared__ float zb[8][12];
  const int tid = threadIdx.x;
  const int r0 = blockIdx.x * 8;
  for (int i = tid; i < 8 * 128; i += 256) {
    int r = i >> 7, c4 = i & 127;
    *reinterpret_cast<float4*>(&row[r][c4 * 4]) =
        reinterpret_cast<const float4*>(h45 + (size_t)(r0 + r) * 512)[c4];
  }
  __syncthreads();
  const int o = tid & 63, rg = tid >> 6;
  float a0 = b6[o], a1 = a0;
  #pragma unroll 8
  for (int k = 0; k < 512; ++k) {
    float wv = wT6[k * 64 + o];
    a0 += row[rg][k] * wv;
    a1 += row[rg + 4][k] * wv;
  }
  h6[rg][o] = fmaxf(a0, 0.0f);
  h6[rg + 4][o] = fmaxf(a1, 0.0f);
  __syncthreads();
  if (tid < 80) {
    int r = tid / 10, c = tid - r * 10;
    float z = b7[c];
    #pragma unroll
    for (int k = 0; k < 64; ++k) z += h6[r][k] * w7[c * 64 + k];
    zb[r][c] = z;
  }
  __syncthreads();
  if (tid < 80) {
    int r = tid / 10, c = tid - r * 10;
    float mx = zb[r][0];
    #pragma unroll
    for (int j = 1; j < 10; ++j) mx = fmaxf(mx, zb[r][j]);
    float se = 0.f;
    #pragma unroll
    for (int j = 0; j < 10; ++j) se += __expf(zb[r][j] - mx);
    out[(size_t)(r0 + r) * 10 + c] = zb[r][c] - mx - __logf(se);
  }
}

__global__ void transpose_kernel(const float* __restrict__ in, float* __restrict__ outp,
                                 int R, int Cc)
{
  int idx = blockIdx.x * blockDim.x + threadIdx.x;
  int total = R * Cc;
  for (; idx < total; idx += gridDim.x * blockDim.x) {
    int rr = idx / Cc, cc = idx - rr * Cc;
    outp[cc * R + rr] = in[idx];
  }
}

// ---------------------------------------------------------------------------
extern "C" void kernel_launch(void* const* d_in, const int* in_sizes, int n_in,
                              void* d_out, int out_size, void* d_ws, size_t ws_size,
                              hipStream_t stream)
{
  (void)in_sizes; (void)n_in; (void)out_size; (void)ws_size;
  const float* x    = (const float*)d_in[0];
  const float* adj  = (const float*)d_in[1];
  const float* w1   = (const float*)d_in[2];
  const float* w2   = (const float*)d_in[3];
  const float* alpha = (const float*)d_in[4];
  const float* bin_score = (const float*)d_in[5];
  const float* fc2w = (const float*)d_in[6];
  const float* fc2b = (const float*)d_in[7];
  const float* fc3w = (const float*)d_in[8];
  const float* fc3b = (const float*)d_in[9];
  const float* ln1g = (const float*)d_in[10];
  const float* ln1b = (const float*)d_in[11];
  const float* fc4w = (const float*)d_in[12];
  const float* fc4b = (const float*)d_in[13];
  const float* ln2g = (const float*)d_in[14];
  const float* ln2b = (const float*)d_in[15];
  const float* fc5w = (const float*)d_in[16];
  const float* fc5b = (const float*)d_in[17];
  const float* fc6w = (const float*)d_in[18];
  const float* fc6b = (const float*)d_in[19];
  const float* fc7w = (const float*)d_in[20];
  const float* fc7b = (const float*)d_in[21];
  float* out = (float*)d_out;

  char* ws = (char*)d_ws;
  unsigned short* Pbuf = (unsigned short*)ws;                       // 4096*8192 bf16 = 64 MB
  size_t off = (size_t)4096 * 8192 * 2;
  unsigned short* lnadj = (unsigned short*)(ws + off);  off += (size_t)2048 * 4096 * 2;
  unsigned short* lnfeats = (unsigned short*)(ws + off); off += (size_t)2048 * 1024 * 2;
  float* h45 = (float*)(ws + off);                      off += (size_t)2048 * 512 * 4;
  float* wT6 = (float*)(ws + off);                      off += (size_t)512 * 64 * 4;

  hipLaunchKernelGGL(ot_kernel, dim3(2048, 2), dim3(64), 0, stream,
                     x, w1, w2, fc2w, fc2b, fc3w, fc3b, bin_score, Pbuf);
  hipLaunchKernelGGL(transpose_kernel, dim3(32), dim3(256), 0, stream, fc6w, wT6, 64, 512);
  hipLaunchKernelGGL(align_kernel, dim3(2048), dim3(256), 0, stream,
                     Pbuf, adj, x, alpha, ln1g, ln1b, ln2g, ln2b, lnadj, lnfeats);
  hipLaunchKernelGGL(gemm_mfma_kernel, dim3(32, 4), dim3(256), 0, stream,
                     lnadj, fc4w, fc4b, h45, 4096, 512, 0);
  hipLaunchKernelGGL(gemm_mfma_kernel, dim3(32, 4), dim3(256), 0, stream,
                     lnfeats, fc5w, fc5b, h45, 1024, 512, 256);
  hipLaunchKernelGGL(head_kernel, dim3(256), dim3(256), 0, stream,
                     h45, wT6, fc6b, fc7w, fc7b, out);
}

// Round 11
// 247.891 us; speedup vs baseline: 1.3775x; 1.0102x over previous
//
#include <hip/hip_runtime.h>
#include <hip/hip_bf16.h>
#include <hip/hip_fp16.h>

// Problem constants
#define B_   2048
#define NN   128    // NMAX
#define MM   64     // HN
#define HD_  128
#define IND  18
#define FD_  16

typedef unsigned int u32;
typedef _Float16 h2_t __attribute__((ext_vector_type(2)));
typedef __attribute__((ext_vector_type(8))) short bf16x8;
typedef __attribute__((ext_vector_type(4))) float f32x4;

__device__ __forceinline__ float fdot2f(u32 a, u32 b, float c) {
#if defined(__has_builtin)
#if __has_builtin(__builtin_amdgcn_fdot2)
  return __builtin_amdgcn_fdot2(__builtin_bit_cast(h2_t, a),
                                __builtin_bit_cast(h2_t, b), c, false);
#else
  h2_t x = __builtin_bit_cast(h2_t, a), y = __builtin_bit_cast(h2_t, b);
  return c + (float)x[0] * (float)y[0] + (float)x[1] * (float)y[1];
#endif
#else
  h2_t x = __builtin_bit_cast(h2_t, a), y = __builtin_bit_cast(h2_t, b);
  return c + (float)x[0] * (float)y[0] + (float)x[1] * (float)y[1];
#endif
}

__device__ __forceinline__ u32 pk2(float a, float b) {
#if defined(__has_builtin)
#if __has_builtin(__builtin_amdgcn_cvt_pkrtz)
  return __builtin_bit_cast(u32, __builtin_amdgcn_cvt_pkrtz(a, b));
#else
  __half ha = __float2half_rn(a), hb = __float2half_rn(b);
  return (u32)__half_as_ushort(ha) | ((u32)__half_as_ushort(hb) << 16);
#endif
#else
  __half ha = __float2half_rn(a), hb = __float2half_rn(b);
  return (u32)__half_as_ushort(ha) | ((u32)__half_as_ushort(hb) << 16);
#endif
}

__device__ __forceinline__ float rcpf_(float x) {
#if defined(__has_builtin)
#if __has_builtin(__builtin_amdgcn_rcpf)
  return __builtin_amdgcn_rcpf(x);
#else
  return 1.0f / x;
#endif
#else
  return 1.0f / x;
#endif
}

__device__ __forceinline__ float h_lo(u32 d) {
  return __half2float(__ushort_as_half((unsigned short)(d & 0xffffu)));
}
__device__ __forceinline__ float h_hi(u32 d) {
  return __half2float(__ushort_as_half((unsigned short)(d >> 16)));
}

__device__ __forceinline__ float bf2f(unsigned short u) {
  union { float f; u32 i; } z; z.i = ((u32)u) << 16; return z.f;
}
__device__ __forceinline__ unsigned short f2bf(float f) {
  union { float fv; u32 u; } z; z.fv = f;
  u32 lsb = (z.u >> 16) & 1u;
  return (unsigned short)((z.u + 0x7fffu + lsb) >> 16);
}
__device__ __forceinline__ u32 bfpk(float a, float b) {
  return (u32)f2bf(a) | ((u32)f2bf(b) << 16);
}

// ---------------------------------------------------------------------------
// Kernel A (R11): ONE wave per (batch, stream) OT problem. grid (2048,2),
// block 64 — EXACTLY R7's proven structure (102us), with the Sinkhorn loop
// changed to FIXED 8 iterations (the point where R7's adaptive exit fired;
// Hilbert contraction kappa~0.06 => residual ~1e-10), shfl_xor butterflies
// kept, all convergence bookkeeping (m1/m2/m3 + max-reduce + break) removed.
// Single-variable change vs R7; A/B vs R10 isolates iter-count+reduce-style.
// ---------------------------------------------------------------------------
__launch_bounds__(64, 2)
__global__ void ot_kernel(const float* __restrict__ x,
                          const float* __restrict__ w1,
                          const float* __restrict__ w2,
                          const float* __restrict__ fc2w, const float* __restrict__ fc2b,
                          const float* __restrict__ fc3w, const float* __restrict__ fc3b,
                          const float* __restrict__ bin_score,
                          unsigned short* __restrict__ Pbuf)
{
  __shared__ __align__(16) u32 Ksh[64 * 68];              // K f16, pitch 68 dw (136 h)
  __shared__ __align__(16) unsigned short actL[16 * 136]; // act slice bf16
  __shared__ __align__(16) u32 vhs[64];                   // v packed f16 pairs
  __shared__ __align__(16) u32 uhs[32];                   // u packed f16 pairs

  const int l = threadIdx.x;
  const int b = blockIdx.x, s = blockIdx.y;
  const int l15 = l & 15, q = l >> 4;
  const float* wm = s ? w2 : w1;
  const float* fw = s ? fc3w : fc2w;
  const float* fb = s ? fc3b : fc2b;
  unsigned short* Kshh = reinterpret_cast<unsigned short*>(Ksh);

  // ---- preload w A-frags (rows m = 16at+l15, ch-octet q within kt) ----
  uint4 wA[4][4];
  #pragma unroll
  for (int at = 0; at < 4; ++at) {
    const float* wrow = wm + (size_t)(16 * at + l15) * 128;
    #pragma unroll
    for (int kt = 0; kt < 4; ++kt) {
      float4 va = *reinterpret_cast<const float4*>(wrow + 32 * kt + 8 * q);
      float4 vb = *reinterpret_cast<const float4*>(wrow + 32 * kt + 8 * q + 4);
      wA[at][kt] = make_uint4(bfpk(va.x, va.y), bfpk(va.z, va.w),
                              bfpk(vb.x, vb.y), bfpk(vb.z, vb.w));
    }
  }
  // ---- preload fcw B-frags (col ch = 16nt+l15, ind-octet q, K=32 zero-pad) ----
  uint4 fcwB[8];
  #pragma unroll
  for (int nt = 0; nt < 8; ++nt) {
    const int ch = 16 * nt + l15;
    uint4 o = make_uint4(0u, 0u, 0u, 0u);
    if (s) {
      if (q < 2) {
        const float* fr = fw + (size_t)ch * 16 + 8 * q;
        float4 va = *reinterpret_cast<const float4*>(fr);
        float4 vb = *reinterpret_cast<const float4*>(fr + 4);
        o = make_uint4(bfpk(va.x, va.y), bfpk(va.z, va.w),
                       bfpk(vb.x, vb.y), bfpk(vb.z, vb.w));
      }
    } else {
      if (q == 0) o.x = bfpk(fw[ch * 2], fw[ch * 2 + 1]);
    }
    fcwB[nt] = o;
  }
  float bb[8];
  #pragma unroll
  for (int nt = 0; nt < 8; ++nt) bb[nt] = fb[16 * nt + l15];

  // ---- preload x A-frags (row node = 16mt+l15, ind-octet q) ----
  uint4 xa[8];
  #pragma unroll
  for (int mt = 0; mt < 8; ++mt) {
    const int node = 16 * mt + l15;
    const float* xp = x + ((size_t)b * NN + node) * IND + (s ? 2 : 0);
    uint4 o = make_uint4(0u, 0u, 0u, 0u);
    if (s) {
      if (q < 2) {
        float2 p0 = *reinterpret_cast<const float2*>(xp + 8 * q);
        float2 p1 = *reinterpret_cast<const float2*>(xp + 8 * q + 2);
        float2 p2 = *reinterpret_cast<const float2*>(xp + 8 * q + 4);
        float2 p3 = *reinterpret_cast<const float2*>(xp + 8 * q + 6);
        o = make_uint4(bfpk(p0.x, p0.y), bfpk(p1.x, p1.y),
                       bfpk(p2.x, p2.y), bfpk(p3.x, p3.y));
      }
    } else {
      if (q == 0) {
        float2 p0 = *reinterpret_cast<const float2*>(xp);
        o.x = bfpk(p0.x, p0.y);
      }
    }
    xa[mt] = o;
  }
  const float ebs = __expf(bin_score[0]);

  // ---- Phase 1: 8 slices of 16 nodes (bf16 MFMA, verified R6-R10) ----
  #pragma unroll
  for (int mt = 0; mt < 8; ++mt) {
    f32x4 acc[8];
    #pragma unroll
    for (int nt = 0; nt < 8; ++nt)
      acc[nt] = __builtin_amdgcn_mfma_f32_16x16x32_bf16(
          __builtin_bit_cast(bf16x8, xa[mt]), __builtin_bit_cast(bf16x8, fcwB[nt]),
          f32x4{0.f, 0.f, 0.f, 0.f}, 0, 0, 0);
    #pragma unroll
    for (int nt = 0; nt < 8; ++nt) {
      #pragma unroll
      for (int r = 0; r < 4; ++r) {
        float v = fmaxf(acc[nt][r] + bb[nt], 0.0f);
        actL[(4 * q + r) * 136 + 16 * nt + l15] = f2bf(v);
      }
    }
    uint4 sB[4];
    #pragma unroll
    for (int kt = 0; kt < 4; ++kt)
      sB[kt] = *reinterpret_cast<const uint4*>(&actL[l15 * 136 + 32 * kt + 8 * q]);
    #pragma unroll
    for (int at = 0; at < 4; ++at) {
      f32x4 sa = f32x4{0.f, 0.f, 0.f, 0.f};
      #pragma unroll
      for (int kt = 0; kt < 4; ++kt)
        sa = __builtin_amdgcn_mfma_f32_16x16x32_bf16(
            __builtin_bit_cast(bf16x8, wA[at][kt]), __builtin_bit_cast(bf16x8, sB[kt]),
            sa, 0, 0, 0);
      #pragma unroll
      for (int r = 0; r < 4; ++r) {
        float kv = fminf(__expf(fmaxf(sa[r], 0.0f)), 60000.0f);
        Kshh[(16 * at + 4 * q + r) * 136 + 16 * mt + l15] =
            __half_as_ushort(__float2half_rn(kv));
      }
    }
  }

  // ---- register K tiles ----
  u32 kr[64];
  #pragma unroll
  for (int t = 0; t < 16; ++t) {
    uint4 kv = *reinterpret_cast<const uint4*>(Ksh + l * 68 + 4 * t);
    kr[4 * t + 0] = kv.x; kr[4 * t + 1] = kv.y;
    kr[4 * t + 2] = kv.z; kr[4 * t + 3] = kv.w;
  }
  u32 kta[32], ktb[32];
  #pragma unroll
  for (int j = 0; j < 32; ++j) {
    u32 d0 = Ksh[(2 * j) * 68 + l];
    u32 d1 = Ksh[(2 * j + 1) * 68 + l];
    kta[j] = (d0 & 0xffffu) | (d1 << 16);
    ktb[j] = (d0 >> 16) | (d1 & 0xffff0000u);
  }

  // ---- Phase 2: FIXED 8-iteration exp-space Sinkhorn (shfl butterflies) ----
  vhs[l] = 0x3C003C00u;
  float v128 = 1.0f, sum_v = 129.0f;
  float ur = 0.0f;

  #pragma unroll 1
  for (int it = 0; it < 8; ++it) {
    const float u64v = 128.0f * rcpf_(ebs * sum_v);
    // u-pass: row l
    float a0 = ebs * v128, a1 = 0.f, a2 = 0.f, a3 = 0.f;
    const uint4* vh4 = reinterpret_cast<const uint4*>(vhs);
    #pragma unroll
    for (int t = 0; t < 16; ++t) {
      uint4 vv = vh4[t];
      a0 = fdot2f(kr[4 * t + 0], vv.x, a0);
      a1 = fdot2f(kr[4 * t + 1], vv.y, a1);
      a2 = fdot2f(kr[4 * t + 2], vv.z, a2);
      a3 = fdot2f(kr[4 * t + 3], vv.w, a3);
    }
    float urn = rcpf_((a0 + a1) + (a2 + a3));
    ur = urn;
    float su = urn;
    su += __shfl_xor(su, 1);  su += __shfl_xor(su, 2);
    su += __shfl_xor(su, 4);  su += __shfl_xor(su, 8);
    su += __shfl_xor(su, 16); su += __shfl_xor(su, 32);
    const float sum_u = su + u64v;
    const float v128n = 64.0f * rcpf_(ebs * sum_u);
    // publish u (packed pairs)
    float upr = __shfl_xor(urn, 1);
    if (!(l & 1)) uhs[l >> 1] = pk2(urn, upr);
    // v-pass: cols 2l, 2l+1
    float c0a = ebs * u64v, c0b = 0.f, c1a = ebs * u64v, c1b = 0.f;
    const uint4* uh4 = reinterpret_cast<const uint4*>(uhs);
    #pragma unroll
    for (int t = 0; t < 8; ++t) {
      uint4 uu = uh4[t];
      c0a = fdot2f(kta[4 * t + 0], uu.x, c0a);
      c0b = fdot2f(kta[4 * t + 1], uu.y, c0b);
      c0a = fdot2f(kta[4 * t + 2], uu.z, c0a);
      c0b = fdot2f(kta[4 * t + 3], uu.w, c0b);
      c1a = fdot2f(ktb[4 * t + 0], uu.x, c1a);
      c1b = fdot2f(ktb[4 * t + 1], uu.y, c1b);
      c1a = fdot2f(ktb[4 * t + 2], uu.z, c1a);
      c1b = fdot2f(ktb[4 * t + 3], uu.w, c1b);
    }
    float v0n = rcpf_(c0a + c0b);
    float v1n = rcpf_(c1a + c1b);
    vhs[l] = pk2(v0n, v1n);
    float sv = v0n + v1n;
    sv += __shfl_xor(sv, 1);  sv += __shfl_xor(sv, 2);
    sv += __shfl_xor(sv, 4);  sv += __shfl_xor(sv, 8);
    sv += __shfl_xor(sv, 16); sv += __shfl_xor(sv, 32);
    sum_v = sv + v128n;
    v128 = v128n;
  }

  // ---- Phase 3: P[l][n] = K*u*v -> bf16 ----
  {
    unsigned short* Pout = Pbuf + ((size_t)(s * B_ + b)) * (MM * NN);
    uint4* P4 = reinterpret_cast<uint4*>(Pout);
    const uint4* vh4 = reinterpret_cast<const uint4*>(vhs);
    #pragma unroll
    for (int t = 0; t < 16; ++t) {
      uint4 vv = vh4[t];
      u32 o0 = bfpk(h_lo(kr[4 * t + 0]) * ur * h_lo(vv.x),
                    h_hi(kr[4 * t + 0]) * ur * h_hi(vv.x));
      u32 o1 = bfpk(h_lo(kr[4 * t + 1]) * ur * h_lo(vv.y),
                    h_hi(kr[4 * t + 1]) * ur * h_hi(vv.y));
      u32 o2 = bfpk(h_lo(kr[4 * t + 2]) * ur * h_lo(vv.z),
                    h_hi(kr[4 * t + 2]) * ur * h_hi(vv.z));
      u32 o3 = bfpk(h_lo(kr[4 * t + 3]) * ur * h_lo(vv.w),
                    h_hi(kr[4 * t + 3]) * ur * h_hi(vv.w));
      P4[l * 16 + t] = make_uint4(o0, o1, o2, o3);
    }
  }
}

// ---------------------------------------------------------------------------
// Kernel B (MFMA): unchanged (passed R4-R10).
// ---------------------------------------------------------------------------
#define AP 136   // bf16 row pitch (272 B, 16B aligned)

__device__ __forceinline__ bf16x8 ldfrag(const unsigned short* p) {
  return __builtin_bit_cast(bf16x8, *reinterpret_cast<const uint4*>(p));
}
__device__ __forceinline__ u32 comb2(u32 ps, u32 pf, float a, float na) {
  float r0 = a * bf2f((unsigned short)(ps & 0xffffu)) + na * bf2f((unsigned short)(pf & 0xffffu));
  float r1 = a * bf2f((unsigned short)(ps >> 16)) + na * bf2f((unsigned short)(pf >> 16));
  return (u32)f2bf(r0) | ((u32)f2bf(r1) << 16);
}

__launch_bounds__(256, 2)
__global__ void align_kernel(const unsigned short* __restrict__ Pbuf,
                             const float* __restrict__ adj,
                             const float* __restrict__ x,
                             const float* __restrict__ alpha_p,
                             const float* __restrict__ ln1g, const float* __restrict__ ln1b,
                             const float* __restrict__ ln2g, const float* __restrict__ ln2b,
                             unsigned short* __restrict__ lnadj,
                             unsigned short* __restrict__ lnfeats)
{
  __shared__ __align__(16) unsigned short adjb[128 * AP];
  __shared__ __align__(16) unsigned short Pms[64 * AP];
  __shared__ __align__(16) unsigned short Z1T[64 * AP];
  __shared__ __align__(16) unsigned short xfT[16 * AP];
  __shared__ float red[16];

  const int tid = threadIdx.x;
  const int b = blockIdx.x;
  const int w = tid >> 6;
  const int lane = tid & 63;
  const int l15 = lane & 15;
  const int q = lane >> 4;
  const float a = 1.0f / (1.0f + __expf(-alpha_p[0]));
  const float na = 1.0f - a;

  {
    const float4* src = reinterpret_cast<const float4*>(adj + (size_t)b * (NN * NN));
    for (int i = tid; i < 128 * 32; i += 256) {
      int row = i >> 5, c4 = i & 31;
      float4 v = src[i];
      u32 w0 = (u32)f2bf(v.x) | ((u32)f2bf(v.y) << 16);
      u32 w1 = (u32)f2bf(v.z) | ((u32)f2bf(v.w) << 16);
      *reinterpret_cast<uint2*>(&adjb[row * AP + c4 * 4]) = make_uint2(w0, w1);
    }
  }
  {
    const uint4* Ps4 = reinterpret_cast<const uint4*>(Pbuf + (size_t)b * (MM * NN));
    const uint4* Pf4 = reinterpret_cast<const uint4*>(Pbuf + ((size_t)B_ + b) * (MM * NN));
    for (int i = tid; i < 64 * 16; i += 256) {
      int row = i >> 4, g = i & 15;
      uint4 sa = Ps4[i];
      uint4 fa = Pf4[i];
      uint4 o;
      o.x = comb2(sa.x, fa.x, a, na); o.y = comb2(sa.y, fa.y, a, na);
      o.z = comb2(sa.z, fa.z, a, na); o.w = comb2(sa.w, fa.w, a, na);
      *reinterpret_cast<uint4*>(&Pms[row * AP + g * 8]) = o;
    }
  }
  for (int i = tid; i < 2048; i += 256) {
    int n = i & 127, f = i >> 7;
    xfT[f * AP + n] = f2bf(x[((size_t)b * NN + n) * IND + 2 + f]);
  }
  __syncthreads();

  {
    f32x4 acc[2][4];
    #pragma unroll
    for (int i = 0; i < 2; ++i)
      #pragma unroll
      for (int j = 0; j < 4; ++j) acc[i][j] = f32x4{0.f, 0.f, 0.f, 0.f};
    #pragma unroll
    for (int kt = 0; kt < 4; ++kt) {
      const int d0 = 32 * kt + 8 * q;
      bf16x8 bf[4];
      #pragma unroll
      for (int j = 0; j < 4; ++j)
        bf[j] = ldfrag(&Pms[(16 * j + l15) * AP + d0]);
      #pragma unroll
      for (int ai = 0; ai < 2; ++ai) {
        bf16x8 af = ldfrag(&adjb[(32 * w + 16 * ai + l15) * AP + d0]);
        #pragma unroll
        for (int j = 0; j < 4; ++j)
          acc[ai][j] = __builtin_amdgcn_mfma_f32_16x16x32_bf16(af, bf[j], acc[ai][j], 0, 0, 0);
      }
    }
    #pragma unroll
    for (int ai = 0; ai < 2; ++ai) {
      #pragma unroll
      for (int j = 0; j < 4; ++j) {
        const int k = 16 * j + l15;
        const int nbase = 32 * w + 16 * ai + 4 * q;
        u32 w0 = (u32)f2bf(acc[ai][j][0]) | ((u32)f2bf(acc[ai][j][1]) << 16);
        u32 w1 = (u32)f2bf(acc[ai][j][2]) | ((u32)f2bf(acc[ai][j][3]) << 16);
        *reinterpret_cast<uint2*>(&Z1T[k * AP + nbase]) = make_uint2(w0, w1);
      }
    }
  }
  __syncthreads();

  f32x4 acc2[4];
  f32x4 acc3 = f32x4{0.f, 0.f, 0.f, 0.f};
  #pragma unroll
  for (int j = 0; j < 4; ++j) acc2[j] = f32x4{0.f, 0.f, 0.f, 0.f};
  #pragma unroll
  for (int nt = 0; nt < 4; ++nt) {
    const int n0 = 32 * nt + 8 * q;
    bf16x8 af = ldfrag(&Pms[(16 * w + l15) * AP + n0]);
    #pragma unroll
    for (int j = 0; j < 4; ++j) {
      bf16x8 bv = ldfrag(&Z1T[(16 * j + l15) * AP + n0]);
      acc2[j] = __builtin_amdgcn_mfma_f32_16x16x32_bf16(af, bv, acc2[j], 0, 0, 0);
    }
    bf16x8 bx = ldfrag(&xfT[l15 * AP + n0]);
    acc3 = __builtin_amdgcn_mfma_f32_16x16x32_bf16(af, bx, acc3, 0, 0, 0);
  }

  {
    float s1 = 0.f, q1 = 0.f, s2 = 0.f, q2 = 0.f;
    #pragma unroll
    for (int j = 0; j < 4; ++j)
      #pragma unroll
      for (int r = 0; r < 4; ++r) { float v = acc2[j][r]; s1 += v; q1 += v * v; }
    #pragma unroll
    for (int r = 0; r < 4; ++r) { float v = acc3[r]; s2 += v; q2 += v * v; }
    #pragma unroll
    for (int off = 1; off < 64; off <<= 1) {
      s1 += __shfl_xor(s1, off); q1 += __shfl_xor(q1, off);
      s2 += __shfl_xor(s2, off); q2 += __shfl_xor(q2, off);
    }
    if (lane == 0) { red[w] = s1; red[4 + w] = q1; red[8 + w] = s2; red[12 + w] = q2; }
  }
  __syncthreads();
  const float S1 = red[0] + red[1] + red[2] + red[3];
  const float Q1 = red[4] + red[5] + red[6] + red[7];
  const float S2 = red[8] + red[9] + red[10] + red[11];
  const float Q2 = red[12] + red[13] + red[14] + red[15];
  const float mean1 = S1 * (1.0f / 4096.0f);
  const float rstd1 = rsqrtf(Q1 * (1.0f / 4096.0f) - mean1 * mean1 + 1e-5f);
  const float mean2 = S2 * (1.0f / 1024.0f);
  const float rstd2 = rsqrtf(Q2 * (1.0f / 1024.0f) - mean2 * mean2 + 1e-5f);

  unsigned short* ob1 = adjb;
  unsigned short* ob2 = Z1T;
  #pragma unroll
  for (int j = 0; j < 4; ++j) {
    const int k = 16 * j + l15;
    #pragma unroll
    for (int r = 0; r < 4; ++r) {
      const int m = 16 * w + 4 * q + r;
      const int pos = m * 64 + k;
      float vv = (acc2[j][r] - mean1) * rstd1 * ln1g[pos] + ln1b[pos];
      ob1[pos] = f2bf(vv);
    }
  }
  {
    const int f = l15;
    #pragma unroll
    for (int r = 0; r < 4; ++r) {
      const int m = 16 * w + 4 * q + r;
      const int pos = m * 16 + f;
      float vv = (acc3[r] - mean2) * rstd2 * ln2g[pos] + ln2b[pos];
      ob2[pos] = f2bf(vv);
    }
  }
  __syncthreads();
  {
    const uint4* sp = reinterpret_cast<const uint4*>(ob1);
    uint4* dp = reinterpret_cast<uint4*>(lnadj + (size_t)b * 4096);
    for (int i = tid; i < 512; i += 256) dp[i] = sp[i];
    if (tid < 128)
      reinterpret_cast<uint4*>(lnfeats + (size_t)b * 1024)[tid] =
          reinterpret_cast<const uint4*>(ob2)[tid];
  }
}

// ---------------------------------------------------------------------------
// Kernel C (MFMA): unchanged.
// ---------------------------------------------------------------------------
#define GP 72
__launch_bounds__(256, 2)
__global__ void gemm_mfma_kernel(const unsigned short* __restrict__ A,
                                 const float* __restrict__ W,
                                 const float* __restrict__ bias,
                                 float* __restrict__ C,
                                 int K, int ldc, int coff)
{
  __shared__ __align__(16) unsigned short At[64 * GP];
  __shared__ __align__(16) unsigned short Wt[64 * GP];
  const int tid = threadIdx.x;
  const int m0 = blockIdx.x * 64;
  const int n0 = blockIdx.y * 64;
  const int w = tid >> 6, lane = tid & 63;
  const int l15 = lane & 15, q = lane >> 4;
  const int srow = tid >> 2, sko = (tid & 3) * 16;

  f32x4 acc[4];
  #pragma unroll
  for (int j = 0; j < 4; ++j) acc[j] = f32x4{0.f, 0.f, 0.f, 0.f};

  for (int kc = 0; kc < K; kc += 64) {
    __syncthreads();
    {
      const unsigned short* ap = &A[(size_t)(m0 + srow) * K + kc + sko];
      *reinterpret_cast<uint4*>(&At[srow * GP + sko]) =
          *reinterpret_cast<const uint4*>(ap);
      *reinterpret_cast<uint4*>(&At[srow * GP + sko + 8]) =
          *reinterpret_cast<const uint4*>(ap + 8);
      const float* wp = &W[(size_t)(n0 + srow) * K + kc + sko];
      const float4 v0 = reinterpret_cast<const float4*>(wp)[0];
      const float4 v1 = reinterpret_cast<const float4*>(wp)[1];
      const float4 v2 = reinterpret_cast<const float4*>(wp)[2];
      const float4 v3 = reinterpret_cast<const float4*>(wp)[3];
      uint4 o0, o1;
      o0.x = (u32)f2bf(v0.x) | ((u32)f2bf(v0.y) << 16);
      o0.y = (u32)f2bf(v0.z) | ((u32)f2bf(v0.w) << 16);
      o0.z = (u32)f2bf(v1.x) | ((u32)f2bf(v1.y) << 16);
      o0.w = (u32)f2bf(v1.z) | ((u32)f2bf(v1.w) << 16);
      o1.x = (u32)f2bf(v2.x) | ((u32)f2bf(v2.y) << 16);
      o1.y = (u32)f2bf(v2.z) | ((u32)f2bf(v2.w) << 16);
      o1.z = (u32)f2bf(v3.x) | ((u32)f2bf(v3.y) << 16);
      o1.w = (u32)f2bf(v3.z) | ((u32)f2bf(v3.w) << 16);
      *reinterpret_cast<uint4*>(&Wt[srow * GP + sko]) = o0;
      *reinterpret_cast<uint4*>(&Wt[srow * GP + sko + 8]) = o1;
    }
    __syncthreads();
    #pragma unroll
    for (int s = 0; s < 2; ++s) {
      bf16x8 af = ldfrag(&At[(16 * w + l15) * GP + 32 * s + 8 * q]);
      #pragma unroll
      for (int j = 0; j < 4; ++j) {
        bf16x8 bf = ldfrag(&Wt[(16 * j + l15) * GP + 32 * s + 8 * q]);
        acc[j] = __builtin_amdgcn_mfma_f32_16x16x32_bf16(af, bf, acc[j], 0, 0, 0);
      }
    }
  }
  #pragma unroll
  for (int j = 0; j < 4; ++j) {
    const int col = n0 + 16 * j + l15;
    const float bb = bias[col];
    #pragma unroll
    for (int r = 0; r < 4; ++r) {
      const int m = m0 + 16 * w + 4 * q + r;
      C[(size_t)m * ldc + coff + col] = fmaxf(acc[j][r] + bb, 0.0f);
    }
  }
}

// ---------------------------------------------------------------------------
// Kernel D: unchanged (8 rows/block).
// ---------------------------------------------------------------------------
__launch_bounds__(256)
__global__ void head_kernel(const float* __restrict__ h45,
                            const float* __restrict__ wT6,   // [512][64]
                            const float* __restrict__ b6,
                            const float* __restrict__ w7,    // [10][64]
                            const float* __restrict__ b7,
                            float* __restrict__ out)
{
  __shared__ float row[8][512];
  __shared__ float h6[8][64];
  __shared__ float zb[8][12];
  const int tid = threadIdx.x;
  const int r0 = blockIdx.x * 8;
  for (int i = tid; i < 8 * 128; i += 256) {
    int r = i >> 7, c4 = i & 127;
    *reinterpret_cast<float4*>(&row[r][c4 * 4]) =
        reinterpret_cast<const float4*>(h45 + (size_t)(r0 + r) * 512)[c4];
  }
  __syncthreads();
  const int o = tid & 63, rg = tid >> 6;
  float a0 = b6[o], a1 = a0;
  #pragma unroll 8
  for (int k = 0; k < 512; ++k) {
    float wv = wT6[k * 64 + o];
    a0 += row[rg][k] * wv;
    a1 += row[rg + 4][k] * wv;
  }
  h6[rg][o] = fmaxf(a0, 0.0f);
  h6[rg + 4][o] = fmaxf(a1, 0.0f);
  __syncthreads();
  if (tid < 80) {
    int r = tid / 10, c = tid - r * 10;
    float z = b7[c];
    #pragma unroll
    for (int k = 0; k < 64; ++k) z += h6[r][k] * w7[c * 64 + k];
    zb[r][c] = z;
  }
  __syncthreads();
  if (tid < 80) {
    int r = tid / 10, c = tid - r * 10;
    float mx = zb[r][0];
    #pragma unroll
    for (int j = 1; j < 10; ++j) mx = fmaxf(mx, zb[r][j]);
    float se = 0.f;
    #pragma unroll
    for (int j = 0; j < 10; ++j) se += __expf(zb[r][j] - mx);
    out[(size_t)(r0 + r) * 10 + c] = zb[r][c] - mx - __logf(se);
  }
}

__global__ void transpose_kernel(const float* __restrict__ in, float* __restrict__ outp,
                                 int R, int Cc)
{
  int idx = blockIdx.x * blockDim.x + threadIdx.x;
  int total = R * Cc;
  for (; idx < total; idx += gridDim.x * blockDim.x) {
    int rr = idx / Cc, cc = idx - rr * Cc;
    outp[cc * R + rr] = in[idx];
  }
}

// ---------------------------------------------------------------------------
extern "C" void kernel_launch(void* const* d_in, const int* in_sizes, int n_in,
                              void* d_out, int out_size, void* d_ws, size_t ws_size,
                              hipStream_t stream)
{
  (void)in_sizes; (void)n_in; (void)out_size; (void)ws_size;
  const float* x    = (const float*)d_in[0];
  const float* adj  = (const float*)d_in[1];
  const float* w1   = (const float*)d_in[2];
  const float* w2   = (const float*)d_in[3];
  const float* alpha = (const float*)d_in[4];
  const float* bin_score = (const float*)d_in[5];
  const float* fc2w = (const float*)d_in[6];
  const float* fc2b = (const float*)d_in[7];
  const float* fc3w = (const float*)d_in[8];
  const float* fc3b = (const float*)d_in[9];
  const float* ln1g = (const float*)d_in[10];
  const float* ln1b = (const float*)d_in[11];
  const float* fc4w = (const float*)d_in[12];
  const float* fc4b = (const float*)d_in[13];
  const float* ln2g = (const float*)d_in[14];
  const float* ln2b = (const float*)d_in[15];
  const float* fc5w = (const float*)d_in[16];
  const float* fc5b = (const float*)d_in[17];
  const float* fc6w = (const float*)d_in[18];
  const float* fc6b = (const float*)d_in[19];
  const float* fc7w = (const float*)d_in[20];
  const float* fc7b = (const float*)d_in[21];
  float* out = (float*)d_out;

  char* ws = (char*)d_ws;
  unsigned short* Pbuf = (unsigned short*)ws;                       // 4096*8192 bf16 = 64 MB
  size_t off = (size_t)4096 * 8192 * 2;
  unsigned short* lnadj = (unsigned short*)(ws + off);  off += (size_t)2048 * 4096 * 2;
  unsigned short* lnfeats = (unsigned short*)(ws + off); off += (size_t)2048 * 1024 * 2;
  float* h45 = (float*)(ws + off);                      off += (size_t)2048 * 512 * 4;
  float* wT6 = (float*)(ws + off);                      off += (size_t)512 * 64 * 4;

  hipLaunchKernelGGL(ot_kernel, dim3(2048, 2), dim3(64), 0, stream,
                     x, w1, w2, fc2w, fc2b, fc3w, fc3b, bin_score, Pbuf);
  hipLaunchKernelGGL(transpose_kernel, dim3(32), dim3(256), 0, stream, fc6w, wT6, 64, 512);
  hipLaunchKernelGGL(align_kernel, dim3(2048), dim3(256), 0, stream,
                     Pbuf, adj, x, alpha, ln1g, ln1b, ln2g, ln2b, lnadj, lnfeats);
  hipLaunchKernelGGL(gemm_mfma_kernel, dim3(32, 4), dim3(256), 0, stream,
                     lnadj, fc4w, fc4b, h45, 4096, 512, 0);
  hipLaunchKernelGGL(gemm_mfma_kernel, dim3(32, 4), dim3(256), 0, stream,
                     lnfeats, fc5w, fc5b, h45, 1024, 512, 256);
  hipLaunchKernelGGL(head_kernel, dim3(256), dim3(256), 0, stream,
                     h45, wT6, fc6b, fc7w, fc7b, out);
}

// Round 12
// 240.137 us; speedup vs baseline: 1.4220x; 1.0323x over previous
//
#include <hip/hip_runtime.h>
#include <hip/hip_bf16.h>
#include <hip/hip_fp16.h>

// Problem constants
#define B_   2048
#define NN   128    // NMAX
#define MM   64     // HN
#define HD_  128
#define IND  18
#define FD_  16

typedef unsigned int u32;
typedef _Float16 h2_t __attribute__((ext_vector_type(2)));
typedef __attribute__((ext_vector_type(8))) short bf16x8;
typedef __attribute__((ext_vector_type(4))) float f32x4;

__device__ __forceinline__ float fdot2f(u32 a, u32 b, float c) {
#if defined(__has_builtin)
#if __has_builtin(__builtin_amdgcn_fdot2)
  return __builtin_amdgcn_fdot2(__builtin_bit_cast(h2_t, a),
                                __builtin_bit_cast(h2_t, b), c, false);
#else
  h2_t x = __builtin_bit_cast(h2_t, a), y = __builtin_bit_cast(h2_t, b);
  return c + (float)x[0] * (float)y[0] + (float)x[1] * (float)y[1];
#endif
#else
  h2_t x = __builtin_bit_cast(h2_t, a), y = __builtin_bit_cast(h2_t, b);
  return c + (float)x[0] * (float)y[0] + (float)x[1] * (float)y[1];
#endif
}

__device__ __forceinline__ u32 pk2(float a, float b) {
#if defined(__has_builtin)
#if __has_builtin(__builtin_amdgcn_cvt_pkrtz)
  return __builtin_bit_cast(u32, __builtin_amdgcn_cvt_pkrtz(a, b));
#else
  __half ha = __float2half_rn(a), hb = __float2half_rn(b);
  return (u32)__half_as_ushort(ha) | ((u32)__half_as_ushort(hb) << 16);
#endif
#else
  __half ha = __float2half_rn(a), hb = __float2half_rn(b);
  return (u32)__half_as_ushort(ha) | ((u32)__half_as_ushort(hb) << 16);
#endif
}

__device__ __forceinline__ float rcpf_(float x) {
#if defined(__has_builtin)
#if __has_builtin(__builtin_amdgcn_rcpf)
  return __builtin_amdgcn_rcpf(x);
#else
  return 1.0f / x;
#endif
#else
  return 1.0f / x;
#endif
}

__device__ __forceinline__ float h_lo(u32 d) {
  return __half2float(__ushort_as_half((unsigned short)(d & 0xffffu)));
}
__device__ __forceinline__ float h_hi(u32 d) {
  return __half2float(__ushort_as_half((unsigned short)(d >> 16)));
}

__device__ __forceinline__ float bf2f(unsigned short u) {
  union { float f; u32 i; } z; z.i = ((u32)u) << 16; return z.f;
}
__device__ __forceinline__ unsigned short f2bf(float f) {
  union { float fv; u32 u; } z; z.fv = f;
  u32 lsb = (z.u >> 16) & 1u;
  return (unsigned short)((z.u + 0x7fffu + lsb) >> 16);
}
__device__ __forceinline__ u32 bfpk(float a, float b) {
  return (u32)f2bf(a) | ((u32)f2bf(b) << 16);
}

// ---------------------------------------------------------------------------
// Kernel A: ONE wave per (batch, stream) OT problem. grid (2048,2), block 64.
// EXACT R7 configuration (proven 102us): bf16-MFMA phase 1, adaptive
// exp-space Sinkhorn (TOL 1.5e-3, __all exit — fires at ~3-4 iters),
// f16 u/v exchange, shfl_xor butterflies.
// ---------------------------------------------------------------------------
__launch_bounds__(64, 2)
__global__ void ot_kernel(const float* __restrict__ x,
                          const float* __restrict__ w1,
                          const float* __restrict__ w2,
                          const float* __restrict__ fc2w, const float* __restrict__ fc2b,
                          const float* __restrict__ fc3w, const float* __restrict__ fc3b,
                          const float* __restrict__ bin_score,
                          unsigned short* __restrict__ Pbuf)
{
  __shared__ __align__(16) u32 Ksh[64 * 68];              // K f16, pitch 68 dw (136 h)
  __shared__ __align__(16) unsigned short actL[16 * 136]; // act slice bf16
  __shared__ __align__(16) u32 vhs[64];                   // v packed f16 pairs
  __shared__ __align__(16) u32 uhs[32];                   // u packed f16 pairs

  const int l = threadIdx.x;
  const int b = blockIdx.x, s = blockIdx.y;
  const int l15 = l & 15, q = l >> 4;
  const float* wm = s ? w2 : w1;
  const float* fw = s ? fc3w : fc2w;
  const float* fb = s ? fc3b : fc2b;
  unsigned short* Kshh = reinterpret_cast<unsigned short*>(Ksh);

  // ---- preload w A-frags ----
  uint4 wA[4][4];
  #pragma unroll
  for (int at = 0; at < 4; ++at) {
    const float* wrow = wm + (size_t)(16 * at + l15) * 128;
    #pragma unroll
    for (int kt = 0; kt < 4; ++kt) {
      float4 va = *reinterpret_cast<const float4*>(wrow + 32 * kt + 8 * q);
      float4 vb = *reinterpret_cast<const float4*>(wrow + 32 * kt + 8 * q + 4);
      wA[at][kt] = make_uint4(bfpk(va.x, va.y), bfpk(va.z, va.w),
                              bfpk(vb.x, vb.y), bfpk(vb.z, vb.w));
    }
  }
  // ---- preload fcw B-frags ----
  uint4 fcwB[8];
  #pragma unroll
  for (int nt = 0; nt < 8; ++nt) {
    const int ch = 16 * nt + l15;
    uint4 o = make_uint4(0u, 0u, 0u, 0u);
    if (s) {
      if (q < 2) {
        const float* fr = fw + (size_t)ch * 16 + 8 * q;
        float4 va = *reinterpret_cast<const float4*>(fr);
        float4 vb = *reinterpret_cast<const float4*>(fr + 4);
        o = make_uint4(bfpk(va.x, va.y), bfpk(va.z, va.w),
                       bfpk(vb.x, vb.y), bfpk(vb.z, vb.w));
      }
    } else {
      if (q == 0) o.x = bfpk(fw[ch * 2], fw[ch * 2 + 1]);
    }
    fcwB[nt] = o;
  }
  float bb[8];
  #pragma unroll
  for (int nt = 0; nt < 8; ++nt) bb[nt] = fb[16 * nt + l15];

  // ---- preload x A-frags ----
  uint4 xa[8];
  #pragma unroll
  for (int mt = 0; mt < 8; ++mt) {
    const int node = 16 * mt + l15;
    const float* xp = x + ((size_t)b * NN + node) * IND + (s ? 2 : 0);
    uint4 o = make_uint4(0u, 0u, 0u, 0u);
    if (s) {
      if (q < 2) {
        float2 p0 = *reinterpret_cast<const float2*>(xp + 8 * q);
        float2 p1 = *reinterpret_cast<const float2*>(xp + 8 * q + 2);
        float2 p2 = *reinterpret_cast<const float2*>(xp + 8 * q + 4);
        float2 p3 = *reinterpret_cast<const float2*>(xp + 8 * q + 6);
        o = make_uint4(bfpk(p0.x, p0.y), bfpk(p1.x, p1.y),
                       bfpk(p2.x, p2.y), bfpk(p3.x, p3.y));
      }
    } else {
      if (q == 0) {
        float2 p0 = *reinterpret_cast<const float2*>(xp);
        o.x = bfpk(p0.x, p0.y);
      }
    }
    xa[mt] = o;
  }
  const float ebs = __expf(bin_score[0]);

  // ---- Phase 1: 8 slices of 16 nodes (bf16 MFMA, verified) ----
  #pragma unroll
  for (int mt = 0; mt < 8; ++mt) {
    f32x4 acc[8];
    #pragma unroll
    for (int nt = 0; nt < 8; ++nt)
      acc[nt] = __builtin_amdgcn_mfma_f32_16x16x32_bf16(
          __builtin_bit_cast(bf16x8, xa[mt]), __builtin_bit_cast(bf16x8, fcwB[nt]),
          f32x4{0.f, 0.f, 0.f, 0.f}, 0, 0, 0);
    #pragma unroll
    for (int nt = 0; nt < 8; ++nt) {
      #pragma unroll
      for (int r = 0; r < 4; ++r) {
        float v = fmaxf(acc[nt][r] + bb[nt], 0.0f);
        actL[(4 * q + r) * 136 + 16 * nt + l15] = f2bf(v);
      }
    }
    uint4 sB[4];
    #pragma unroll
    for (int kt = 0; kt < 4; ++kt)
      sB[kt] = *reinterpret_cast<const uint4*>(&actL[l15 * 136 + 32 * kt + 8 * q]);
    #pragma unroll
    for (int at = 0; at < 4; ++at) {
      f32x4 sa = f32x4{0.f, 0.f, 0.f, 0.f};
      #pragma unroll
      for (int kt = 0; kt < 4; ++kt)
        sa = __builtin_amdgcn_mfma_f32_16x16x32_bf16(
            __builtin_bit_cast(bf16x8, wA[at][kt]), __builtin_bit_cast(bf16x8, sB[kt]),
            sa, 0, 0, 0);
      #pragma unroll
      for (int r = 0; r < 4; ++r) {
        float kv = fminf(__expf(fmaxf(sa[r], 0.0f)), 60000.0f);
        Kshh[(16 * at + 4 * q + r) * 136 + 16 * mt + l15] =
            __half_as_ushort(__float2half_rn(kv));
      }
    }
  }

  // ---- register K tiles ----
  u32 kr[64];
  #pragma unroll
  for (int t = 0; t < 16; ++t) {
    uint4 kv = *reinterpret_cast<const uint4*>(Ksh + l * 68 + 4 * t);
    kr[4 * t + 0] = kv.x; kr[4 * t + 1] = kv.y;
    kr[4 * t + 2] = kv.z; kr[4 * t + 3] = kv.w;
  }
  u32 kta[32], ktb[32];
  #pragma unroll
  for (int j = 0; j < 32; ++j) {
    u32 d0 = Ksh[(2 * j) * 68 + l];
    u32 d1 = Ksh[(2 * j + 1) * 68 + l];
    kta[j] = (d0 & 0xffffu) | (d1 << 16);
    ktb[j] = (d0 >> 16) | (d1 & 0xffff0000u);
  }

  // ---- Phase 2: adaptive exp-space Sinkhorn (R7 verbatim) ----
  vhs[l] = 0x3C003C00u;
  float v128 = 1.0f, sum_v = 129.0f;
  float u_old = 0.0f, vo0 = 1.0f, vo1 = 1.0f;
  float ur = 0.0f;
  const float TOL = 1.5e-3f;

  for (int it = 0; it < 100; ++it) {
    const float u64v = 128.0f * rcpf_(ebs * sum_v);
    float a0 = ebs * v128, a1 = 0.f, a2 = 0.f, a3 = 0.f;
    const uint4* vh4 = reinterpret_cast<const uint4*>(vhs);
    #pragma unroll
    for (int t = 0; t < 16; ++t) {
      uint4 vv = vh4[t];
      a0 = fdot2f(kr[4 * t + 0], vv.x, a0);
      a1 = fdot2f(kr[4 * t + 1], vv.y, a1);
      a2 = fdot2f(kr[4 * t + 2], vv.z, a2);
      a3 = fdot2f(kr[4 * t + 3], vv.w, a3);
    }
    float urn = rcpf_((a0 + a1) + (a2 + a3));
    float m1 = fabsf(urn - u_old) - TOL * urn;
    u_old = urn; ur = urn;
    float su = urn;
    su += __shfl_xor(su, 1);  su += __shfl_xor(su, 2);
    su += __shfl_xor(su, 4);  su += __shfl_xor(su, 8);
    su += __shfl_xor(su, 16); su += __shfl_xor(su, 32);
    const float sum_u = su + u64v;
    const float v128n = 64.0f * rcpf_(ebs * sum_u);
    float upr = __shfl_xor(urn, 1);
    if (!(l & 1)) uhs[l >> 1] = pk2(urn, upr);
    float c0a = ebs * u64v, c0b = 0.f, c1a = ebs * u64v, c1b = 0.f;
    const uint4* uh4 = reinterpret_cast<const uint4*>(uhs);
    #pragma unroll
    for (int t = 0; t < 8; ++t) {
      uint4 uu = uh4[t];
      c0a = fdot2f(kta[4 * t + 0], uu.x, c0a);
      c0b = fdot2f(kta[4 * t + 1], uu.y, c0b);
      c0a = fdot2f(kta[4 * t + 2], uu.z, c0a);
      c0b = fdot2f(kta[4 * t + 3], uu.w, c0b);
      c1a = fdot2f(ktb[4 * t + 0], uu.x, c1a);
      c1b = fdot2f(ktb[4 * t + 1], uu.y, c1b);
      c1a = fdot2f(ktb[4 * t + 2], uu.z, c1a);
      c1b = fdot2f(ktb[4 * t + 3], uu.w, c1b);
    }
    float v0n = rcpf_(c0a + c0b);
    float v1n = rcpf_(c1a + c1b);
    float m2 = fabsf(v0n - vo0) - TOL * v0n;
    float m3 = fabsf(v1n - vo1) - TOL * v1n;
    vo0 = v0n; vo1 = v1n;
    vhs[l] = pk2(v0n, v1n);
    float sv = v0n + v1n;
    sv += __shfl_xor(sv, 1);  sv += __shfl_xor(sv, 2);
    sv += __shfl_xor(sv, 4);  sv += __shfl_xor(sv, 8);
    sv += __shfl_xor(sv, 16); sv += __shfl_xor(sv, 32);
    sum_v = sv + v128n;
    v128 = v128n;
    float mcond = fmaxf(m1, fmaxf(m2, m3));
    if (__all(mcond <= 0.0f)) break;
  }

  // ---- Phase 3: P[l][n] = K*u*v -> bf16 ----
  {
    unsigned short* Pout = Pbuf + ((size_t)(s * B_ + b)) * (MM * NN);
    uint4* P4 = reinterpret_cast<uint4*>(Pout);
    const uint4* vh4 = reinterpret_cast<const uint4*>(vhs);
    #pragma unroll
    for (int t = 0; t < 16; ++t) {
      uint4 vv = vh4[t];
      u32 o0 = bfpk(h_lo(kr[4 * t + 0]) * ur * h_lo(vv.x),
                    h_hi(kr[4 * t + 0]) * ur * h_hi(vv.x));
      u32 o1 = bfpk(h_lo(kr[4 * t + 1]) * ur * h_lo(vv.y),
                    h_hi(kr[4 * t + 1]) * ur * h_hi(vv.y));
      u32 o2 = bfpk(h_lo(kr[4 * t + 2]) * ur * h_lo(vv.z),
                    h_hi(kr[4 * t + 2]) * ur * h_hi(vv.z));
      u32 o3 = bfpk(h_lo(kr[4 * t + 3]) * ur * h_lo(vv.w),
                    h_hi(kr[4 * t + 3]) * ur * h_hi(vv.w));
      P4[l * 16 + t] = make_uint4(o0, o1, o2, o3);
    }
  }
}

// ---------------------------------------------------------------------------
// Kernel B (R12): MFMA align restructured for occupancy. LDS 59.4 -> 51.1 KB
// (3 blocks/CU vs 2): adj staged in TWO 64-row halves reusing one buffer;
// xfT staged into the freed adjb region after M1. Same 52 MFMAs/wave.
// ---------------------------------------------------------------------------
#define AP 136   // bf16 row pitch (272 B, 16B aligned)

__device__ __forceinline__ bf16x8 ldfrag(const unsigned short* p) {
  return __builtin_bit_cast(bf16x8, *reinterpret_cast<const uint4*>(p));
}
__device__ __forceinline__ u32 comb2(u32 ps, u32 pf, float a, float na) {
  float r0 = a * bf2f((unsigned short)(ps & 0xffffu)) + na * bf2f((unsigned short)(pf & 0xffffu));
  float r1 = a * bf2f((unsigned short)(ps >> 16)) + na * bf2f((unsigned short)(pf >> 16));
  return (u32)f2bf(r0) | ((u32)f2bf(r1) << 16);
}

__launch_bounds__(256, 3)
__global__ void align_kernel(const unsigned short* __restrict__ Pbuf,
                             const float* __restrict__ adj,
                             const float* __restrict__ x,
                             const float* __restrict__ alpha_p,
                             const float* __restrict__ ln1g, const float* __restrict__ ln1b,
                             const float* __restrict__ ln2g, const float* __restrict__ ln2b,
                             unsigned short* __restrict__ lnadj,
                             unsigned short* __restrict__ lnfeats)
{
  __shared__ __align__(16) unsigned short adjb[64 * AP];   // adj half / xfT / ob1
  __shared__ __align__(16) unsigned short Pms[64 * AP];
  __shared__ __align__(16) unsigned short Z1T[64 * AP];    // ob2 later
  __shared__ float red[16];

  const int tid = threadIdx.x;
  const int b = blockIdx.x;
  const int w = tid >> 6;
  const int lane = tid & 63;
  const int l15 = lane & 15;
  const int q = lane >> 4;
  const float a = 1.0f / (1.0f + __expf(-alpha_p[0]));
  const float na = 1.0f - a;

  // ---- stage Pms = a*Ps + (1-a)*Pf ----
  {
    const uint4* Ps4 = reinterpret_cast<const uint4*>(Pbuf + (size_t)b * (MM * NN));
    const uint4* Pf4 = reinterpret_cast<const uint4*>(Pbuf + ((size_t)B_ + b) * (MM * NN));
    for (int i = tid; i < 64 * 16; i += 256) {
      int row = i >> 4, g = i & 15;
      uint4 sa = Ps4[i];
      uint4 fa = Pf4[i];
      uint4 o;
      o.x = comb2(sa.x, fa.x, a, na); o.y = comb2(sa.y, fa.y, a, na);
      o.z = comb2(sa.z, fa.z, a, na); o.w = comb2(sa.w, fa.w, a, na);
      *reinterpret_cast<uint4*>(&Pms[row * AP + g * 8]) = o;
    }
  }

  // ---- M1 over two adj halves: Z1T[k][n] = sum_d adj[n][d]*Pm[k][d] ----
  for (int h = 0; h < 2; ++h) {
    __syncthreads();   // h=0: nothing pending; h=1: WAR on adjb (M1-h0 reads done)
    {
      const float4* src = reinterpret_cast<const float4*>(
          adj + (size_t)b * (NN * NN) + (size_t)(64 * h) * NN);
      for (int i = tid; i < 64 * 32; i += 256) {
        int row = i >> 5, c4 = i & 31;
        float4 v = src[i];
        u32 w0 = (u32)f2bf(v.x) | ((u32)f2bf(v.y) << 16);
        u32 w1 = (u32)f2bf(v.z) | ((u32)f2bf(v.w) << 16);
        *reinterpret_cast<uint2*>(&adjb[row * AP + c4 * 4]) = make_uint2(w0, w1);
      }
    }
    __syncthreads();   // adjb (and Pms, first pass) ready
    f32x4 acch[4];
    #pragma unroll
    for (int j = 0; j < 4; ++j) acch[j] = f32x4{0.f, 0.f, 0.f, 0.f};
    #pragma unroll
    for (int kt = 0; kt < 4; ++kt) {
      const int d0 = 32 * kt + 8 * q;
      bf16x8 af = ldfrag(&adjb[(16 * w + l15) * AP + d0]);
      #pragma unroll
      for (int j = 0; j < 4; ++j) {
        bf16x8 bf = ldfrag(&Pms[(16 * j + l15) * AP + d0]);
        acch[j] = __builtin_amdgcn_mfma_f32_16x16x32_bf16(af, bf, acch[j], 0, 0, 0);
      }
    }
    #pragma unroll
    for (int j = 0; j < 4; ++j) {
      const int k = 16 * j + l15;
      const int nbase = 64 * h + 16 * w + 4 * q;
      u32 w0 = (u32)f2bf(acch[j][0]) | ((u32)f2bf(acch[j][1]) << 16);
      u32 w1 = (u32)f2bf(acch[j][2]) | ((u32)f2bf(acch[j][3]) << 16);
      *reinterpret_cast<uint2*>(&Z1T[k * AP + nbase]) = make_uint2(w0, w1);
    }
  }
  __syncthreads();   // Z1T complete; adjb free

  // ---- stage xfT[f][n] into adjb region ----
  for (int i = tid; i < 2048; i += 256) {
    int n = i & 127, f = i >> 7;
    adjb[f * AP + n] = f2bf(x[((size_t)b * NN + n) * IND + 2 + f]);
  }
  __syncthreads();

  // ---- M2: al2 = Pm @ Z1; M3: feats = Pm @ xf ----
  f32x4 acc2[4];
  f32x4 acc3 = f32x4{0.f, 0.f, 0.f, 0.f};
  #pragma unroll
  for (int j = 0; j < 4; ++j) acc2[j] = f32x4{0.f, 0.f, 0.f, 0.f};
  #pragma unroll
  for (int nt = 0; nt < 4; ++nt) {
    const int n0 = 32 * nt + 8 * q;
    bf16x8 af = ldfrag(&Pms[(16 * w + l15) * AP + n0]);
    #pragma unroll
    for (int j = 0; j < 4; ++j) {
      bf16x8 bv = ldfrag(&Z1T[(16 * j + l15) * AP + n0]);
      acc2[j] = __builtin_amdgcn_mfma_f32_16x16x32_bf16(af, bv, acc2[j], 0, 0, 0);
    }
    bf16x8 bx = ldfrag(&adjb[l15 * AP + n0]);
    acc3 = __builtin_amdgcn_mfma_f32_16x16x32_bf16(af, bx, acc3, 0, 0, 0);
  }

  // ---- LN reductions ----
  {
    float s1 = 0.f, q1 = 0.f, s2 = 0.f, q2 = 0.f;
    #pragma unroll
    for (int j = 0; j < 4; ++j)
      #pragma unroll
      for (int r = 0; r < 4; ++r) { float v = acc2[j][r]; s1 += v; q1 += v * v; }
    #pragma unroll
    for (int r = 0; r < 4; ++r) { float v = acc3[r]; s2 += v; q2 += v * v; }
    #pragma unroll
    for (int off = 1; off < 64; off <<= 1) {
      s1 += __shfl_xor(s1, off); q1 += __shfl_xor(q1, off);
      s2 += __shfl_xor(s2, off); q2 += __shfl_xor(q2, off);
    }
    if (lane == 0) { red[w] = s1; red[4 + w] = q1; red[8 + w] = s2; red[12 + w] = q2; }
  }
  __syncthreads();
  const float S1 = red[0] + red[1] + red[2] + red[3];
  const float Q1 = red[4] + red[5] + red[6] + red[7];
  const float S2 = red[8] + red[9] + red[10] + red[11];
  const float Q2 = red[12] + red[13] + red[14] + red[15];
  const float mean1 = S1 * (1.0f / 4096.0f);
  const float rstd1 = rsqrtf(Q1 * (1.0f / 4096.0f) - mean1 * mean1 + 1e-5f);
  const float mean2 = S2 * (1.0f / 1024.0f);
  const float rstd2 = rsqrtf(Q2 * (1.0f / 1024.0f) - mean2 * mean2 + 1e-5f);

  // ---- normalize + bounce through freed LDS (all M2/M3 reads done: barriers above) ----
  unsigned short* ob1 = adjb;   // 4096 shorts (xfT dead after M3 + LN barriers)
  unsigned short* ob2 = Z1T;    // 1024 shorts
  #pragma unroll
  for (int j = 0; j < 4; ++j) {
    const int k = 16 * j + l15;
    #pragma unroll
    for (int r = 0; r < 4; ++r) {
      const int m = 16 * w + 4 * q + r;
      const int pos = m * 64 + k;
      float vv = (acc2[j][r] - mean1) * rstd1 * ln1g[pos] + ln1b[pos];
      ob1[pos] = f2bf(vv);
    }
  }
  {
    const int f = l15;
    #pragma unroll
    for (int r = 0; r < 4; ++r) {
      const int m = 16 * w + 4 * q + r;
      const int pos = m * 16 + f;
      float vv = (acc3[r] - mean2) * rstd2 * ln2g[pos] + ln2b[pos];
      ob2[pos] = f2bf(vv);
    }
  }
  __syncthreads();
  {
    const uint4* sp = reinterpret_cast<const uint4*>(ob1);
    uint4* dp = reinterpret_cast<uint4*>(lnadj + (size_t)b * 4096);
    for (int i = tid; i < 512; i += 256) dp[i] = sp[i];
    if (tid < 128)
      reinterpret_cast<uint4*>(lnfeats + (size_t)b * 1024)[tid] =
          reinterpret_cast<const uint4*>(ob2)[tid];
  }
}

// ---------------------------------------------------------------------------
// Kernel C (MFMA): unchanged.
// ---------------------------------------------------------------------------
#define GP 72
__launch_bounds__(256, 2)
__global__ void gemm_mfma_kernel(const unsigned short* __restrict__ A,
                                 const float* __restrict__ W,
                                 const float* __restrict__ bias,
                                 float* __restrict__ C,
                                 int K, int ldc, int coff)
{
  __shared__ __align__(16) unsigned short At[64 * GP];
  __shared__ __align__(16) unsigned short Wt[64 * GP];
  const int tid = threadIdx.x;
  const int m0 = blockIdx.x * 64;
  const int n0 = blockIdx.y * 64;
  const int w = tid >> 6, lane = tid & 63;
  const int l15 = lane & 15, q = lane >> 4;
  const int srow = tid >> 2, sko = (tid & 3) * 16;

  f32x4 acc[4];
  #pragma unroll
  for (int j = 0; j < 4; ++j) acc[j] = f32x4{0.f, 0.f, 0.f, 0.f};

  for (int kc = 0; kc < K; kc += 64) {
    __syncthreads();
    {
      const unsigned short* ap = &A[(size_t)(m0 + srow) * K + kc + sko];
      *reinterpret_cast<uint4*>(&At[srow * GP + sko]) =
          *reinterpret_cast<const uint4*>(ap);
      *reinterpret_cast<uint4*>(&At[srow * GP + sko + 8]) =
          *reinterpret_cast<const uint4*>(ap + 8);
      const float* wp = &W[(size_t)(n0 + srow) * K + kc + sko];
      const float4 v0 = reinterpret_cast<const float4*>(wp)[0];
      const float4 v1 = reinterpret_cast<const float4*>(wp)[1];
      const float4 v2 = reinterpret_cast<const float4*>(wp)[2];
      const float4 v3 = reinterpret_cast<const float4*>(wp)[3];
      uint4 o0, o1;
      o0.x = (u32)f2bf(v0.x) | ((u32)f2bf(v0.y) << 16);
      o0.y = (u32)f2bf(v0.z) | ((u32)f2bf(v0.w) << 16);
      o0.z = (u32)f2bf(v1.x) | ((u32)f2bf(v1.y) << 16);
      o0.w = (u32)f2bf(v1.z) | ((u32)f2bf(v1.w) << 16);
      o1.x = (u32)f2bf(v2.x) | ((u32)f2bf(v2.y) << 16);
      o1.y = (u32)f2bf(v2.z) | ((u32)f2bf(v2.w) << 16);
      o1.z = (u32)f2bf(v3.x) | ((u32)f2bf(v3.y) << 16);
      o1.w = (u32)f2bf(v3.z) | ((u32)f2bf(v3.w) << 16);
      *reinterpret_cast<uint4*>(&Wt[srow * GP + sko]) = o0;
      *reinterpret_cast<uint4*>(&Wt[srow * GP + sko + 8]) = o1;
    }
    __syncthreads();
    #pragma unroll
    for (int s = 0; s < 2; ++s) {
      bf16x8 af = ldfrag(&At[(16 * w + l15) * GP + 32 * s + 8 * q]);
      #pragma unroll
      for (int j = 0; j < 4; ++j) {
        bf16x8 bf = ldfrag(&Wt[(16 * j + l15) * GP + 32 * s + 8 * q]);
        acc[j] = __builtin_amdgcn_mfma_f32_16x16x32_bf16(af, bf, acc[j], 0, 0, 0);
      }
    }
  }
  #pragma unroll
  for (int j = 0; j < 4; ++j) {
    const int col = n0 + 16 * j + l15;
    const float bb = bias[col];
    #pragma unroll
    for (int r = 0; r < 4; ++r) {
      const int m = m0 + 16 * w + 4 * q + r;
      C[(size_t)m * ldc + coff + col] = fmaxf(acc[j][r] + bb, 0.0f);
    }
  }
}

// ---------------------------------------------------------------------------
// Kernel D: unchanged (8 rows/block).
// ---------------------------------------------------------------------------
__launch_bounds__(256)
__global__ void head_kernel(const float* __restrict__ h45,
                            const float* __restrict__ wT6,   // [512][64]
                            const float* __restrict__ b6,
                            const float* __restrict__ w7,    // [10][64]
                            const float* __restrict__ b7,
                            float* __restrict__ out)
{
  __shared__ float row[8][512];
  __shared__ float h6[8][64];
  __shared__ float zb[8][12];
  const int tid = threadIdx.x;
  const int r0 = blockIdx.x * 8;
  for (int i = tid; i < 8 * 128; i += 256) {
    int r = i >> 7, c4 = i & 127;
    *reinterpret_cast<float4*>(&row[r][c4 * 4]) =
        reinterpret_cast<const float4*>(h45 + (size_t)(r0 + r) * 512)[c4];
  }
  __syncthreads();
  const int o = tid & 63, rg = tid >> 6;
  float a0 = b6[o], a1 = a0;
  #pragma unroll 8
  for (int k = 0; k < 512; ++k) {
    float wv = wT6[k * 64 + o];
    a0 += row[rg][k] * wv;
    a1 += row[rg + 4][k] * wv;
  }
  h6[rg][o] = fmaxf(a0, 0.0f);
  h6[rg + 4][o] = fmaxf(a1, 0.0f);
  __syncthreads();
  if (tid < 80) {
    int r = tid / 10, c = tid - r * 10;
    float z = b7[c];
    #pragma unroll
    for (int k = 0; k < 64; ++k) z += h6[r][k] * w7[c * 64 + k];
    zb[r][c] = z;
  }
  __syncthreads();
  if (tid < 80) {
    int r = tid / 10, c = tid - r * 10;
    float mx = zb[r][0];
    #pragma unroll
    for (int j = 1; j < 10; ++j) mx = fmaxf(mx, zb[r][j]);
    float se = 0.f;
    #pragma unroll
    for (int j = 0; j < 10; ++j) se += __expf(zb[r][j] - mx);
    out[(size_t)(r0 + r) * 10 + c] = zb[r][c] - mx - __logf(se);
  }
}

__global__ void transpose_kernel(const float* __restrict__ in, float* __restrict__ outp,
                                 int R, int Cc)
{
  int idx = blockIdx.x * blockDim.x + threadIdx.x;
  int total = R * Cc;
  for (; idx < total; idx += gridDim.x * blockDim.x) {
    int rr = idx / Cc, cc = idx - rr * Cc;
    outp[cc * R + rr] = in[idx];
  }
}

// ---------------------------------------------------------------------------
extern "C" void kernel_launch(void* const* d_in, const int* in_sizes, int n_in,
                              void* d_out, int out_size, void* d_ws, size_t ws_size,
                              hipStream_t stream)
{
  (void)in_sizes; (void)n_in; (void)out_size; (void)ws_size;
  const float* x    = (const float*)d_in[0];
  const float* adj  = (const float*)d_in[1];
  const float* w1   = (const float*)d_in[2];
  const float* w2   = (const float*)d_in[3];
  const float* alpha = (const float*)d_in[4];
  const float* bin_score = (const float*)d_in[5];
  const float* fc2w = (const float*)d_in[6];
  const float* fc2b = (const float*)d_in[7];
  const float* fc3w = (const float*)d_in[8];
  const float* fc3b = (const float*)d_in[9];
  const float* ln1g = (const float*)d_in[10];
  const float* ln1b = (const float*)d_in[11];
  const float* fc4w = (const float*)d_in[12];
  const float* fc4b = (const float*)d_in[13];
  const float* ln2g = (const float*)d_in[14];
  const float* ln2b = (const float*)d_in[15];
  const float* fc5w = (const float*)d_in[16];
  const float* fc5b = (const float*)d_in[17];
  const float* fc6w = (const float*)d_in[18];
  const float* fc6b = (const float*)d_in[19];
  const float* fc7w = (const float*)d_in[20];
  const float* fc7b = (const float*)d_in[21];
  float* out = (float*)d_out;

  char* ws = (char*)d_ws;
  unsigned short* Pbuf = (unsigned short*)ws;                       // 4096*8192 bf16 = 64 MB
  size_t off = (size_t)4096 * 8192 * 2;
  unsigned short* lnadj = (unsigned short*)(ws + off);  off += (size_t)2048 * 4096 * 2;
  unsigned short* lnfeats = (unsigned short*)(ws + off); off += (size_t)2048 * 1024 * 2;
  float* h45 = (float*)(ws + off);                      off += (size_t)2048 * 512 * 4;
  float* wT6 = (float*)(ws + off);                      off += (size_t)512 * 64 * 4;

  hipLaunchKernelGGL(ot_kernel, dim3(2048, 2), dim3(64), 0, stream,
                     x, w1, w2, fc2w, fc2b, fc3w, fc3b, bin_score, Pbuf);
  hipLaunchKernelGGL(transpose_kernel, dim3(32), dim3(256), 0, stream, fc6w, wT6, 64, 512);
  hipLaunchKernelGGL(align_kernel, dim3(2048), dim3(256), 0, stream,
                     Pbuf, adj, x, alpha, ln1g, ln1b, ln2g, ln2b, lnadj, lnfeats);
  hipLaunchKernelGGL(gemm_mfma_kernel, dim3(32, 4), dim3(256), 0, stream,
                     lnadj, fc4w, fc4b, h45, 4096, 512, 0);
  hipLaunchKernelGGL(gemm_mfma_kernel, dim3(32, 4), dim3(256), 0, stream,
                     lnfeats, fc5w, fc5b, h45, 1024, 512, 256);
  hipLaunchKernelGGL(head_kernel, dim3(256), dim3(256), 0, stream,
                     h45, wT6, fc6b, fc7w, fc7b, out);
}

// Round 13
// 226.279 us; speedup vs baseline: 1.5091x; 1.0612x over previous
//
#include <hip/hip_runtime.h>
#include <hip/hip_bf16.h>
#include <hip/hip_fp16.h>

// Problem constants
#define B_   2048
#define NN   128    // NMAX
#define MM   64     // HN
#define HD_  128
#define IND  18
#define FD_  16

typedef unsigned int u32;
typedef _Float16 h2_t __attribute__((ext_vector_type(2)));
typedef __attribute__((ext_vector_type(8))) short bf16x8;
typedef __attribute__((ext_vector_type(4))) float f32x4;

__device__ __forceinline__ float fdot2f(u32 a, u32 b, float c) {
#if defined(__has_builtin)
#if __has_builtin(__builtin_amdgcn_fdot2)
  return __builtin_amdgcn_fdot2(__builtin_bit_cast(h2_t, a),
                                __builtin_bit_cast(h2_t, b), c, false);
#else
  h2_t x = __builtin_bit_cast(h2_t, a), y = __builtin_bit_cast(h2_t, b);
  return c + (float)x[0] * (float)y[0] + (float)x[1] * (float)y[1];
#endif
#else
  h2_t x = __builtin_bit_cast(h2_t, a), y = __builtin_bit_cast(h2_t, b);
  return c + (float)x[0] * (float)y[0] + (float)x[1] * (float)y[1];
#endif
}

__device__ __forceinline__ u32 pk2(float a, float b) {
#if defined(__has_builtin)
#if __has_builtin(__builtin_amdgcn_cvt_pkrtz)
  return __builtin_bit_cast(u32, __builtin_amdgcn_cvt_pkrtz(a, b));
#else
  __half ha = __float2half_rn(a), hb = __float2half_rn(b);
  return (u32)__half_as_ushort(ha) | ((u32)__half_as_ushort(hb) << 16);
#endif
#else
  __half ha = __float2half_rn(a), hb = __float2half_rn(b);
  return (u32)__half_as_ushort(ha) | ((u32)__half_as_ushort(hb) << 16);
#endif
}

__device__ __forceinline__ float rcpf_(float x) {
#if defined(__has_builtin)
#if __has_builtin(__builtin_amdgcn_rcpf)
  return __builtin_amdgcn_rcpf(x);
#else
  return 1.0f / x;
#endif
#else
  return 1.0f / x;
#endif
}

__device__ __forceinline__ float h_lo(u32 d) {
  return __half2float(__ushort_as_half((unsigned short)(d & 0xffffu)));
}
__device__ __forceinline__ float h_hi(u32 d) {
  return __half2float(__ushort_as_half((unsigned short)(d >> 16)));
}

__device__ __forceinline__ float bf2f(unsigned short u) {
  union { float f; u32 i; } z; z.i = ((u32)u) << 16; return z.f;
}
__device__ __forceinline__ unsigned short f2bf(float f) {
  union { float fv; u32 u; } z; z.fv = f;
  u32 lsb = (z.u >> 16) & 1u;
  return (unsigned short)((z.u + 0x7fffu + lsb) >> 16);
}
__device__ __forceinline__ u32 bfpk(float a, float b) {
  return (u32)f2bf(a) | ((u32)f2bf(b) << 16);
}
__device__ __forceinline__ bf16x8 ldfrag(const unsigned short* p) {
  return __builtin_bit_cast(bf16x8, *reinterpret_cast<const uint4*>(p));
}
__device__ __forceinline__ u32 comb2(u32 ps, u32 pf, float a, float na) {
  float r0 = a * bf2f((unsigned short)(ps & 0xffffu)) + na * bf2f((unsigned short)(pf & 0xffffu));
  float r1 = a * bf2f((unsigned short)(ps >> 16)) + na * bf2f((unsigned short)(pf >> 16));
  return (u32)f2bf(r0) | ((u32)f2bf(r1) << 16);
}

// ---------------------------------------------------------------------------
// FUSED kernel (R13): one block per batch, 256 threads (4 waves).
//  Phase A (all 4 waves): scores->K phase-1, split: wave = (slice-half, stream)
//    sw = wv&1 (stream), mtbase = (wv>>1)*4. actL aliased into Z1T (dead).
//  Phase B: waves 0-1 run R7's adaptive Sinkhorn (stream = wv) and write
//    P = K*u*v bf16 IN PLACE over Ksh[wv]; waves 2-3 stage adj half 0 -> adjb.
//  Phase C (all): Pc = a*P0+(1-a)*P1 into Ksh[0]; M1 over 2 adj halves;
//    xfT into adjb tail; M2 (al2) + M3 (feats); LN1/LN2; outputs.
//  LDS total 68.8 KB -> 2 blocks/CU. All compute bodies verbatim R7/R12.
// ---------------------------------------------------------------------------
#define AP 136   // bf16 row pitch (272 B)

__launch_bounds__(256, 2)
__global__ void fused_kernel(const float* __restrict__ x,
                             const float* __restrict__ adj,
                             const float* __restrict__ w1,
                             const float* __restrict__ w2,
                             const float* __restrict__ alpha_p,
                             const float* __restrict__ bin_score,
                             const float* __restrict__ fc2w, const float* __restrict__ fc2b,
                             const float* __restrict__ fc3w, const float* __restrict__ fc3b,
                             const float* __restrict__ ln1g, const float* __restrict__ ln1b,
                             const float* __restrict__ ln2g, const float* __restrict__ ln2b,
                             unsigned short* __restrict__ lnadj,
                             unsigned short* __restrict__ lnfeats)
{
  __shared__ __align__(16) u32 Ksh[2][64 * 68];            // 34816 B (K then P)
  __shared__ __align__(16) u32 vhs[2][64];                 // 512 B
  __shared__ __align__(16) u32 uhs[2][32];                 // 256 B
  __shared__ __align__(16) unsigned short adjb[64 * AP];   // 17408 B (adj halves / xfT tail / ob1)
  __shared__ __align__(16) unsigned short Z1T[64 * AP];    // 17408 B (actL alias / Z1 / ob2)
  __shared__ float red[16];

  const int tid = threadIdx.x;
  const int wv = tid >> 6;
  const int lane = tid & 63;
  const int l15 = lane & 15, q = lane >> 4;
  const int b = blockIdx.x;

  // ======================= Phase A: scores -> K ==========================
  {
    const int sw = wv & 1;               // stream
    const int mtbase = (wv >> 1) * 4;    // slice half
    const float* wm = sw ? w2 : w1;
    const float* fw = sw ? fc3w : fc2w;
    const float* fb = sw ? fc3b : fc2b;
    unsigned short* Kshh = reinterpret_cast<unsigned short*>(Ksh[sw]);
    unsigned short* actw = Z1T + (size_t)wv * (16 * AP);   // per-wave scratch

    uint4 wA[4][4];
    #pragma unroll
    for (int at = 0; at < 4; ++at) {
      const float* wrow = wm + (size_t)(16 * at + l15) * 128;
      #pragma unroll
      for (int kt = 0; kt < 4; ++kt) {
        float4 va = *reinterpret_cast<const float4*>(wrow + 32 * kt + 8 * q);
        float4 vb = *reinterpret_cast<const float4*>(wrow + 32 * kt + 8 * q + 4);
        wA[at][kt] = make_uint4(bfpk(va.x, va.y), bfpk(va.z, va.w),
                                bfpk(vb.x, vb.y), bfpk(vb.z, vb.w));
      }
    }
    uint4 fcwB[8];
    #pragma unroll
    for (int nt = 0; nt < 8; ++nt) {
      const int ch = 16 * nt + l15;
      uint4 o = make_uint4(0u, 0u, 0u, 0u);
      if (sw) {
        if (q < 2) {
          const float* fr = fw + (size_t)ch * 16 + 8 * q;
          float4 va = *reinterpret_cast<const float4*>(fr);
          float4 vb = *reinterpret_cast<const float4*>(fr + 4);
          o = make_uint4(bfpk(va.x, va.y), bfpk(va.z, va.w),
                         bfpk(vb.x, vb.y), bfpk(vb.z, vb.w));
        }
      } else {
        if (q == 0) o.x = bfpk(fw[ch * 2], fw[ch * 2 + 1]);
      }
      fcwB[nt] = o;
    }
    float bb[8];
    #pragma unroll
    for (int nt = 0; nt < 8; ++nt) bb[nt] = fb[16 * nt + l15];

    uint4 xa[4];
    #pragma unroll
    for (int mi = 0; mi < 4; ++mi) {
      const int node = 16 * (mtbase + mi) + l15;
      const float* xp = x + ((size_t)b * NN + node) * IND + (sw ? 2 : 0);
      uint4 o = make_uint4(0u, 0u, 0u, 0u);
      if (sw) {
        if (q < 2) {
          float2 p0 = *reinterpret_cast<const float2*>(xp + 8 * q);
          float2 p1 = *reinterpret_cast<const float2*>(xp + 8 * q + 2);
          float2 p2 = *reinterpret_cast<const float2*>(xp + 8 * q + 4);
          float2 p3 = *reinterpret_cast<const float2*>(xp + 8 * q + 6);
          o = make_uint4(bfpk(p0.x, p0.y), bfpk(p1.x, p1.y),
                         bfpk(p2.x, p2.y), bfpk(p3.x, p3.y));
        }
      } else {
        if (q == 0) {
          float2 p0 = *reinterpret_cast<const float2*>(xp);
          o.x = bfpk(p0.x, p0.y);
        }
      }
      xa[mi] = o;
    }

    #pragma unroll
    for (int mi = 0; mi < 4; ++mi) {
      const int mt = mtbase + mi;
      f32x4 acc[8];
      #pragma unroll
      for (int nt = 0; nt < 8; ++nt)
        acc[nt] = __builtin_amdgcn_mfma_f32_16x16x32_bf16(
            __builtin_bit_cast(bf16x8, xa[mi]), __builtin_bit_cast(bf16x8, fcwB[nt]),
            f32x4{0.f, 0.f, 0.f, 0.f}, 0, 0, 0);
      #pragma unroll
      for (int nt = 0; nt < 8; ++nt) {
        #pragma unroll
        for (int r = 0; r < 4; ++r) {
          float v = fmaxf(acc[nt][r] + bb[nt], 0.0f);
          actw[(4 * q + r) * AP + 16 * nt + l15] = f2bf(v);
        }
      }
      uint4 sB[4];
      #pragma unroll
      for (int kt = 0; kt < 4; ++kt)
        sB[kt] = *reinterpret_cast<const uint4*>(&actw[l15 * AP + 32 * kt + 8 * q]);
      #pragma unroll
      for (int at = 0; at < 4; ++at) {
        f32x4 sa = f32x4{0.f, 0.f, 0.f, 0.f};
        #pragma unroll
        for (int kt = 0; kt < 4; ++kt)
          sa = __builtin_amdgcn_mfma_f32_16x16x32_bf16(
              __builtin_bit_cast(bf16x8, wA[at][kt]), __builtin_bit_cast(bf16x8, sB[kt]),
              sa, 0, 0, 0);
        #pragma unroll
        for (int r = 0; r < 4; ++r) {
          float kv = fminf(__expf(fmaxf(sa[r], 0.0f)), 60000.0f);
          Kshh[(16 * at + 4 * q + r) * AP + 16 * mt + l15] =
              __half_as_ushort(__float2half_rn(kv));
        }
      }
    }
  }
  __syncthreads();   // Ksh[0..1] complete; actL (Z1T) dead

  const float ebs = __expf(bin_score[0]);

  // ============== Phase B: Sinkhorn (waves 0-1) | adj h0 (waves 2-3) =====
  if (wv < 2) {
    const int l = lane;
    u32* Ks = Ksh[wv];
    u32 kr[64];
    #pragma unroll
    for (int t = 0; t < 16; ++t) {
      uint4 kv = *reinterpret_cast<const uint4*>(Ks + l * 68 + 4 * t);
      kr[4 * t + 0] = kv.x; kr[4 * t + 1] = kv.y;
      kr[4 * t + 2] = kv.z; kr[4 * t + 3] = kv.w;
    }
    u32 kta[32], ktb[32];
    #pragma unroll
    for (int j = 0; j < 32; ++j) {
      u32 d0 = Ks[(2 * j) * 68 + l];
      u32 d1 = Ks[(2 * j + 1) * 68 + l];
      kta[j] = (d0 & 0xffffu) | (d1 << 16);
      ktb[j] = (d0 >> 16) | (d1 & 0xffff0000u);
    }

    u32* vh = vhs[wv];
    u32* uh = uhs[wv];
    vh[l] = 0x3C003C00u;
    float v128 = 1.0f, sum_v = 129.0f;
    float u_old = 0.0f, vo0 = 1.0f, vo1 = 1.0f;
    float ur = 0.0f;
    const float TOL = 1.5e-3f;

    for (int it = 0; it < 100; ++it) {
      const float u64v = 128.0f * rcpf_(ebs * sum_v);
      float a0 = ebs * v128, a1 = 0.f, a2 = 0.f, a3 = 0.f;
      const uint4* vh4 = reinterpret_cast<const uint4*>(vh);
      #pragma unroll
      for (int t = 0; t < 16; ++t) {
        uint4 vvv = vh4[t];
        a0 = fdot2f(kr[4 * t + 0], vvv.x, a0);
        a1 = fdot2f(kr[4 * t + 1], vvv.y, a1);
        a2 = fdot2f(kr[4 * t + 2], vvv.z, a2);
        a3 = fdot2f(kr[4 * t + 3], vvv.w, a3);
      }
      float urn = rcpf_((a0 + a1) + (a2 + a3));
      float m1 = fabsf(urn - u_old) - TOL * urn;
      u_old = urn; ur = urn;
      float su = urn;
      su += __shfl_xor(su, 1);  su += __shfl_xor(su, 2);
      su += __shfl_xor(su, 4);  su += __shfl_xor(su, 8);
      su += __shfl_xor(su, 16); su += __shfl_xor(su, 32);
      const float sum_u = su + u64v;
      const float v128n = 64.0f * rcpf_(ebs * sum_u);
      float upr = __shfl_xor(urn, 1);
      if (!(l & 1)) uh[l >> 1] = pk2(urn, upr);
      float c0a = ebs * u64v, c0b = 0.f, c1a = ebs * u64v, c1b = 0.f;
      const uint4* uh4 = reinterpret_cast<const uint4*>(uh);
      #pragma unroll
      for (int t = 0; t < 8; ++t) {
        uint4 uu = uh4[t];
        c0a = fdot2f(kta[4 * t + 0], uu.x, c0a);
        c0b = fdot2f(kta[4 * t + 1], uu.y, c0b);
        c0a = fdot2f(kta[4 * t + 2], uu.z, c0a);
        c0b = fdot2f(kta[4 * t + 3], uu.w, c0b);
        c1a = fdot2f(ktb[4 * t + 0], uu.x, c1a);
        c1b = fdot2f(ktb[4 * t + 1], uu.y, c1b);
        c1a = fdot2f(ktb[4 * t + 2], uu.z, c1a);
        c1b = fdot2f(ktb[4 * t + 3], uu.w, c1b);
      }
      float v0n = rcpf_(c0a + c0b);
      float v1n = rcpf_(c1a + c1b);
      float m2 = fabsf(v0n - vo0) - TOL * v0n;
      float m3 = fabsf(v1n - vo1) - TOL * v1n;
      vo0 = v0n; vo1 = v1n;
      vh[l] = pk2(v0n, v1n);
      float sv = v0n + v1n;
      sv += __shfl_xor(sv, 1);  sv += __shfl_xor(sv, 2);
      sv += __shfl_xor(sv, 4);  sv += __shfl_xor(sv, 8);
      sv += __shfl_xor(sv, 16); sv += __shfl_xor(sv, 32);
      sum_v = sv + v128n;
      v128 = v128n;
      float mcond = fmaxf(m1, fmaxf(m2, m3));
      if (__all(mcond <= 0.0f)) break;
    }

    // P = K*u*v (bf16) IN PLACE over Ksh[wv]
    {
      const uint4* vh4 = reinterpret_cast<const uint4*>(vh);
      #pragma unroll
      for (int t = 0; t < 16; ++t) {
        uint4 vvv = vh4[t];
        u32 o0 = bfpk(h_lo(kr[4 * t + 0]) * ur * h_lo(vvv.x),
                      h_hi(kr[4 * t + 0]) * ur * h_hi(vvv.x));
        u32 o1 = bfpk(h_lo(kr[4 * t + 1]) * ur * h_lo(vvv.y),
                      h_hi(kr[4 * t + 1]) * ur * h_hi(vvv.y));
        u32 o2 = bfpk(h_lo(kr[4 * t + 2]) * ur * h_lo(vvv.z),
                      h_hi(kr[4 * t + 2]) * ur * h_hi(vvv.z));
        u32 o3 = bfpk(h_lo(kr[4 * t + 3]) * ur * h_lo(vvv.w),
                      h_hi(kr[4 * t + 3]) * ur * h_hi(vvv.w));
        *reinterpret_cast<uint4*>(&Ks[l * 68 + 4 * t]) = make_uint4(o0, o1, o2, o3);
      }
    }
  } else {
    // stage adj rows 0..63 -> adjb (128 threads)
    const float4* src = reinterpret_cast<const float4*>(adj + (size_t)b * (NN * NN));
    for (int i = tid - 128; i < 64 * 32; i += 128) {
      int row = i >> 5, c4 = i & 31;
      float4 v = src[i];
      u32 w0 = (u32)f2bf(v.x) | ((u32)f2bf(v.y) << 16);
      u32 w1 = (u32)f2bf(v.z) | ((u32)f2bf(v.w) << 16);
      *reinterpret_cast<uint2*>(&adjb[row * AP + c4 * 4]) = make_uint2(w0, w1);
    }
  }
  __syncthreads();   // P0,P1 in Ksh; adjb h0 staged

  // ======================= Phase C: align ================================
  const float aa = 1.0f / (1.0f + __expf(-alpha_p[0]));
  const float na = 1.0f - aa;
  // Pc = aa*P0 + na*P1 into Ksh[0]
  for (int i = tid; i < 4096; i += 256) {
    int row = i >> 6, cd = i & 63;
    Ksh[0][row * 68 + cd] = comb2(Ksh[0][row * 68 + cd], Ksh[1][row * 68 + cd], aa, na);
  }
  __syncthreads();
  const unsigned short* Pc = reinterpret_cast<const unsigned short*>(Ksh[0]);

  // M1 half 0: Z1T[k][n] = sum_d adj[n][d]*Pc[k][d], n in 0..63
  {
    f32x4 acch[4];
    #pragma unroll
    for (int j = 0; j < 4; ++j) acch[j] = f32x4{0.f, 0.f, 0.f, 0.f};
    #pragma unroll
    for (int kt = 0; kt < 4; ++kt) {
      const int d0 = 32 * kt + 8 * q;
      bf16x8 af = ldfrag(&adjb[(16 * wv + l15) * AP + d0]);
      #pragma unroll
      for (int j = 0; j < 4; ++j) {
        bf16x8 bf = ldfrag(&Pc[(16 * j + l15) * AP + d0]);
        acch[j] = __builtin_amdgcn_mfma_f32_16x16x32_bf16(af, bf, acch[j], 0, 0, 0);
      }
    }
    __syncthreads();   // actL ghosts gone; (Z1T writes after all reads? Z1T=scratch now) 
    #pragma unroll
    for (int j = 0; j < 4; ++j) {
      const int k = 16 * j + l15;
      const int nbase = 16 * wv + 4 * q;
      u32 w0 = (u32)f2bf(acch[j][0]) | ((u32)f2bf(acch[j][1]) << 16);
      u32 w1 = (u32)f2bf(acch[j][2]) | ((u32)f2bf(acch[j][3]) << 16);
      *reinterpret_cast<uint2*>(&Z1T[k * AP + nbase]) = make_uint2(w0, w1);
    }
  }
  __syncthreads();   // adjb h0 reads done

  // stage adj rows 64..127
  {
    const float4* src = reinterpret_cast<const float4*>(
        adj + (size_t)b * (NN * NN) + (size_t)64 * NN);
    for (int i = tid; i < 64 * 32; i += 256) {
      int row = i >> 5, c4 = i & 31;
      float4 v = src[i];
      u32 w0 = (u32)f2bf(v.x) | ((u32)f2bf(v.y) << 16);
      u32 w1 = (u32)f2bf(v.z) | ((u32)f2bf(v.w) << 16);
      *reinterpret_cast<uint2*>(&adjb[row * AP + c4 * 4]) = make_uint2(w0, w1);
    }
  }
  __syncthreads();

  // M1 half 1
  {
    f32x4 acch[4];
    #pragma unroll
    for (int j = 0; j < 4; ++j) acch[j] = f32x4{0.f, 0.f, 0.f, 0.f};
    #pragma unroll
    for (int kt = 0; kt < 4; ++kt) {
      const int d0 = 32 * kt + 8 * q;
      bf16x8 af = ldfrag(&adjb[(16 * wv + l15) * AP + d0]);
      #pragma unroll
      for (int j = 0; j < 4; ++j) {
        bf16x8 bf = ldfrag(&Pc[(16 * j + l15) * AP + d0]);
        acch[j] = __builtin_amdgcn_mfma_f32_16x16x32_bf16(af, bf, acch[j], 0, 0, 0);
      }
    }
    #pragma unroll
    for (int j = 0; j < 4; ++j) {
      const int k = 16 * j + l15;
      const int nbase = 64 + 16 * wv + 4 * q;
      u32 w0 = (u32)f2bf(acch[j][0]) | ((u32)f2bf(acch[j][1]) << 16);
      u32 w1 = (u32)f2bf(acch[j][2]) | ((u32)f2bf(acch[j][3]) << 16);
      *reinterpret_cast<uint2*>(&Z1T[k * AP + nbase]) = make_uint2(w0, w1);
    }
  }
  __syncthreads();   // Z1T complete; adjb h1 reads done

  // stage xfT into adjb tail (rows 48..63 region: no overlap with ob1 head)
  unsigned short* xfT = adjb + 48 * AP;
  for (int i = tid; i < 2048; i += 256) {
    int n = i & 127, f = i >> 7;
    xfT[f * AP + n] = f2bf(x[((size_t)b * NN + n) * IND + 2 + f]);
  }
  __syncthreads();

  // M2: al2 = Pc @ Z1 ; M3: feats = Pc @ xf
  f32x4 acc2[4];
  f32x4 acc3 = f32x4{0.f, 0.f, 0.f, 0.f};
  #pragma unroll
  for (int j = 0; j < 4; ++j) acc2[j] = f32x4{0.f, 0.f, 0.f, 0.f};
  #pragma unroll
  for (int nt = 0; nt < 4; ++nt) {
    const int n0 = 32 * nt + 8 * q;
    bf16x8 af = ldfrag(&Pc[(16 * wv + l15) * AP + n0]);
    #pragma unroll
    for (int j = 0; j < 4; ++j) {
      bf16x8 bv = ldfrag(&Z1T[(16 * j + l15) * AP + n0]);
      acc2[j] = __builtin_amdgcn_mfma_f32_16x16x32_bf16(af, bv, acc2[j], 0, 0, 0);
    }
    bf16x8 bx = ldfrag(&xfT[l15 * AP + n0]);
    acc3 = __builtin_amdgcn_mfma_f32_16x16x32_bf16(af, bx, acc3, 0, 0, 0);
  }

  // LN reductions
  {
    float s1 = 0.f, q1 = 0.f, s2 = 0.f, q2 = 0.f;
    #pragma unroll
    for (int j = 0; j < 4; ++j)
      #pragma unroll
      for (int r = 0; r < 4; ++r) { float v = acc2[j][r]; s1 += v; q1 += v * v; }
    #pragma unroll
    for (int r = 0; r < 4; ++r) { float v = acc3[r]; s2 += v; q2 += v * v; }
    #pragma unroll
    for (int off = 1; off < 64; off <<= 1) {
      s1 += __shfl_xor(s1, off); q1 += __shfl_xor(q1, off);
      s2 += __shfl_xor(s2, off); q2 += __shfl_xor(q2, off);
    }
    if (lane == 0) { red[wv] = s1; red[4 + wv] = q1; red[8 + wv] = s2; red[12 + wv] = q2; }
  }
  __syncthreads();
  const float S1 = red[0] + red[1] + red[2] + red[3];
  const float Q1 = red[4] + red[5] + red[6] + red[7];
  const float S2 = red[8] + red[9] + red[10] + red[11];
  const float Q2 = red[12] + red[13] + red[14] + red[15];
  const float mean1 = S1 * (1.0f / 4096.0f);
  const float rstd1 = rsqrtf(Q1 * (1.0f / 4096.0f) - mean1 * mean1 + 1e-5f);
  const float mean2 = S2 * (1.0f / 1024.0f);
  const float rstd2 = rsqrtf(Q2 * (1.0f / 1024.0f) - mean2 * mean2 + 1e-5f);

  // normalize + bounce (ob1 = adjb head 4096 shorts; ob2 = Z1T head 1024)
  unsigned short* ob1 = adjb;
  unsigned short* ob2 = Z1T;
  #pragma unroll
  for (int j = 0; j < 4; ++j) {
    const int k = 16 * j + l15;
    #pragma unroll
    for (int r = 0; r < 4; ++r) {
      const int m = 16 * wv + 4 * q + r;
      const int pos = m * 64 + k;
      float vv2 = (acc2[j][r] - mean1) * rstd1 * ln1g[pos] + ln1b[pos];
      ob1[pos] = f2bf(vv2);
    }
  }
  {
    const int f = l15;
    #pragma unroll
    for (int r = 0; r < 4; ++r) {
      const int m = 16 * wv + 4 * q + r;
      const int pos = m * 16 + f;
      float vv2 = (acc3[r] - mean2) * rstd2 * ln2g[pos] + ln2b[pos];
      ob2[pos] = f2bf(vv2);
    }
  }
  __syncthreads();
  {
    const uint4* sp = reinterpret_cast<const uint4*>(ob1);
    uint4* dp = reinterpret_cast<uint4*>(lnadj + (size_t)b * 4096);
    for (int i = tid; i < 512; i += 256) dp[i] = sp[i];
    if (tid < 128)
      reinterpret_cast<uint4*>(lnfeats + (size_t)b * 1024)[tid] =
          reinterpret_cast<const uint4*>(ob2)[tid];
  }
}

// ---------------------------------------------------------------------------
// Kernel C (MFMA): unchanged.
// ---------------------------------------------------------------------------
#define GP 72
__launch_bounds__(256, 2)
__global__ void gemm_mfma_kernel(const unsigned short* __restrict__ A,
                                 const float* __restrict__ W,
                                 const float* __restrict__ bias,
                                 float* __restrict__ C,
                                 int K, int ldc, int coff)
{
  __shared__ __align__(16) unsigned short At[64 * GP];
  __shared__ __align__(16) unsigned short Wt[64 * GP];
  const int tid = threadIdx.x;
  const int m0 = blockIdx.x * 64;
  const int n0 = blockIdx.y * 64;
  const int w = tid >> 6, lane = tid & 63;
  const int l15 = lane & 15, q = lane >> 4;
  const int srow = tid >> 2, sko = (tid & 3) * 16;

  f32x4 acc[4];
  #pragma unroll
  for (int j = 0; j < 4; ++j) acc[j] = f32x4{0.f, 0.f, 0.f, 0.f};

  for (int kc = 0; kc < K; kc += 64) {
    __syncthreads();
    {
      const unsigned short* ap = &A[(size_t)(m0 + srow) * K + kc + sko];
      *reinterpret_cast<uint4*>(&At[srow * GP + sko]) =
          *reinterpret_cast<const uint4*>(ap);
      *reinterpret_cast<uint4*>(&At[srow * GP + sko + 8]) =
          *reinterpret_cast<const uint4*>(ap + 8);
      const float* wp = &W[(size_t)(n0 + srow) * K + kc + sko];
      const float4 v0 = reinterpret_cast<const float4*>(wp)[0];
      const float4 v1 = reinterpret_cast<const float4*>(wp)[1];
      const float4 v2 = reinterpret_cast<const float4*>(wp)[2];
      const float4 v3 = reinterpret_cast<const float4*>(wp)[3];
      uint4 o0, o1;
      o0.x = (u32)f2bf(v0.x) | ((u32)f2bf(v0.y) << 16);
      o0.y = (u32)f2bf(v0.z) | ((u32)f2bf(v0.w) << 16);
      o0.z = (u32)f2bf(v1.x) | ((u32)f2bf(v1.y) << 16);
      o0.w = (u32)f2bf(v1.z) | ((u32)f2bf(v1.w) << 16);
      o1.x = (u32)f2bf(v2.x) | ((u32)f2bf(v2.y) << 16);
      o1.y = (u32)f2bf(v2.z) | ((u32)f2bf(v2.w) << 16);
      o1.z = (u32)f2bf(v3.x) | ((u32)f2bf(v3.y) << 16);
      o1.w = (u32)f2bf(v3.z) | ((u32)f2bf(v3.w) << 16);
      *reinterpret_cast<uint4*>(&Wt[srow * GP + sko]) = o0;
      *reinterpret_cast<uint4*>(&Wt[srow * GP + sko + 8]) = o1;
    }
    __syncthreads();
    #pragma unroll
    for (int s = 0; s < 2; ++s) {
      bf16x8 af = ldfrag(&At[(16 * w + l15) * GP + 32 * s + 8 * q]);
      #pragma unroll
      for (int j = 0; j < 4; ++j) {
        bf16x8 bf = ldfrag(&Wt[(16 * j + l15) * GP + 32 * s + 8 * q]);
        acc[j] = __builtin_amdgcn_mfma_f32_16x16x32_bf16(af, bf, acc[j], 0, 0, 0);
      }
    }
  }
  #pragma unroll
  for (int j = 0; j < 4; ++j) {
    const int col = n0 + 16 * j + l15;
    const float bb = bias[col];
    #pragma unroll
    for (int r = 0; r < 4; ++r) {
      const int m = m0 + 16 * w + 4 * q + r;
      C[(size_t)m * ldc + coff + col] = fmaxf(acc[j][r] + bb, 0.0f);
    }
  }
}

// ---------------------------------------------------------------------------
// Kernel D: unchanged (8 rows/block).
// ---------------------------------------------------------------------------
__launch_bounds__(256)
__global__ void head_kernel(const float* __restrict__ h45,
                            const float* __restrict__ wT6,   // [512][64]
                            const float* __restrict__ b6,
                            const float* __restrict__ w7,    // [10][64]
                            const float* __restrict__ b7,
                            float* __restrict__ out)
{
  __shared__ float row[8][512];
  __shared__ float h6[8][64];
  __shared__ float zb[8][12];
  const int tid = threadIdx.x;
  const int r0 = blockIdx.x * 8;
  for (int i = tid; i < 8 * 128; i += 256) {
    int r = i >> 7, c4 = i & 127;
    *reinterpret_cast<float4*>(&row[r][c4 * 4]) =
        reinterpret_cast<const float4*>(h45 + (size_t)(r0 + r) * 512)[c4];
  }
  __syncthreads();
  const int o = tid & 63, rg = tid >> 6;
  float a0 = b6[o], a1 = a0;
  #pragma unroll 8
  for (int k = 0; k < 512; ++k) {
    float wv = wT6[k * 64 + o];
    a0 += row[rg][k] * wv;
    a1 += row[rg + 4][k] * wv;
  }
  h6[rg][o] = fmaxf(a0, 0.0f);
  h6[rg + 4][o] = fmaxf(a1, 0.0f);
  __syncthreads();
  if (tid < 80) {
    int r = tid / 10, c = tid - r * 10;
    float z = b7[c];
    #pragma unroll
    for (int k = 0; k < 64; ++k) z += h6[r][k] * w7[c * 64 + k];
    zb[r][c] = z;
  }
  __syncthreads();
  if (tid < 80) {
    int r = tid / 10, c = tid - r * 10;
    float mx = zb[r][0];
    #pragma unroll
    for (int j = 1; j < 10; ++j) mx = fmaxf(mx, zb[r][j]);
    float se = 0.f;
    #pragma unroll
    for (int j = 0; j < 10; ++j) se += __expf(zb[r][j] - mx);
    out[(size_t)(r0 + r) * 10 + c] = zb[r][c] - mx - __logf(se);
  }
}

__global__ void transpose_kernel(const float* __restrict__ in, float* __restrict__ outp,
                                 int R, int Cc)
{
  int idx = blockIdx.x * blockDim.x + threadIdx.x;
  int total = R * Cc;
  for (; idx < total; idx += gridDim.x * blockDim.x) {
    int rr = idx / Cc, cc = idx - rr * Cc;
    outp[cc * R + rr] = in[idx];
  }
}

// ---------------------------------------------------------------------------
extern "C" void kernel_launch(void* const* d_in, const int* in_sizes, int n_in,
                              void* d_out, int out_size, void* d_ws, size_t ws_size,
                              hipStream_t stream)
{
  (void)in_sizes; (void)n_in; (void)out_size; (void)ws_size;
  const float* x    = (const float*)d_in[0];
  const float* adj  = (const float*)d_in[1];
  const float* w1   = (const float*)d_in[2];
  const float* w2   = (const float*)d_in[3];
  const float* alpha = (const float*)d_in[4];
  const float* bin_score = (const float*)d_in[5];
  const float* fc2w = (const float*)d_in[6];
  const float* fc2b = (const float*)d_in[7];
  const float* fc3w = (const float*)d_in[8];
  const float* fc3b = (const float*)d_in[9];
  const float* ln1g = (const float*)d_in[10];
  const float* ln1b = (const float*)d_in[11];
  const float* fc4w = (const float*)d_in[12];
  const float* fc4b = (const float*)d_in[13];
  const float* ln2g = (const float*)d_in[14];
  const float* ln2b = (const float*)d_in[15];
  const float* fc5w = (const float*)d_in[16];
  const float* fc5b = (const float*)d_in[17];
  const float* fc6w = (const float*)d_in[18];
  const float* fc6b = (const float*)d_in[19];
  const float* fc7w = (const float*)d_in[20];
  const float* fc7b = (const float*)d_in[21];
  float* out = (float*)d_out;

  char* ws = (char*)d_ws;
  size_t off = 0;
  unsigned short* lnadj = (unsigned short*)(ws + off);  off += (size_t)2048 * 4096 * 2;
  unsigned short* lnfeats = (unsigned short*)(ws + off); off += (size_t)2048 * 1024 * 2;
  float* h45 = (float*)(ws + off);                      off += (size_t)2048 * 512 * 4;
  float* wT6 = (float*)(ws + off);                      off += (size_t)512 * 64 * 4;

  hipLaunchKernelGGL(transpose_kernel, dim3(32), dim3(256), 0, stream, fc6w, wT6, 64, 512);
  hipLaunchKernelGGL(fused_kernel, dim3(2048), dim3(256), 0, stream,
                     x, adj, w1, w2, alpha, bin_score,
                     fc2w, fc2b, fc3w, fc3b,
                     ln1g, ln1b, ln2g, ln2b, lnadj, lnfeats);
  hipLaunchKernelGGL(gemm_mfma_kernel, dim3(32, 4), dim3(256), 0, stream,
                     lnadj, fc4w, fc4b, h45, 4096, 512, 0);
  hipLaunchKernelGGL(gemm_mfma_kernel, dim3(32, 4), dim3(256), 0, stream,
                     lnfeats, fc5w, fc5b, h45, 1024, 512, 256);
  hipLaunchKernelGGL(head_kernel, dim3(256), dim3(256), 0, stream,
                     h45, wT6, fc6b, fc7w, fc7b, out);
}